// Round 1
// baseline (179969.385 us; speedup 1.0000x reference)
//
#include <hip/hip_runtime.h>
#include <math.h>

// Sizes (fixed by the problem)
// B=32, T=100, S=100, H=512, E=256, V=30000, 4H=2048, T-1=99, M_log=3168
#define DIV_UP(a,b) (((a)+(b)-1)/(b))

__device__ __forceinline__ float sigf(float x){ return 1.0f/(1.0f + __expf(-x)); }
__device__ __forceinline__ float tanhc(float x){
  x = fminf(fmaxf(x, -15.f), 15.f);
  float e = __expf(2.f*x);
  return (e-1.f)/(e+1.f);
}

// ---------------------------------------------------------------------------
// prep: build gate-permuted weights for one LSTM.
//  o' = u*4 + g  (u = hidden unit 0..511, g = 0:i 1:f 2:g 3:o ; source row g*512+u)
//  WiP[o'][e]   = Wi[g*512+u][e]
//  WhTp[k][o']  = Wh[g*512+u][k]     (transposed for coalesced per-step reads)
//  biasP[o']    = bi[g*512+u] + bh[g*512+u]
// ---------------------------------------------------------------------------
__global__ void prep_permute(const float* __restrict__ Wi, const float* __restrict__ Wh,
                             const float* __restrict__ bi, const float* __restrict__ bh,
                             float* __restrict__ WiP, float* __restrict__ WhTp,
                             float* __restrict__ biasP)
{
  int idx = blockIdx.x*256 + threadIdx.x;      // 0 .. 1048575
  {
    int k = idx >> 11, op = idx & 2047;
    int u = op >> 2, g = op & 3;
    WhTp[idx] = Wh[(g*512+u)*512 + k];
  }
  if (idx < 2048*256) {
    int op = idx >> 8, e = idx & 255;
    int u = op >> 2, g = op & 3;
    WiP[idx] = Wi[(g*512+u)*256 + e];
  }
  if (idx < 2048) {
    int u = idx >> 2, g = idx & 3;
    biasP[idx] = bi[g*512+u] + bh[g*512+u];
  }
}

// init transposed state buffers hT/cT [parity=0][lstm][u=512][b=32]
__global__ void init_state(const float* __restrict__ h0, const float* __restrict__ c0,
                           float* __restrict__ hT, float* __restrict__ cT)
{
  int idx = blockIdx.x*256 + threadIdx.x;   // 0..32767 : l,u,b
  int l = idx >> 14, u = (idx >> 5) & 511, b = idx & 31;
  float hv = h0[b*512 + u];
  float cv = c0[b*512 + u];
  hT[((0*2 + l)*512 + u)*32 + b] = hv;
  cT[((0*2 + l)*512 + u)*32 + b] = cv;
}

// ---------------------------------------------------------------------------
// Generic f32 GEMM  C[M,N] = act( A * op(B) + bias ), batched via blockIdx.z.
//  TRANSB=1 : B is [N][K] row-major (C = A·B^T)
//  TRANSB=0 : B is [K][N] row-major (C = A·B)
//  GATHER=1 : A row index m is replaced by tok[m] (rows of A are emb rows)
// Tiles 64x64x32, 256 threads, 4x4 micro-tile.
// ---------------------------------------------------------------------------
template<int GATHER,int TRANSB,int BIAS,int TANH>
__global__ __launch_bounds__(256) void gemm_f32(
    const float* __restrict__ A, const int* __restrict__ tok,
    const float* __restrict__ Bmat, const float* __restrict__ bias,
    float* __restrict__ C,
    int M, int N, int K, int lda, int ldb, int ldc,
    long sA, long sB, long sC)
{
  __shared__ float As[32][68];
  __shared__ float Bs[32][68];
  const int z = blockIdx.z;
  A    += (long)z * sA;
  Bmat += (long)z * sB;
  C    += (long)z * sC;
  const int bm = blockIdx.y*64, bn = blockIdx.x*64;
  const int tid = threadIdx.x;
  const int tx = tid & 15, ty = tid >> 4;
  float acc[4][4] = {};

  for (int k0 = 0; k0 < K; k0 += 32) {
    // ---- A tile: rows bm..bm+63, k0..k0+31  -> As[k][m]
    {
      int r = tid >> 2;
      int c0 = (tid & 3) * 8;
      int row = bm + r; if (row > M-1) row = M-1;
      int arow = row;
      if (GATHER) arow = tok[row];
      const float* ap = A + (long)arow * lda;
      #pragma unroll
      for (int q = 0; q < 2; ++q) {
        int kk = c0 + q*4;
        float4 v;
        if (k0 + kk + 4 <= K) v = *(const float4*)(ap + k0 + kk);
        else {
          v.x = (k0+kk+0 < K) ? ap[k0+kk+0] : 0.f;
          v.y = (k0+kk+1 < K) ? ap[k0+kk+1] : 0.f;
          v.z = (k0+kk+2 < K) ? ap[k0+kk+2] : 0.f;
          v.w = (k0+kk+3 < K) ? ap[k0+kk+3] : 0.f;
        }
        As[kk+0][r]=v.x; As[kk+1][r]=v.y; As[kk+2][r]=v.z; As[kk+3][r]=v.w;
      }
    }
    // ---- B tile -> Bs[k][n]
    if (TRANSB) {
      int n = tid >> 2;
      int c0 = (tid & 3) * 8;
      int col = bn + n; if (col > N-1) col = N-1;
      const float* bp = Bmat + (long)col * ldb;
      #pragma unroll
      for (int q = 0; q < 2; ++q) {
        int kk = c0 + q*4;
        float4 v;
        if (k0 + kk + 4 <= K) v = *(const float4*)(bp + k0 + kk);
        else {
          v.x = (k0+kk+0 < K) ? bp[k0+kk+0] : 0.f;
          v.y = (k0+kk+1 < K) ? bp[k0+kk+1] : 0.f;
          v.z = (k0+kk+2 < K) ? bp[k0+kk+2] : 0.f;
          v.w = (k0+kk+3 < K) ? bp[k0+kk+3] : 0.f;
        }
        Bs[kk+0][n]=v.x; Bs[kk+1][n]=v.y; Bs[kk+2][n]=v.z; Bs[kk+3][n]=v.w;
      }
    } else {
      int kk = tid >> 3;
      int c0 = (tid & 7) * 8;
      int krow = k0 + kk;
      #pragma unroll
      for (int q = 0; q < 2; ++q) {
        int cc = c0 + q*4;
        int col = bn + cc;
        float4 v = make_float4(0.f,0.f,0.f,0.f);
        if (krow < K) {
          const float* bp = Bmat + (long)krow * ldb;
          if (col + 4 <= N) v = *(const float4*)(bp + col);
          else {
            v.x = (col+0 < N) ? bp[col+0] : 0.f;
            v.y = (col+1 < N) ? bp[col+1] : 0.f;
            v.z = (col+2 < N) ? bp[col+2] : 0.f;
            v.w = (col+3 < N) ? bp[col+3] : 0.f;
          }
        }
        Bs[kk][cc+0]=v.x; Bs[kk][cc+1]=v.y; Bs[kk][cc+2]=v.z; Bs[kk][cc+3]=v.w;
      }
    }
    __syncthreads();
    #pragma unroll
    for (int kk = 0; kk < 32; ++kk) {
      float4 a = *(const float4*)&As[kk][ty*4];
      float4 b = *(const float4*)&Bs[kk][tx*4];
      acc[0][0]=fmaf(a.x,b.x,acc[0][0]); acc[0][1]=fmaf(a.x,b.y,acc[0][1]);
      acc[0][2]=fmaf(a.x,b.z,acc[0][2]); acc[0][3]=fmaf(a.x,b.w,acc[0][3]);
      acc[1][0]=fmaf(a.y,b.x,acc[1][0]); acc[1][1]=fmaf(a.y,b.y,acc[1][1]);
      acc[1][2]=fmaf(a.y,b.z,acc[1][2]); acc[1][3]=fmaf(a.y,b.w,acc[1][3]);
      acc[2][0]=fmaf(a.z,b.x,acc[2][0]); acc[2][1]=fmaf(a.z,b.y,acc[2][1]);
      acc[2][2]=fmaf(a.z,b.z,acc[2][2]); acc[2][3]=fmaf(a.z,b.w,acc[2][3]);
      acc[3][0]=fmaf(a.w,b.x,acc[3][0]); acc[3][1]=fmaf(a.w,b.y,acc[3][1]);
      acc[3][2]=fmaf(a.w,b.z,acc[3][2]); acc[3][3]=fmaf(a.w,b.w,acc[3][3]);
    }
    __syncthreads();
  }
  #pragma unroll
  for (int i = 0; i < 4; ++i) {
    int row = bm + ty*4 + i;
    if (row >= M) continue;
    #pragma unroll
    for (int j = 0; j < 4; ++j) {
      int col = bn + tx*4 + j;
      if (col >= N) continue;
      float v = acc[i][j];
      if (BIAS) v += bias[col];
      if (TANH) v = tanhc(v);
      C[(long)row*ldc + col] = v;
    }
  }
}

// ---------------------------------------------------------------------------
// One LSTM step for both LSTMs. Gate-permuted: o' = u*4+g.
// grid (32, 2): 64 o' per block; block 256 = 32 b-lanes x 8 og-groups.
// Thread (bl, og) owns units u = ob*16+og*2+{0,1}, all 4 gates each -> local
// cell update. States transposed [parity][lstm][u][b] for coalesced access.
// ---------------------------------------------------------------------------
__global__ __launch_bounds__(256) void lstm_step(
    const float* __restrict__ WhTp_e, const float* __restrict__ WhTp_w,
    const float* __restrict__ Xp_e,  const float* __restrict__ Xp_w,
    float* __restrict__ hT, float* __restrict__ cT,
    float* __restrict__ outT,   // [lstm][t][u][b]
    int t)
{
  const int l  = blockIdx.y;
  const float* WhTp = l ? WhTp_w : WhTp_e;
  const float* Xp   = l ? Xp_w   : Xp_e;
  const int ob = blockIdx.x;            // 0..31
  const int tid = threadIdx.x;
  const int bl = tid & 31, og = tid >> 5;
  const int pin = t & 1, pout = pin ^ 1;

  __shared__ float h_lds[64][36];
  __shared__ float w_lds[64][64];

  const float* hin = hT + (long)((pin*2 + l)*512)*32;
  float acc[8] = {0.f,0.f,0.f,0.f,0.f,0.f,0.f,0.f};

  for (int k0 = 0; k0 < 512; k0 += 64) {
    { // stage h chunk [64k][32b]
      int kk = tid >> 2;
      int c0 = (tid & 3) * 8;
      const float* hp = hin + (long)(k0+kk)*32 + c0;
      float4 v0 = *(const float4*)hp;
      float4 v1 = *(const float4*)(hp + 4);
      *(float4*)&h_lds[kk][c0]   = v0;
      *(float4*)&h_lds[kk][c0+4] = v1;
    }
    { // stage w chunk [64k][64 o']
      int kk = tid >> 2;
      int c0 = (tid & 3) * 16;
      const float* wp = WhTp + (long)(k0+kk)*2048 + ob*64 + c0;
      float4 v0 = *(const float4*)(wp+0);
      float4 v1 = *(const float4*)(wp+4);
      float4 v2 = *(const float4*)(wp+8);
      float4 v3 = *(const float4*)(wp+12);
      *(float4*)&w_lds[kk][c0+0]  = v0;
      *(float4*)&w_lds[kk][c0+4]  = v1;
      *(float4*)&w_lds[kk][c0+8]  = v2;
      *(float4*)&w_lds[kk][c0+12] = v3;
    }
    __syncthreads();
    #pragma unroll 8
    for (int kk = 0; kk < 64; ++kk) {
      float hv = h_lds[kk][bl];
      const float* wr = &w_lds[kk][og*8];
      float4 w0 = *(const float4*)wr;
      float4 w1 = *(const float4*)(wr+4);
      acc[0]=fmaf(hv,w0.x,acc[0]); acc[1]=fmaf(hv,w0.y,acc[1]);
      acc[2]=fmaf(hv,w0.z,acc[2]); acc[3]=fmaf(hv,w0.w,acc[3]);
      acc[4]=fmaf(hv,w1.x,acc[4]); acc[5]=fmaf(hv,w1.y,acc[5]);
      acc[6]=fmaf(hv,w1.z,acc[6]); acc[7]=fmaf(hv,w1.w,acc[7]);
    }
    __syncthreads();
  }

  // epilogue: add Xproj, nonlinearities, state update
  const float* xp = Xp + ((long)(bl*100 + t))*2048 + ob*64 + og*8;
  float4 x0 = *(const float4*)xp;
  float4 x1 = *(const float4*)(xp+4);
  float g[8] = { acc[0]+x0.x, acc[1]+x0.y, acc[2]+x0.z, acc[3]+x0.w,
                 acc[4]+x1.x, acc[5]+x1.y, acc[6]+x1.z, acc[7]+x1.w };

  float* cin  = cT + (long)((pin*2 + l)*512)*32;
  float* cout = cT + (long)((pout*2 + l)*512)*32;
  float* hout = hT + (long)((pout*2 + l)*512)*32;
  float* oseq = outT + (long)((l*100 + t)*512)*32;

  #pragma unroll
  for (int uu = 0; uu < 2; ++uu) {
    int u = ob*16 + og*2 + uu;
    float ii = sigf(g[uu*4+0]);
    float ff = sigf(g[uu*4+1]);
    float gt = tanhc(g[uu*4+2]);
    float oo = sigf(g[uu*4+3]);
    float cprev = cin[u*32 + bl];
    float cnew = ff*cprev + ii*gt;
    float hnew = oo*tanhc(cnew);
    cout[u*32 + bl] = cnew;
    hout[u*32 + bl] = hnew;
    oseq[u*32 + bl] = hnew;
  }
}

// transpose out sequences [lstm][t][u][b] -> standard [b][t][u]
__global__ __launch_bounds__(256) void transpose_out(
    const float* __restrict__ outT, float* __restrict__ out_e, float* __restrict__ out_w)
{
  __shared__ float tile[512][33];
  const int t = blockIdx.x, l = blockIdx.y;
  const float* src = outT + (long)((l*100 + t))*512*32;
  const int tid = threadIdx.x;
  #pragma unroll
  for (int i = 0; i < 16; ++i) {
    int fi = tid + 256*i;                 // float4 index, 0..4095
    int u = fi >> 3, b4 = (fi & 7) * 4;
    float4 v = *(const float4*)(src + (long)fi*4);
    tile[u][b4+0]=v.x; tile[u][b4+1]=v.y; tile[u][b4+2]=v.z; tile[u][b4+3]=v.w;
  }
  __syncthreads();
  float* dst = l ? out_w : out_e;
  for (int b = 0; b < 32; ++b) {
    float* drow = dst + (long)(b*100 + t)*512;
    drow[tid]       = tile[tid][b];
    drow[tid+256]   = tile[tid+256][b];
  }
}

// softmax over rows of P [3200][128] (100 valid cols), one wave per row
__global__ void softmax_rows(float* __restrict__ P)
{
  int row  = blockIdx.x*4 + (threadIdx.x >> 6);
  int lane = threadIdx.x & 63;
  float* p = P + (long)row*128;
  float x0 = (lane      < 100) ? p[lane]    : -INFINITY;
  float x1 = (lane + 64 < 100) ? p[lane+64] : -INFINITY;
  float m = fmaxf(x0, x1);
  #pragma unroll
  for (int off = 32; off; off >>= 1) m = fmaxf(m, __shfl_xor(m, off));
  float e0 = (lane      < 100) ? __expf(x0 - m) : 0.f;
  float e1 = (lane + 64 < 100) ? __expf(x1 - m) : 0.f;
  float s = e0 + e1;
  #pragma unroll
  for (int off = 32; off; off >>= 1) s += __shfl_xor(s, off);
  float inv = 1.f / s;
  if (lane      < 100) p[lane]    = e0 * inv;
  if (lane + 64 < 100) p[lane+64] = e1 * inv;
}

// edit counters (exclusive cumsum, clipped)
__global__ void counters_kernel(const int* __restrict__ ie,
                                int* __restrict__ ctr_del, int* __restrict__ ctr_ins)
{
  int b = threadIdx.x;
  if (b >= 32) return;
  int rd = 0, ri = 0;
  for (int t = 0; t < 99; ++t) {
    int a = ie[b*100 + t + 1];
    int incd = (a == 2 || a == 3) ? 1 : 0;                 // KEEP|DEL
    int inci = (a != 3 && a != 5 && a != 0) ? 1 : 0;       // !DEL,!STOP,!PAD
    ctr_del[b*99 + t] = min(rd, 99);
    ctr_ins[b*99 + t] = min(ri, 99);
    rd += incd; ri += inci;
  }
}

// build feat rows [3168][2048] = [out_e | applied | enc[ctr_del] | out_w[ctr_ins]]
__global__ void feat_kernel(const float* __restrict__ out_e, const float* __restrict__ applied,
                            const float* __restrict__ enc,  const float* __restrict__ out_w,
                            const int* __restrict__ ctr_del, const int* __restrict__ ctr_ins,
                            float* __restrict__ feat)
{
  int n = blockIdx.x;                 // 0..3167
  int b = n / 99, t = n % 99;
  const float* s0 = out_e  + (long)(b*100 + t)*512;
  const float* s1 = applied+ (long)(b*100 + t)*512;
  const float* s2 = enc    + (long)(b*100 + ctr_del[n])*512;
  const float* s3 = out_w  + (long)(b*100 + ctr_ins[n])*512;
  float* d = feat + (long)n*2048;
  int tid = threadIdx.x;
  #pragma unroll
  for (int q = 0; q < 2; ++q) {
    int slot = tid + 256*q;           // 0..511 float4 slots
    int seg = slot >> 7;
    int off = (slot & 127) * 4;
    const float* s = (seg==0) ? s0 : (seg==1) ? s1 : (seg==2) ? s2 : s3;
    *(float4*)(d + seg*512 + off) = *(const float4*)(s + off);
  }
}

// logits GEMM: C[3168][30000] = hmlp[3168][256] * emb^T + b_out, writes raw
// logits to d_out and per-64-col-tile (rowmax, sumexp) partials.
__global__ __launch_bounds__(256) void logits_partial(
    const float* __restrict__ A, const float* __restrict__ Bmat,
    const float* __restrict__ bias, float* __restrict__ C,
    float2* __restrict__ partial)
{
  __shared__ float As[32][68];
  __shared__ float Bs[32][68];
  __shared__ float red[64][17];
  const int bm = blockIdx.y*64, bn = blockIdx.x*64;
  const int tid = threadIdx.x;
  const int tx = tid & 15, ty = tid >> 4;
  float acc[4][4] = {};

  #pragma unroll
  for (int k0 = 0; k0 < 256; k0 += 32) {
    {
      int r = tid >> 2, c0 = (tid & 3)*8;
      int row = bm + r; if (row > 3167) row = 3167;
      const float* ap = A + (long)row*256 + k0 + c0;
      float4 v0 = *(const float4*)ap;
      float4 v1 = *(const float4*)(ap+4);
      As[c0+0][r]=v0.x; As[c0+1][r]=v0.y; As[c0+2][r]=v0.z; As[c0+3][r]=v0.w;
      As[c0+4][r]=v1.x; As[c0+5][r]=v1.y; As[c0+6][r]=v1.z; As[c0+7][r]=v1.w;
    }
    {
      int n = tid >> 2, c0 = (tid & 3)*8;
      int col = bn + n; if (col > 29999) col = 29999;
      const float* bp = Bmat + (long)col*256 + k0 + c0;
      float4 v0 = *(const float4*)bp;
      float4 v1 = *(const float4*)(bp+4);
      Bs[c0+0][n]=v0.x; Bs[c0+1][n]=v0.y; Bs[c0+2][n]=v0.z; Bs[c0+3][n]=v0.w;
      Bs[c0+4][n]=v1.x; Bs[c0+5][n]=v1.y; Bs[c0+6][n]=v1.z; Bs[c0+7][n]=v1.w;
    }
    __syncthreads();
    #pragma unroll
    for (int kk = 0; kk < 32; ++kk) {
      float4 a = *(const float4*)&As[kk][ty*4];
      float4 b = *(const float4*)&Bs[kk][tx*4];
      acc[0][0]=fmaf(a.x,b.x,acc[0][0]); acc[0][1]=fmaf(a.x,b.y,acc[0][1]);
      acc[0][2]=fmaf(a.x,b.z,acc[0][2]); acc[0][3]=fmaf(a.x,b.w,acc[0][3]);
      acc[1][0]=fmaf(a.y,b.x,acc[1][0]); acc[1][1]=fmaf(a.y,b.y,acc[1][1]);
      acc[1][2]=fmaf(a.y,b.z,acc[1][2]); acc[1][3]=fmaf(a.y,b.w,acc[1][3]);
      acc[2][0]=fmaf(a.z,b.x,acc[2][0]); acc[2][1]=fmaf(a.z,b.y,acc[2][1]);
      acc[2][2]=fmaf(a.z,b.z,acc[2][2]); acc[2][3]=fmaf(a.z,b.w,acc[2][3]);
      acc[3][0]=fmaf(a.w,b.x,acc[3][0]); acc[3][1]=fmaf(a.w,b.y,acc[3][1]);
      acc[3][2]=fmaf(a.w,b.z,acc[3][2]); acc[3][3]=fmaf(a.w,b.w,acc[3][3]);
    }
    __syncthreads();
  }

  // bias + mask invalid cols
  float vals[4][4];
  #pragma unroll
  for (int i = 0; i < 4; ++i)
    #pragma unroll
    for (int j = 0; j < 4; ++j) {
      int col = bn + tx*4 + j;
      vals[i][j] = (col < 30000) ? (acc[i][j] + bias[col]) : -INFINITY;
    }
  // per-row (within-tile) max
  #pragma unroll
  for (int i = 0; i < 4; ++i) {
    float m = fmaxf(fmaxf(vals[i][0], vals[i][1]), fmaxf(vals[i][2], vals[i][3]));
    red[ty*4+i][tx] = m;
  }
  __syncthreads();
  if (tid < 64) {
    float m = red[tid][0];
    #pragma unroll
    for (int x = 1; x < 16; ++x) m = fmaxf(m, red[tid][x]);
    red[tid][16] = m;
  }
  __syncthreads();
  float se[4];
  #pragma unroll
  for (int i = 0; i < 4; ++i) {
    float m = red[ty*4+i][16];
    float s = 0.f;
    #pragma unroll
    for (int j = 0; j < 4; ++j) s += __expf(vals[i][j] - m);
    se[i] = s;
  }
  __syncthreads();
  #pragma unroll
  for (int i = 0; i < 4; ++i) red[ty*4+i][tx] = se[i];
  __syncthreads();
  if (tid < 64) {
    int row = bm + tid;
    if (row < 3168) {
      float s = 0.f;
      #pragma unroll
      for (int x = 0; x < 16; ++x) s += red[tid][x];
      partial[(long)row*469 + blockIdx.x] = make_float2(red[tid][16], s);
    }
  }
  // write raw logits
  #pragma unroll
  for (int i = 0; i < 4; ++i) {
    int row = bm + ty*4 + i;
    if (row >= 3168) continue;
    #pragma unroll
    for (int j = 0; j < 4; ++j) {
      int col = bn + tx*4 + j;
      if (col >= 30000) continue;
      C[(long)row*30000 + col] = vals[i][j];
    }
  }
}

// combine per-tile partials -> lse per row; one wave per row
__global__ void lse_reduce(const float2* __restrict__ partial, float* __restrict__ lse)
{
  int row  = blockIdx.x*4 + (threadIdx.x >> 6);
  int lane = threadIdx.x & 63;
  if (row >= 3168) return;
  const float2* pr = partial + (long)row*469;
  float m = -INFINITY, s = 0.f;
  for (int tl = lane; tl < 469; tl += 64) {
    float2 p = pr[tl];
    float nm = fmaxf(m, p.x);
    s = s*__expf(m - nm) + p.y*__expf(p.x - nm);
    m = nm;
  }
  #pragma unroll
  for (int off = 32; off; off >>= 1) {
    float om = __shfl_xor(m, off);
    float os = __shfl_xor(s, off);
    float nm = fmaxf(m, om);
    s = s*__expf(m - nm) + os*__expf(om - nm);
    m = nm;
  }
  if (lane == 0) lse[row] = m + __logf(s);
}

// in-place logp = logits - lse
__global__ void sub_lse(float* __restrict__ C, const float* __restrict__ lse)
{
  int row = blockIdx.x;
  float l = lse[row];
  float* p = C + (long)row*30000;
  for (int i = threadIdx.x; i < 7500; i += 256) {
    float4 v = *(float4*)(p + i*4);
    v.x -= l; v.y -= l; v.z -= l; v.w -= l;
    *(float4*)(p + i*4) = v;
  }
}

// he/ce outputs from final transposed state (parity 0, lstm 0)
__global__ void write_hc(const float* __restrict__ hT, const float* __restrict__ cT,
                         float* __restrict__ dst)
{
  int idx = blockIdx.x*256 + threadIdx.x;   // 0..16383
  int b = idx >> 9, u = idx & 511;
  dst[idx]         = hT[u*32 + b];
  dst[16384 + idx] = cT[u*32 + b];
}

// ---------------------------------------------------------------------------
extern "C" void kernel_launch(void* const* d_in, const int* in_sizes, int n_in,
                              void* d_out, int out_size, void* d_ws, size_t ws_size,
                              hipStream_t stream)
{
  const int*   input_edits = (const int*)  d_in[0];
  const int*   simp_sent   = (const int*)  d_in[1];
  const float* enc   = (const float*)d_in[3];
  const float* h0    = (const float*)d_in[4];
  const float* c0    = (const float*)d_in[5];
  const float* emb   = (const float*)d_in[6];
  const float* Wi_e  = (const float*)d_in[7];
  const float* Wh_e  = (const float*)d_in[8];
  const float* bi_e  = (const float*)d_in[9];
  const float* bh_e  = (const float*)d_in[10];
  const float* Wi_w  = (const float*)d_in[11];
  const float* Wh_w  = (const float*)d_in[12];
  const float* bi_w  = (const float*)d_in[13];
  const float* bh_w  = (const float*)d_in[14];
  const float* Wp    = (const float*)d_in[15];
  const float* Wm    = (const float*)d_in[16];
  const float* bmv   = (const float*)d_in[17];
  const float* b_out = (const float*)d_in[18];
  float* out = (float*)d_out;

  float* ws = (float*)d_ws;
  size_t off = 0;
  auto alloc = [&](size_t n){ float* p = ws + off; off += (n + 63) & ~(size_t)63; return p; };

  float* WiP_e   = alloc(2048*256);
  float* WiP_w   = alloc(2048*256);
  float* biasP_e = alloc(2048);
  float* biasP_w = alloc(2048);
  float* WhTp_e  = alloc(512*2048);
  float* WhTp_w  = alloc(512*2048);
  float* Xp_e    = alloc(3200*2048);
  float* Xp_w    = alloc(3200*2048);
  float* outT    = alloc(2*100*512*32);
  float* out_e   = alloc(3200*512);
  float* out_w   = alloc(3200*512);
  float* hT      = alloc(2*2*512*32);
  float* cT      = alloc(2*2*512*32);
  float* Pbuf    = alloc(3200*128);
  float* lse     = alloc(3168);
  int*   ctr_del = (int*)alloc(3168);
  int*   ctr_ins = (int*)alloc(3168);
  // overlays (lifetimes disjoint, stream-ordered):
  float*  key     = outT;                         // after transpose_out
  float*  applied = outT + 3200*512;
  float*  feat    = Xp_e;                         // after last lstm_step
  float*  hmlp    = Xp_w;
  float2* partial = (float2*)(Xp_w + 1048576);    // 3168*469 float2

  // 1) weight prep (gate-permuted)
  prep_permute<<<4096, 256, 0, stream>>>(Wi_e, Wh_e, bi_e, bh_e, WiP_e, WhTp_e, biasP_e);
  prep_permute<<<4096, 256, 0, stream>>>(Wi_w, Wh_w, bi_w, bh_w, WiP_w, WhTp_w, biasP_w);
  init_state<<<128, 256, 0, stream>>>(h0, c0, hT, cT);

  // 2) Xproj = emb[tok] @ WiP^T + biasP   (M=3200, N=2048, K=256)
  gemm_f32<1,1,1,0><<<dim3(32,50,1), 256, 0, stream>>>(
      emb, input_edits, WiP_e, biasP_e, Xp_e, 3200, 2048, 256, 256, 256, 2048, 0,0,0);
  gemm_f32<1,1,1,0><<<dim3(32,50,1), 256, 0, stream>>>(
      emb, simp_sent,   WiP_w, biasP_w, Xp_w, 3200, 2048, 256, 256, 256, 2048, 0,0,0);

  // 3) recurrence: 100 steps, both LSTMs per launch
  for (int t = 0; t < 100; ++t)
    lstm_step<<<dim3(32,2), 256, 0, stream>>>(WhTp_e, WhTp_w, Xp_e, Xp_w, hT, cT, outT, t);

  // he / ce outputs (final state is parity 0)
  write_hc<<<64, 256, 0, stream>>>(hT, cT, out + 95040000L);

  // 4) transpose sequences to [b][t][u]
  transpose_out<<<dim3(100,2), 256, 0, stream>>>(outT, out_e, out_w);

  // 5) key = out_e @ Wp^T  (M=3200,N=512,K=512)
  gemm_f32<0,1,0,0><<<dim3(8,50,1), 256, 0, stream>>>(
      out_e, nullptr, Wp, nullptr, key, 3200, 512, 512, 512, 512, 512, 0,0,0);

  // 6) scores (batched over b): P = key_b @ enc_b^T  (M=100,N=100,K=512, ldc=128)
  gemm_f32<0,1,0,0><<<dim3(2,2,32), 256, 0, stream>>>(
      key, nullptr, enc, nullptr, Pbuf, 100, 100, 512, 512, 512, 128,
      51200, 51200, 12800);
  softmax_rows<<<800, 256, 0, stream>>>(Pbuf);
  // applied = P @ enc  (M=100,N=512,K=100)
  gemm_f32<0,0,0,0><<<dim3(8,2,32), 256, 0, stream>>>(
      Pbuf, nullptr, enc, nullptr, applied, 100, 512, 100, 128, 512, 512,
      12800, 51200, 51200);

  // 7) counters + feat + MLP
  counters_kernel<<<1, 64, 0, stream>>>(input_edits, ctr_del, ctr_ins);
  feat_kernel<<<3168, 256, 0, stream>>>(out_e, applied, enc, out_w, ctr_del, ctr_ins, feat);
  gemm_f32<0,1,1,1><<<dim3(4,50,1), 256, 0, stream>>>(
      feat, nullptr, Wm, bmv, hmlp, 3168, 256, 2048, 2048, 2048, 256, 0,0,0);

  // 8) logits + log-softmax
  logits_partial<<<dim3(469,50), 256, 0, stream>>>(hmlp, emb, b_out, out, partial);
  lse_reduce<<<792, 256, 0, stream>>>(partial, lse);
  sub_lse<<<3168, 256, 0, stream>>>(out, lse);
}

// Round 2
// 2996.096 us; speedup vs baseline: 60.0680x; 60.0680x over previous
//
#include <hip/hip_runtime.h>
#include <math.h>

// Sizes (fixed): B=32, T=100, S=100, H=512, E=256, V=30000, 4H=2048, M_log=3168

typedef __attribute__((ext_vector_type(8))) short short8v;  // 8 bf16 (4 VGPRs)
typedef __attribute__((ext_vector_type(4))) float f32x4;

__device__ __forceinline__ float sigf(float x){ return 1.0f/(1.0f + __expf(-x)); }
__device__ __forceinline__ float tanhc(float x){
  x = fminf(fmaxf(x, -15.f), 15.f);
  float e = __expf(2.f*x);
  return (e-1.f)/(e+1.f);
}
__device__ __forceinline__ short f2bf(float f){
  unsigned u = __float_as_uint(f);
  u = (u + 0x7fffu + ((u >> 16) & 1u)) >> 16;
  return (short)u;
}

// ---------------------------------------------------------------------------
// prep: gate-permuted weights. o' = u*4 + g (source row g*512+u)
// ---------------------------------------------------------------------------
__global__ void prep_permute(const float* __restrict__ Wi, const float* __restrict__ Wh,
                             const float* __restrict__ bi, const float* __restrict__ bh,
                             float* __restrict__ WiP, float* __restrict__ WhTp,
                             float* __restrict__ biasP)
{
  int idx = blockIdx.x*256 + threadIdx.x;      // 0 .. 1048575
  {
    int k = idx >> 11, op = idx & 2047;
    int u = op >> 2, g = op & 3;
    WhTp[idx] = Wh[(g*512+u)*512 + k];
  }
  if (idx < 2048*256) {
    int op = idx >> 8, e = idx & 255;
    int u = op >> 2, g = op & 3;
    WiP[idx] = Wi[(g*512+u)*256 + e];
  }
  if (idx < 2048) {
    int u = idx >> 2, g = idx & 3;
    biasP[idx] = bi[g*512+u] + bh[g*512+u];
  }
}

__global__ void init_state(const float* __restrict__ h0, const float* __restrict__ c0,
                           float* __restrict__ hT, float* __restrict__ cT)
{
  int idx = blockIdx.x*256 + threadIdx.x;   // 0..32767 : l,u,b
  int l = idx >> 14, u = (idx >> 5) & 511, b = idx & 31;
  float hv = h0[b*512 + u];
  float cv = c0[b*512 + u];
  hT[((0*2 + l)*512 + u)*32 + b] = hv;
  cT[((0*2 + l)*512 + u)*32 + b] = cv;
}

// ---------------------------------------------------------------------------
// Generic f32 GEMM (small/medium ops only: Xproj, key, scores, applied, MLP)
// ---------------------------------------------------------------------------
template<int GATHER,int TRANSB,int BIAS,int TANH>
__global__ __launch_bounds__(256) void gemm_f32(
    const float* __restrict__ A, const int* __restrict__ tok,
    const float* __restrict__ Bmat, const float* __restrict__ bias,
    float* __restrict__ C,
    int M, int N, int K, int lda, int ldb, int ldc,
    long sA, long sB, long sC)
{
  __shared__ float As[32][68];
  __shared__ float Bs[32][68];
  const int z = blockIdx.z;
  A    += (long)z * sA;
  Bmat += (long)z * sB;
  C    += (long)z * sC;
  const int bm = blockIdx.y*64, bn = blockIdx.x*64;
  const int tid = threadIdx.x;
  const int tx = tid & 15, ty = tid >> 4;
  float acc[4][4] = {};

  for (int k0 = 0; k0 < K; k0 += 32) {
    {
      int r = tid >> 2;
      int c0 = (tid & 3) * 8;
      int row = bm + r; if (row > M-1) row = M-1;
      int arow = row;
      if (GATHER) arow = tok[row];
      const float* ap = A + (long)arow * lda;
      #pragma unroll
      for (int q = 0; q < 2; ++q) {
        int kk = c0 + q*4;
        float4 v;
        if (k0 + kk + 4 <= K) v = *(const float4*)(ap + k0 + kk);
        else {
          v.x = (k0+kk+0 < K) ? ap[k0+kk+0] : 0.f;
          v.y = (k0+kk+1 < K) ? ap[k0+kk+1] : 0.f;
          v.z = (k0+kk+2 < K) ? ap[k0+kk+2] : 0.f;
          v.w = (k0+kk+3 < K) ? ap[k0+kk+3] : 0.f;
        }
        As[kk+0][r]=v.x; As[kk+1][r]=v.y; As[kk+2][r]=v.z; As[kk+3][r]=v.w;
      }
    }
    if (TRANSB) {
      int n = tid >> 2;
      int c0 = (tid & 3) * 8;
      int col = bn + n; if (col > N-1) col = N-1;
      const float* bp = Bmat + (long)col * ldb;
      #pragma unroll
      for (int q = 0; q < 2; ++q) {
        int kk = c0 + q*4;
        float4 v;
        if (k0 + kk + 4 <= K) v = *(const float4*)(bp + k0 + kk);
        else {
          v.x = (k0+kk+0 < K) ? bp[k0+kk+0] : 0.f;
          v.y = (k0+kk+1 < K) ? bp[k0+kk+1] : 0.f;
          v.z = (k0+kk+2 < K) ? bp[k0+kk+2] : 0.f;
          v.w = (k0+kk+3 < K) ? bp[k0+kk+3] : 0.f;
        }
        Bs[kk+0][n]=v.x; Bs[kk+1][n]=v.y; Bs[kk+2][n]=v.z; Bs[kk+3][n]=v.w;
      }
    } else {
      int kk = tid >> 3;
      int c0 = (tid & 7) * 8;
      int krow = k0 + kk;
      #pragma unroll
      for (int q = 0; q < 2; ++q) {
        int cc = c0 + q*4;
        int col = bn + cc;
        float4 v = make_float4(0.f,0.f,0.f,0.f);
        if (krow < K) {
          const float* bp = Bmat + (long)krow * ldb;
          if (col + 4 <= N) v = *(const float4*)(bp + col);
          else {
            v.x = (col+0 < N) ? bp[col+0] : 0.f;
            v.y = (col+1 < N) ? bp[col+1] : 0.f;
            v.z = (col+2 < N) ? bp[col+2] : 0.f;
            v.w = (col+3 < N) ? bp[col+3] : 0.f;
          }
        }
        Bs[kk][cc+0]=v.x; Bs[kk][cc+1]=v.y; Bs[kk][cc+2]=v.z; Bs[kk][cc+3]=v.w;
      }
    }
    __syncthreads();
    #pragma unroll
    for (int kk = 0; kk < 32; ++kk) {
      float4 a = *(const float4*)&As[kk][ty*4];
      float4 b = *(const float4*)&Bs[kk][tx*4];
      acc[0][0]=fmaf(a.x,b.x,acc[0][0]); acc[0][1]=fmaf(a.x,b.y,acc[0][1]);
      acc[0][2]=fmaf(a.x,b.z,acc[0][2]); acc[0][3]=fmaf(a.x,b.w,acc[0][3]);
      acc[1][0]=fmaf(a.y,b.x,acc[1][0]); acc[1][1]=fmaf(a.y,b.y,acc[1][1]);
      acc[1][2]=fmaf(a.y,b.z,acc[1][2]); acc[1][3]=fmaf(a.y,b.w,acc[1][3]);
      acc[2][0]=fmaf(a.z,b.x,acc[2][0]); acc[2][1]=fmaf(a.z,b.y,acc[2][1]);
      acc[2][2]=fmaf(a.z,b.z,acc[2][2]); acc[2][3]=fmaf(a.z,b.w,acc[2][3]);
      acc[3][0]=fmaf(a.w,b.x,acc[3][0]); acc[3][1]=fmaf(a.w,b.y,acc[3][1]);
      acc[3][2]=fmaf(a.w,b.z,acc[3][2]); acc[3][3]=fmaf(a.w,b.w,acc[3][3]);
    }
    __syncthreads();
  }
  #pragma unroll
  for (int i = 0; i < 4; ++i) {
    int row = bm + ty*4 + i;
    if (row >= M) continue;
    #pragma unroll
    for (int j = 0; j < 4; ++j) {
      int col = bn + tx*4 + j;
      if (col >= N) continue;
      float v = acc[i][j];
      if (BIAS) v += bias[col];
      if (TANH) v = tanhc(v);
      C[(long)row*ldc + col] = v;
    }
  }
}

// ---------------------------------------------------------------------------
// One LSTM step for both LSTMs (gate-permuted o' = u*4+g)
// ---------------------------------------------------------------------------
__global__ __launch_bounds__(256) void lstm_step(
    const float* __restrict__ WhTp_e, const float* __restrict__ WhTp_w,
    const float* __restrict__ Xp_e,  const float* __restrict__ Xp_w,
    float* __restrict__ hT, float* __restrict__ cT,
    float* __restrict__ outT,   // [lstm][t][u][b]
    int t)
{
  const int l  = blockIdx.y;
  const float* WhTp = l ? WhTp_w : WhTp_e;
  const float* Xp   = l ? Xp_w   : Xp_e;
  const int ob = blockIdx.x;            // 0..31
  const int tid = threadIdx.x;
  const int bl = tid & 31, og = tid >> 5;
  const int pin = t & 1, pout = pin ^ 1;

  __shared__ float h_lds[64][36];
  __shared__ float w_lds[64][64];

  const float* hin = hT + (long)((pin*2 + l)*512)*32;
  float acc[8] = {0.f,0.f,0.f,0.f,0.f,0.f,0.f,0.f};

  for (int k0 = 0; k0 < 512; k0 += 64) {
    {
      int kk = tid >> 2;
      int c0 = (tid & 3) * 8;
      const float* hp = hin + (long)(k0+kk)*32 + c0;
      float4 v0 = *(const float4*)hp;
      float4 v1 = *(const float4*)(hp + 4);
      *(float4*)&h_lds[kk][c0]   = v0;
      *(float4*)&h_lds[kk][c0+4] = v1;
    }
    {
      int kk = tid >> 2;
      int c0 = (tid & 3) * 16;
      const float* wp = WhTp + (long)(k0+kk)*2048 + ob*64 + c0;
      float4 v0 = *(const float4*)(wp+0);
      float4 v1 = *(const float4*)(wp+4);
      float4 v2 = *(const float4*)(wp+8);
      float4 v3 = *(const float4*)(wp+12);
      *(float4*)&w_lds[kk][c0+0]  = v0;
      *(float4*)&w_lds[kk][c0+4]  = v1;
      *(float4*)&w_lds[kk][c0+8]  = v2;
      *(float4*)&w_lds[kk][c0+12] = v3;
    }
    __syncthreads();
    #pragma unroll 8
    for (int kk = 0; kk < 64; ++kk) {
      float hv = h_lds[kk][bl];
      const float* wr = &w_lds[kk][og*8];
      float4 w0 = *(const float4*)wr;
      float4 w1 = *(const float4*)(wr+4);
      acc[0]=fmaf(hv,w0.x,acc[0]); acc[1]=fmaf(hv,w0.y,acc[1]);
      acc[2]=fmaf(hv,w0.z,acc[2]); acc[3]=fmaf(hv,w0.w,acc[3]);
      acc[4]=fmaf(hv,w1.x,acc[4]); acc[5]=fmaf(hv,w1.y,acc[5]);
      acc[6]=fmaf(hv,w1.z,acc[6]); acc[7]=fmaf(hv,w1.w,acc[7]);
    }
    __syncthreads();
  }

  const float* xp = Xp + ((long)(bl*100 + t))*2048 + ob*64 + og*8;
  float4 x0 = *(const float4*)xp;
  float4 x1 = *(const float4*)(xp+4);
  float g[8] = { acc[0]+x0.x, acc[1]+x0.y, acc[2]+x0.z, acc[3]+x0.w,
                 acc[4]+x1.x, acc[5]+x1.y, acc[6]+x1.z, acc[7]+x1.w };

  float* cin  = cT + (long)((pin*2 + l)*512)*32;
  float* cout = cT + (long)((pout*2 + l)*512)*32;
  float* hout = hT + (long)((pout*2 + l)*512)*32;
  float* oseq = outT + (long)((l*100 + t)*512)*32;

  #pragma unroll
  for (int uu = 0; uu < 2; ++uu) {
    int u = ob*16 + og*2 + uu;
    float ii = sigf(g[uu*4+0]);
    float ff = sigf(g[uu*4+1]);
    float gt = tanhc(g[uu*4+2]);
    float oo = sigf(g[uu*4+3]);
    float cprev = cin[u*32 + bl];
    float cnew = ff*cprev + ii*gt;
    float hnew = oo*tanhc(cnew);
    cout[u*32 + bl] = cnew;
    hout[u*32 + bl] = hnew;
    oseq[u*32 + bl] = hnew;
  }
}

// transpose out sequences [lstm][t][u][b] -> [b][t][u]
__global__ __launch_bounds__(256) void transpose_out(
    const float* __restrict__ outT, float* __restrict__ out_e, float* __restrict__ out_w)
{
  __shared__ float tile[512][33];
  const int t = blockIdx.x, l = blockIdx.y;
  const float* src = outT + (long)((l*100 + t))*512*32;
  const int tid = threadIdx.x;
  #pragma unroll
  for (int i = 0; i < 16; ++i) {
    int fi = tid + 256*i;
    int u = fi >> 3, b4 = (fi & 7) * 4;
    float4 v = *(const float4*)(src + (long)fi*4);
    tile[u][b4+0]=v.x; tile[u][b4+1]=v.y; tile[u][b4+2]=v.z; tile[u][b4+3]=v.w;
  }
  __syncthreads();
  float* dst = l ? out_w : out_e;
  for (int b = 0; b < 32; ++b) {
    float* drow = dst + (long)(b*100 + t)*512;
    drow[tid]       = tile[tid][b];
    drow[tid+256]   = tile[tid+256][b];
  }
}

__global__ void softmax_rows(float* __restrict__ P)
{
  int row  = blockIdx.x*4 + (threadIdx.x >> 6);
  int lane = threadIdx.x & 63;
  float* p = P + (long)row*128;
  float x0 = (lane      < 100) ? p[lane]    : -INFINITY;
  float x1 = (lane + 64 < 100) ? p[lane+64] : -INFINITY;
  float m = fmaxf(x0, x1);
  #pragma unroll
  for (int off = 32; off; off >>= 1) m = fmaxf(m, __shfl_xor(m, off));
  float e0 = (lane      < 100) ? __expf(x0 - m) : 0.f;
  float e1 = (lane + 64 < 100) ? __expf(x1 - m) : 0.f;
  float s = e0 + e1;
  #pragma unroll
  for (int off = 32; off; off >>= 1) s += __shfl_xor(s, off);
  float inv = 1.f / s;
  if (lane      < 100) p[lane]    = e0 * inv;
  if (lane + 64 < 100) p[lane+64] = e1 * inv;
}

__global__ void counters_kernel(const int* __restrict__ ie,
                                int* __restrict__ ctr_del, int* __restrict__ ctr_ins)
{
  int b = threadIdx.x;
  if (b >= 32) return;
  int rd = 0, ri = 0;
  for (int t = 0; t < 99; ++t) {
    int a = ie[b*100 + t + 1];
    int incd = (a == 2 || a == 3) ? 1 : 0;
    int inci = (a != 3 && a != 5 && a != 0) ? 1 : 0;
    ctr_del[b*99 + t] = min(rd, 99);
    ctr_ins[b*99 + t] = min(ri, 99);
    rd += incd; ri += inci;
  }
}

__global__ void feat_kernel(const float* __restrict__ out_e, const float* __restrict__ applied,
                            const float* __restrict__ enc,  const float* __restrict__ out_w,
                            const int* __restrict__ ctr_del, const int* __restrict__ ctr_ins,
                            float* __restrict__ feat)
{
  int n = blockIdx.x;                 // 0..3167
  int b = n / 99, t = n % 99;
  const float* s0 = out_e  + (long)(b*100 + t)*512;
  const float* s1 = applied+ (long)(b*100 + t)*512;
  const float* s2 = enc    + (long)(b*100 + ctr_del[n])*512;
  const float* s3 = out_w  + (long)(b*100 + ctr_ins[n])*512;
  float* d = feat + (long)n*2048;
  int tid = threadIdx.x;
  #pragma unroll
  for (int q = 0; q < 2; ++q) {
    int slot = tid + 256*q;
    int seg = slot >> 7;
    int off = (slot & 127) * 4;
    const float* s = (seg==0) ? s0 : (seg==1) ? s1 : (seg==2) ? s2 : s3;
    *(float4*)(d + seg*512 + off) = *(const float4*)(s + off);
  }
}

// f32 -> bf16 (RNE), n4 float4-groups
__global__ void conv_bf16(const float* __restrict__ src, short* __restrict__ dst, int n4)
{
  int i = blockIdx.x*256 + threadIdx.x;
  if (i >= n4) return;
  float4 v = *(const float4*)(src + (long)i*4);
  short4 o;
  o.x = f2bf(v.x); o.y = f2bf(v.y); o.z = f2bf(v.z); o.w = f2bf(v.w);
  *(short4*)(dst + (long)i*4) = o;
}

// ---------------------------------------------------------------------------
// logits GEMM (bf16 MFMA): C[3168][30000] = hmlp_bf16 @ emb_bf16^T + b_out
// 128x128 tile, BK=64, 4 waves (2x2), 16x16x32 MFMA, padded LDS (bank-clean).
// grid (25 row-tiles, 235 col-tiles) — row-tiles fast => emb panel L2 reuse.
// ---------------------------------------------------------------------------
__global__ __launch_bounds__(256) void logits_mfma(
    const short* __restrict__ Ah,   // [3168][256] bf16 (row-clamped)
    const short* __restrict__ Bh,   // [30000][256] bf16
    const float* __restrict__ bias, // [30000]
    float* __restrict__ C)          // [3168][30000] f32
{
  __shared__ short As[128][72];     // 64 + 8 pad (16B) per row
  __shared__ short Bs[128][72];
  const int bm = blockIdx.x * 128;
  const int bn = blockIdx.y * 128;
  const int tid = threadIdx.x;
  const int w = tid >> 6, l = tid & 63;
  const int wr = (w >> 1) * 64, wc = (w & 1) * 64;
  const int lr = l & 15, kg = l >> 4;

  f32x4 acc[4][4] = {};

  for (int k0 = 0; k0 < 256; k0 += 64) {
    #pragma unroll
    for (int q = 0; q < 4; ++q) {
      int ci = tid + 256*q;          // 0..1023
      int r = ci >> 3, ch = ci & 7;
      int ar = bm + r; if (ar > 3167) ar = 3167;
      int br = bn + r; if (br > 29999) br = 29999;
      *(short8v*)&As[r][ch*8] = *(const short8v*)(Ah + (long)ar*256 + k0 + ch*8);
      *(short8v*)&Bs[r][ch*8] = *(const short8v*)(Bh + (long)br*256 + k0 + ch*8);
    }
    __syncthreads();
    #pragma unroll
    for (int ks = 0; ks < 2; ++ks) {
      short8v a[4], b[4];
      #pragma unroll
      for (int m = 0; m < 4; ++m)
        a[m] = *(const short8v*)&As[wr + m*16 + lr][ks*32 + kg*8];
      #pragma unroll
      for (int n = 0; n < 4; ++n)
        b[n] = *(const short8v*)&Bs[wc + n*16 + lr][ks*32 + kg*8];
      #pragma unroll
      for (int m = 0; m < 4; ++m)
        #pragma unroll
        for (int n = 0; n < 4; ++n)
          acc[m][n] = __builtin_amdgcn_mfma_f32_16x16x32_bf16(a[m], b[n], acc[m][n], 0, 0, 0);
    }
    __syncthreads();
  }

  // epilogue: C/D layout col=lane&15, row=(lane>>4)*4+reg  [m89 verified]
  #pragma unroll
  for (int n = 0; n < 4; ++n) {
    int col = bn + wc + n*16 + lr;
    bool cok = (col < 30000);
    float bv = cok ? bias[col] : 0.f;
    #pragma unroll
    for (int m = 0; m < 4; ++m) {
      int row0 = bm + wr + m*16 + kg*4;
      #pragma unroll
      for (int r = 0; r < 4; ++r) {
        int row = row0 + r;
        if (cok && row < 3168)
          C[(long)row*30000 + col] = acc[m][n][r] + bv;
      }
    }
  }
}

// per-row LSE over 30000 cols of C, one block per row
__global__ __launch_bounds__(256) void lse_rows(const float* __restrict__ C,
                                                float* __restrict__ lse)
{
  int row = blockIdx.x;
  const float* p = C + (long)row*30000;
  float m = -INFINITY, s = 0.f;
  for (int i = threadIdx.x; i < 7500; i += 256) {
    float4 v = *(const float4*)(p + (long)i*4);
    float mv = fmaxf(fmaxf(v.x, v.y), fmaxf(v.z, v.w));
    if (mv > m) { s *= __expf(m - mv); m = mv; }
    s += __expf(v.x - m) + __expf(v.y - m) + __expf(v.z - m) + __expf(v.w - m);
  }
  #pragma unroll
  for (int off = 32; off; off >>= 1) {
    float om = __shfl_xor(m, off);
    float os = __shfl_xor(s, off);
    float nm = fmaxf(m, om);
    s = s*__expf(m - nm) + os*__expf(om - nm);
    m = nm;
  }
  __shared__ float sm[4], ss[4];
  int wv = threadIdx.x >> 6;
  if ((threadIdx.x & 63) == 0) { sm[wv] = m; ss[wv] = s; }
  __syncthreads();
  if (threadIdx.x == 0) {
    float M = sm[0], S = ss[0];
    #pragma unroll
    for (int i = 1; i < 4; ++i) {
      float nm = fmaxf(M, sm[i]);
      S = S*__expf(M - nm) + ss[i]*__expf(sm[i] - nm);
      M = nm;
    }
    lse[row] = M + __logf(S);
  }
}

__global__ void sub_lse(float* __restrict__ C, const float* __restrict__ lse)
{
  int row = blockIdx.x;
  float lv = lse[row];
  float* p = C + (long)row*30000;
  for (int i = threadIdx.x; i < 7500; i += 256) {
    float4 v = *(float4*)(p + (long)i*4);
    v.x -= lv; v.y -= lv; v.z -= lv; v.w -= lv;
    *(float4*)(p + (long)i*4) = v;
  }
}

__global__ void write_hc(const float* __restrict__ hT, const float* __restrict__ cT,
                         float* __restrict__ dst)
{
  int idx = blockIdx.x*256 + threadIdx.x;   // 0..16383
  int b = idx >> 9, u = idx & 511;
  dst[idx]         = hT[u*32 + b];
  dst[16384 + idx] = cT[u*32 + b];
}

// ---------------------------------------------------------------------------
extern "C" void kernel_launch(void* const* d_in, const int* in_sizes, int n_in,
                              void* d_out, int out_size, void* d_ws, size_t ws_size,
                              hipStream_t stream)
{
  const int*   input_edits = (const int*)  d_in[0];
  const int*   simp_sent   = (const int*)  d_in[1];
  const float* enc   = (const float*)d_in[3];
  const float* h0    = (const float*)d_in[4];
  const float* c0    = (const float*)d_in[5];
  const float* emb   = (const float*)d_in[6];
  const float* Wi_e  = (const float*)d_in[7];
  const float* Wh_e  = (const float*)d_in[8];
  const float* bi_e  = (const float*)d_in[9];
  const float* bh_e  = (const float*)d_in[10];
  const float* Wi_w  = (const float*)d_in[11];
  const float* Wh_w  = (const float*)d_in[12];
  const float* bi_w  = (const float*)d_in[13];
  const float* bh_w  = (const float*)d_in[14];
  const float* Wp    = (const float*)d_in[15];
  const float* Wm    = (const float*)d_in[16];
  const float* bmv   = (const float*)d_in[17];
  const float* b_out = (const float*)d_in[18];
  float* out = (float*)d_out;

  float* ws = (float*)d_ws;
  size_t off = 0;
  auto alloc = [&](size_t n){ float* p = ws + off; off += (n + 63) & ~(size_t)63; return p; };

  float* WiP_e   = alloc(2048*256);
  float* WiP_w   = alloc(2048*256);
  float* biasP_e = alloc(2048);
  float* biasP_w = alloc(2048);
  float* WhTp_e  = alloc(512*2048);
  float* WhTp_w  = alloc(512*2048);
  float* Xp_e    = alloc(3200*2048);
  float* Xp_w    = alloc(3200*2048);
  float* outT    = alloc(2*100*512*32);
  float* out_e   = alloc(3200*512);
  float* out_w   = alloc(3200*512);
  float* hT      = alloc(2*2*512*32);
  float* cT      = alloc(2*2*512*32);
  float* Pbuf    = alloc(3200*128);
  float* lse     = alloc(3168);
  int*   ctr_del = (int*)alloc(3168);
  int*   ctr_ins = (int*)alloc(3168);
  // overlays (lifetimes disjoint, stream-ordered):
  float*  key     = outT;                      // after transpose_out
  float*  applied = outT + 3200*512;
  float*  feat    = Xp_e;                      // after last lstm_step
  float*  hmlp    = Xp_w;                      // after MLP gemm
  short*  hmlph   = (short*)(Xp_w + 1048576);  // bf16 hmlp (405504 float-slots)
  short*  embh    = (short*)Xp_e;              // bf16 emb, overlays feat after MLP

  // 1) weight prep
  prep_permute<<<4096, 256, 0, stream>>>(Wi_e, Wh_e, bi_e, bh_e, WiP_e, WhTp_e, biasP_e);
  prep_permute<<<4096, 256, 0, stream>>>(Wi_w, Wh_w, bi_w, bh_w, WiP_w, WhTp_w, biasP_w);
  init_state<<<128, 256, 0, stream>>>(h0, c0, hT, cT);

  // 2) Xproj = emb[tok] @ WiP^T + biasP
  gemm_f32<1,1,1,0><<<dim3(32,50,1), 256, 0, stream>>>(
      emb, input_edits, WiP_e, biasP_e, Xp_e, 3200, 2048, 256, 256, 256, 2048, 0,0,0);
  gemm_f32<1,1,1,0><<<dim3(32,50,1), 256, 0, stream>>>(
      emb, simp_sent,   WiP_w, biasP_w, Xp_w, 3200, 2048, 256, 256, 256, 2048, 0,0,0);

  // 3) recurrence
  for (int t = 0; t < 100; ++t)
    lstm_step<<<dim3(32,2), 256, 0, stream>>>(WhTp_e, WhTp_w, Xp_e, Xp_w, hT, cT, outT, t);

  write_hc<<<64, 256, 0, stream>>>(hT, cT, out + 95040000L);

  // 4) transpose sequences
  transpose_out<<<dim3(100,2), 256, 0, stream>>>(outT, out_e, out_w);

  // 5) key = out_e @ Wp^T
  gemm_f32<0,1,0,0><<<dim3(8,50,1), 256, 0, stream>>>(
      out_e, nullptr, Wp, nullptr, key, 3200, 512, 512, 512, 512, 512, 0,0,0);

  // 6) attention
  gemm_f32<0,1,0,0><<<dim3(2,2,32), 256, 0, stream>>>(
      key, nullptr, enc, nullptr, Pbuf, 100, 100, 512, 512, 512, 128,
      51200, 51200, 12800);
  softmax_rows<<<800, 256, 0, stream>>>(Pbuf);
  gemm_f32<0,0,0,0><<<dim3(8,2,32), 256, 0, stream>>>(
      Pbuf, nullptr, enc, nullptr, applied, 100, 512, 100, 128, 512, 512,
      12800, 51200, 51200);

  // 7) counters + feat + MLP
  counters_kernel<<<1, 64, 0, stream>>>(input_edits, ctr_del, ctr_ins);
  feat_kernel<<<3168, 256, 0, stream>>>(out_e, applied, enc, out_w, ctr_del, ctr_ins, feat);
  gemm_f32<0,1,1,1><<<dim3(4,50,1), 256, 0, stream>>>(
      feat, nullptr, Wm, bmv, hmlp, 3168, 256, 2048, 2048, 2048, 256, 0,0,0);

  // 8) bf16 converts (feat/Xp_e is dead now -> embh overlay is safe)
  conv_bf16<<<792,  256, 0, stream>>>(hmlp, hmlph, 3168*256/4);
  conv_bf16<<<7500, 256, 0, stream>>>(emb,  embh,  30000*256/4);

  // 9) logits (MFMA) + log-softmax
  logits_mfma<<<dim3(25, 235), 256, 0, stream>>>(hmlph, embh, b_out, out);
  lse_rows<<<3168, 256, 0, stream>>>(out, lse);
  sub_lse<<<3168, 256, 0, stream>>>(out, lse);
}

// Round 3
// 2797.834 us; speedup vs baseline: 64.3245x; 1.0709x over previous
//
#include <hip/hip_runtime.h>
#include <math.h>

// Sizes (fixed): B=32, T=100, S=100, H=512, E=256, V=30000, 4H=2048, M_log=3168

typedef __attribute__((ext_vector_type(8))) short short8v;  // 8 bf16 (4 VGPRs)
typedef __attribute__((ext_vector_type(4))) float f32x4;

__device__ __forceinline__ float sigf(float x){ return 1.0f/(1.0f + __expf(-x)); }
__device__ __forceinline__ float tanhc(float x){
  x = fminf(fmaxf(x, -15.f), 15.f);
  float e = __expf(2.f*x);
  return (e-1.f)/(e+1.f);
}
__device__ __forceinline__ short f2bf(float f){
  unsigned u = __float_as_uint(f);
  u = (u + 0x7fffu + ((u >> 16) & 1u)) >> 16;
  return (short)u;
}

// ---------------------------------------------------------------------------
// prep: gate-permuted weights. o' = u*4 + g (source row g*512+u)
// WiPh bf16 (for MFMA Xproj), WhTp f32 (for f32 recurrence), biasP f32.
// ---------------------------------------------------------------------------
__global__ void prep_permute(const float* __restrict__ Wi, const float* __restrict__ Wh,
                             const float* __restrict__ bi, const float* __restrict__ bh,
                             short* __restrict__ WiPh, float* __restrict__ WhTp,
                             float* __restrict__ biasP)
{
  int idx = blockIdx.x*256 + threadIdx.x;      // 0 .. 1048575
  {
    int k = idx >> 11, op = idx & 2047;
    int u = op >> 2, g = op & 3;
    WhTp[idx] = Wh[(g*512+u)*512 + k];
  }
  if (idx < 2048*256) {
    int op = idx >> 8, e = idx & 255;
    int u = op >> 2, g = op & 3;
    WiPh[idx] = f2bf(Wi[(g*512+u)*256 + e]);
  }
  if (idx < 2048) {
    int u = idx >> 2, g = idx & 3;
    biasP[idx] = bi[g*512+u] + bh[g*512+u];
  }
}

__global__ void init_state(const float* __restrict__ h0, const float* __restrict__ c0,
                           float* __restrict__ hT, float* __restrict__ cT)
{
  int idx = blockIdx.x*256 + threadIdx.x;   // 0..32767 : l,u,b
  int l = idx >> 14, u = (idx >> 5) & 511, b = idx & 31;
  float hv = h0[b*512 + u];
  float cv = c0[b*512 + u];
  hT[((0*2 + l)*512 + u)*32 + b] = hv;
  cT[((0*2 + l)*512 + u)*32 + b] = cv;
}

// f32 -> bf16 (RNE), n4 float4-groups
__global__ void conv_bf16(const float* __restrict__ src, short* __restrict__ dst, int n4)
{
  int i = blockIdx.x*256 + threadIdx.x;
  if (i >= n4) return;
  float4 v = *(const float4*)(src + (long)i*4);
  short4 o;
  o.x = f2bf(v.x); o.y = f2bf(v.y); o.z = f2bf(v.z); o.w = f2bf(v.w);
  *(short4*)(dst + (long)i*4) = o;
}

// ---------------------------------------------------------------------------
// bf16 MFMA GEMM template: C[M,N] = act( A @ B^T + bias )
//  A: bf16 [M][lda]  (or f32 with CVT_A=1; GATHER=1 -> row m = tok[m] of A)
//  B: bf16 [N][K] row-major
//  C: f32 or bf16 (OUT_BF16), ldc
// 128x128 tile, BK=64, 4 waves (2x2), 16x16x32 MFMA, padded LDS.
// grid (M-tiles fast, N-tiles) so consecutive blocks reuse B panel in L2.
// ---------------------------------------------------------------------------
template<int GATHER,int CVT_A,int BIAS,int TANH,int OUT_BF16>
__global__ __launch_bounds__(256) void gemm_mfma(
    const void* __restrict__ Av, const int* __restrict__ tok,
    const short* __restrict__ Bh, const float* __restrict__ bias,
    void* __restrict__ Cv, int M, int N, int K, int lda, int ldc)
{
  __shared__ short As[128][72];     // 64 + 8 pad (16B) per row
  __shared__ short Bs[128][72];
  const int bm = blockIdx.x * 128;
  const int bn = blockIdx.y * 128;
  const int tid = threadIdx.x;
  const int w = tid >> 6, l = tid & 63;
  const int wr = (w >> 1) * 64, wc = (w & 1) * 64;
  const int lr = l & 15, kg = l >> 4;

  f32x4 acc[4][4] = {};

  for (int k0 = 0; k0 < K; k0 += 64) {
    #pragma unroll
    for (int q = 0; q < 4; ++q) {
      int ci = tid + 256*q;          // 0..1023
      int r = ci >> 3, ch = ci & 7;
      int ar = bm + r; if (ar > M-1) ar = M-1;
      if (GATHER) ar = tok[ar];
      if (CVT_A) {
        const float* ap = ((const float*)Av) + (long)ar*lda + k0 + ch*8;
        float4 v0 = *(const float4*)ap;
        float4 v1 = *(const float4*)(ap + 4);
        short8v s;
        s[0]=f2bf(v0.x); s[1]=f2bf(v0.y); s[2]=f2bf(v0.z); s[3]=f2bf(v0.w);
        s[4]=f2bf(v1.x); s[5]=f2bf(v1.y); s[6]=f2bf(v1.z); s[7]=f2bf(v1.w);
        *(short8v*)&As[r][ch*8] = s;
      } else {
        *(short8v*)&As[r][ch*8] =
            *(const short8v*)(((const short*)Av) + (long)ar*lda + k0 + ch*8);
      }
      int br = bn + r; if (br > N-1) br = N-1;
      *(short8v*)&Bs[r][ch*8] = *(const short8v*)(Bh + (long)br*K + k0 + ch*8);
    }
    __syncthreads();
    #pragma unroll
    for (int ks = 0; ks < 2; ++ks) {
      short8v a[4], b[4];
      #pragma unroll
      for (int m = 0; m < 4; ++m)
        a[m] = *(const short8v*)&As[wr + m*16 + lr][ks*32 + kg*8];
      #pragma unroll
      for (int n = 0; n < 4; ++n)
        b[n] = *(const short8v*)&Bs[wc + n*16 + lr][ks*32 + kg*8];
      #pragma unroll
      for (int m = 0; m < 4; ++m)
        #pragma unroll
        for (int n = 0; n < 4; ++n)
          acc[m][n] = __builtin_amdgcn_mfma_f32_16x16x32_bf16(a[m], b[n], acc[m][n], 0, 0, 0);
    }
    __syncthreads();
  }

  // epilogue: C/D layout col=lane&15, row=(lane>>4)*4+reg  [m89 verified]
  #pragma unroll
  for (int n = 0; n < 4; ++n) {
    int col = bn + wc + n*16 + lr;
    bool cok = (col < N);
    float bv = (BIAS && cok) ? bias[col] : 0.f;
    #pragma unroll
    for (int m = 0; m < 4; ++m) {
      int row0 = bm + wr + m*16 + kg*4;
      #pragma unroll
      for (int r = 0; r < 4; ++r) {
        int row = row0 + r;
        if (cok && row < M) {
          float v = acc[m][n][r] + bv;
          if (TANH) v = tanhc(v);
          if (OUT_BF16) ((short*)Cv)[(long)row*ldc + col] = f2bf(v);
          else          ((float*)Cv)[(long)row*ldc + col] = v;
        }
      }
    }
  }
}

// ---------------------------------------------------------------------------
// Generic f32 GEMM (attention scores / applied only)
// ---------------------------------------------------------------------------
template<int TRANSB>
__global__ __launch_bounds__(256) void gemm_f32(
    const float* __restrict__ A, const float* __restrict__ Bmat,
    float* __restrict__ C,
    int M, int N, int K, int lda, int ldb, int ldc,
    long sA, long sB, long sC)
{
  __shared__ float As[32][68];
  __shared__ float Bs[32][68];
  const int z = blockIdx.z;
  A    += (long)z * sA;
  Bmat += (long)z * sB;
  C    += (long)z * sC;
  const int bm = blockIdx.y*64, bn = blockIdx.x*64;
  const int tid = threadIdx.x;
  const int tx = tid & 15, ty = tid >> 4;
  float acc[4][4] = {};

  for (int k0 = 0; k0 < K; k0 += 32) {
    {
      int r = tid >> 2;
      int c0 = (tid & 3) * 8;
      int row = bm + r; if (row > M-1) row = M-1;
      const float* ap = A + (long)row * lda;
      #pragma unroll
      for (int q = 0; q < 2; ++q) {
        int kk = c0 + q*4;
        float4 v;
        if (k0 + kk + 4 <= K) v = *(const float4*)(ap + k0 + kk);
        else {
          v.x = (k0+kk+0 < K) ? ap[k0+kk+0] : 0.f;
          v.y = (k0+kk+1 < K) ? ap[k0+kk+1] : 0.f;
          v.z = (k0+kk+2 < K) ? ap[k0+kk+2] : 0.f;
          v.w = (k0+kk+3 < K) ? ap[k0+kk+3] : 0.f;
        }
        As[kk+0][r]=v.x; As[kk+1][r]=v.y; As[kk+2][r]=v.z; As[kk+3][r]=v.w;
      }
    }
    if (TRANSB) {
      int n = tid >> 2;
      int c0 = (tid & 3) * 8;
      int col = bn + n; if (col > N-1) col = N-1;
      const float* bp = Bmat + (long)col * ldb;
      #pragma unroll
      for (int q = 0; q < 2; ++q) {
        int kk = c0 + q*4;
        float4 v;
        if (k0 + kk + 4 <= K) v = *(const float4*)(bp + k0 + kk);
        else {
          v.x = (k0+kk+0 < K) ? bp[k0+kk+0] : 0.f;
          v.y = (k0+kk+1 < K) ? bp[k0+kk+1] : 0.f;
          v.z = (k0+kk+2 < K) ? bp[k0+kk+2] : 0.f;
          v.w = (k0+kk+3 < K) ? bp[k0+kk+3] : 0.f;
        }
        Bs[kk+0][n]=v.x; Bs[kk+1][n]=v.y; Bs[kk+2][n]=v.z; Bs[kk+3][n]=v.w;
      }
    } else {
      int kk = tid >> 3;
      int c0 = (tid & 7) * 8;
      int krow = k0 + kk;
      #pragma unroll
      for (int q = 0; q < 2; ++q) {
        int cc = c0 + q*4;
        int col = bn + cc;
        float4 v = make_float4(0.f,0.f,0.f,0.f);
        if (krow < K) {
          const float* bp = Bmat + (long)krow * ldb;
          if (col + 4 <= N) v = *(const float4*)(bp + col);
          else {
            v.x = (col+0 < N) ? bp[col+0] : 0.f;
            v.y = (col+1 < N) ? bp[col+1] : 0.f;
            v.z = (col+2 < N) ? bp[col+2] : 0.f;
            v.w = (col+3 < N) ? bp[col+3] : 0.f;
          }
        }
        Bs[kk][cc+0]=v.x; Bs[kk][cc+1]=v.y; Bs[kk][cc+2]=v.z; Bs[kk][cc+3]=v.w;
      }
    }
    __syncthreads();
    #pragma unroll
    for (int kk = 0; kk < 32; ++kk) {
      float4 a = *(const float4*)&As[kk][ty*4];
      float4 b = *(const float4*)&Bs[kk][tx*4];
      acc[0][0]=fmaf(a.x,b.x,acc[0][0]); acc[0][1]=fmaf(a.x,b.y,acc[0][1]);
      acc[0][2]=fmaf(a.x,b.z,acc[0][2]); acc[0][3]=fmaf(a.x,b.w,acc[0][3]);
      acc[1][0]=fmaf(a.y,b.x,acc[1][0]); acc[1][1]=fmaf(a.y,b.y,acc[1][1]);
      acc[1][2]=fmaf(a.y,b.z,acc[1][2]); acc[1][3]=fmaf(a.y,b.w,acc[1][3]);
      acc[2][0]=fmaf(a.z,b.x,acc[2][0]); acc[2][1]=fmaf(a.z,b.y,acc[2][1]);
      acc[2][2]=fmaf(a.z,b.z,acc[2][2]); acc[2][3]=fmaf(a.z,b.w,acc[2][3]);
      acc[3][0]=fmaf(a.w,b.x,acc[3][0]); acc[3][1]=fmaf(a.w,b.y,acc[3][1]);
      acc[3][2]=fmaf(a.w,b.z,acc[3][2]); acc[3][3]=fmaf(a.w,b.w,acc[3][3]);
    }
    __syncthreads();
  }
  #pragma unroll
  for (int i = 0; i < 4; ++i) {
    int row = bm + ty*4 + i;
    if (row >= M) continue;
    #pragma unroll
    for (int j = 0; j < 4; ++j) {
      int col = bn + tx*4 + j;
      if (col >= N) continue;
      C[(long)row*ldc + col] = acc[i][j];
    }
  }
}

// ---------------------------------------------------------------------------
// One LSTM step for both LSTMs (gate-permuted o' = u*4+g), f32
// ---------------------------------------------------------------------------
__global__ __launch_bounds__(256) void lstm_step(
    const float* __restrict__ WhTp_e, const float* __restrict__ WhTp_w,
    const float* __restrict__ Xp_e,  const float* __restrict__ Xp_w,
    float* __restrict__ hT, float* __restrict__ cT,
    float* __restrict__ outT,   // [lstm][t][u][b]
    int t)
{
  const int l  = blockIdx.y;
  const float* WhTp = l ? WhTp_w : WhTp_e;
  const float* Xp   = l ? Xp_w   : Xp_e;
  const int ob = blockIdx.x;            // 0..31
  const int tid = threadIdx.x;
  const int bl = tid & 31, og = tid >> 5;
  const int pin = t & 1, pout = pin ^ 1;

  __shared__ float h_lds[64][36];
  __shared__ float w_lds[64][64];

  const float* hin = hT + (long)((pin*2 + l)*512)*32;
  float acc[8] = {0.f,0.f,0.f,0.f,0.f,0.f,0.f,0.f};

  for (int k0 = 0; k0 < 512; k0 += 64) {
    {
      int kk = tid >> 2;
      int c0 = (tid & 3) * 8;
      const float* hp = hin + (long)(k0+kk)*32 + c0;
      float4 v0 = *(const float4*)hp;
      float4 v1 = *(const float4*)(hp + 4);
      *(float4*)&h_lds[kk][c0]   = v0;
      *(float4*)&h_lds[kk][c0+4] = v1;
    }
    {
      int kk = tid >> 2;
      int c0 = (tid & 3) * 16;
      const float* wp = WhTp + (long)(k0+kk)*2048 + ob*64 + c0;
      float4 v0 = *(const float4*)(wp+0);
      float4 v1 = *(const float4*)(wp+4);
      float4 v2 = *(const float4*)(wp+8);
      float4 v3 = *(const float4*)(wp+12);
      *(float4*)&w_lds[kk][c0+0]  = v0;
      *(float4*)&w_lds[kk][c0+4]  = v1;
      *(float4*)&w_lds[kk][c0+8]  = v2;
      *(float4*)&w_lds[kk][c0+12] = v3;
    }
    __syncthreads();
    #pragma unroll 8
    for (int kk = 0; kk < 64; ++kk) {
      float hv = h_lds[kk][bl];
      const float* wr = &w_lds[kk][og*8];
      float4 w0 = *(const float4*)wr;
      float4 w1 = *(const float4*)(wr+4);
      acc[0]=fmaf(hv,w0.x,acc[0]); acc[1]=fmaf(hv,w0.y,acc[1]);
      acc[2]=fmaf(hv,w0.z,acc[2]); acc[3]=fmaf(hv,w0.w,acc[3]);
      acc[4]=fmaf(hv,w1.x,acc[4]); acc[5]=fmaf(hv,w1.y,acc[5]);
      acc[6]=fmaf(hv,w1.z,acc[6]); acc[7]=fmaf(hv,w1.w,acc[7]);
    }
    __syncthreads();
  }

  const float* xp = Xp + ((long)(bl*100 + t))*2048 + ob*64 + og*8;
  float4 x0 = *(const float4*)xp;
  float4 x1 = *(const float4*)(xp+4);
  float g[8] = { acc[0]+x0.x, acc[1]+x0.y, acc[2]+x0.z, acc[3]+x0.w,
                 acc[4]+x1.x, acc[5]+x1.y, acc[6]+x1.z, acc[7]+x1.w };

  float* cin  = cT + (long)((pin*2 + l)*512)*32;
  float* cout = cT + (long)((pout*2 + l)*512)*32;
  float* hout = hT + (long)((pout*2 + l)*512)*32;
  float* oseq = outT + (long)((l*100 + t)*512)*32;

  #pragma unroll
  for (int uu = 0; uu < 2; ++uu) {
    int u = ob*16 + og*2 + uu;
    float ii = sigf(g[uu*4+0]);
    float ff = sigf(g[uu*4+1]);
    float gt = tanhc(g[uu*4+2]);
    float oo = sigf(g[uu*4+3]);
    float cprev = cin[u*32 + bl];
    float cnew = ff*cprev + ii*gt;
    float hnew = oo*tanhc(cnew);
    cout[u*32 + bl] = cnew;
    hout[u*32 + bl] = hnew;
    oseq[u*32 + bl] = hnew;
  }
}

// transpose out sequences [lstm][t][u][b] -> bf16 [b][t][u]
__global__ __launch_bounds__(256) void transpose_out(
    const float* __restrict__ outT, short* __restrict__ out_e, short* __restrict__ out_w)
{
  __shared__ float tile[512][33];
  const int t = blockIdx.x, l = blockIdx.y;
  const float* src = outT + (long)((l*100 + t))*512*32;
  const int tid = threadIdx.x;
  #pragma unroll
  for (int i = 0; i < 16; ++i) {
    int fi = tid + 256*i;
    int u = fi >> 3, b4 = (fi & 7) * 4;
    float4 v = *(const float4*)(src + (long)fi*4);
    tile[u][b4+0]=v.x; tile[u][b4+1]=v.y; tile[u][b4+2]=v.z; tile[u][b4+3]=v.w;
  }
  __syncthreads();
  short* dst = l ? out_w : out_e;
  for (int b = 0; b < 32; ++b) {
    short* drow = dst + (long)(b*100 + t)*512;
    drow[tid]       = f2bf(tile[tid][b]);
    drow[tid+256]   = f2bf(tile[tid+256][b]);
  }
}

__global__ void softmax_rows(float* __restrict__ P)
{
  int row  = blockIdx.x*4 + (threadIdx.x >> 6);
  int lane = threadIdx.x & 63;
  float* p = P + (long)row*128;
  float x0 = (lane      < 100) ? p[lane]    : -INFINITY;
  float x1 = (lane + 64 < 100) ? p[lane+64] : -INFINITY;
  float m = fmaxf(x0, x1);
  #pragma unroll
  for (int off = 32; off; off >>= 1) m = fmaxf(m, __shfl_xor(m, off));
  float e0 = (lane      < 100) ? __expf(x0 - m) : 0.f;
  float e1 = (lane + 64 < 100) ? __expf(x1 - m) : 0.f;
  float s = e0 + e1;
  #pragma unroll
  for (int off = 32; off; off >>= 1) s += __shfl_xor(s, off);
  float inv = 1.f / s;
  if (lane      < 100) p[lane]    = e0 * inv;
  if (lane + 64 < 100) p[lane+64] = e1 * inv;
}

__global__ void counters_kernel(const int* __restrict__ ie,
                                int* __restrict__ ctr_del, int* __restrict__ ctr_ins)
{
  int b = threadIdx.x;
  if (b >= 32) return;
  int rd = 0, ri = 0;
  for (int t = 0; t < 99; ++t) {
    int a = ie[b*100 + t + 1];
    int incd = (a == 2 || a == 3) ? 1 : 0;
    int inci = (a != 3 && a != 5 && a != 0) ? 1 : 0;
    ctr_del[b*99 + t] = min(rd, 99);
    ctr_ins[b*99 + t] = min(ri, 99);
    rd += incd; ri += inci;
  }
}

// build bf16 feat rows [3168][2048] = [out_e | applied | enc[ctr_del] | out_w[ctr_ins]]
__global__ void feat_kernel(const short* __restrict__ out_e, const float* __restrict__ applied,
                            const float* __restrict__ enc,  const short* __restrict__ out_w,
                            const int* __restrict__ ctr_del, const int* __restrict__ ctr_ins,
                            short* __restrict__ feat)
{
  int n = blockIdx.x;                 // 0..3167
  int b = n / 99, t = n % 99;
  int tid = threadIdx.x;
  int seg = tid >> 6;                 // 0..3 (512-col segments)
  int off = (tid & 63) * 8;
  short8v v;
  if (seg == 0) {
    v = *(const short8v*)(out_e + (long)(b*100 + t)*512 + off);
  } else if (seg == 3) {
    v = *(const short8v*)(out_w + (long)(b*100 + ctr_ins[n])*512 + off);
  } else {
    const float* s = (seg == 1) ? applied + (long)(b*100 + t)*512
                                : enc     + (long)(b*100 + ctr_del[n])*512;
    float4 v0 = *(const float4*)(s + off);
    float4 v1 = *(const float4*)(s + off + 4);
    v[0]=f2bf(v0.x); v[1]=f2bf(v0.y); v[2]=f2bf(v0.z); v[3]=f2bf(v0.w);
    v[4]=f2bf(v1.x); v[5]=f2bf(v1.y); v[6]=f2bf(v1.z); v[7]=f2bf(v1.w);
  }
  *(short8v*)(feat + (long)n*2048 + seg*512 + off) = v;
}

// per-row LSE over 30000 cols of C, one block per row
__global__ __launch_bounds__(256) void lse_rows(const float* __restrict__ C,
                                                float* __restrict__ lse)
{
  int row = blockIdx.x;
  const float* p = C + (long)row*30000;
  float m = -INFINITY, s = 0.f;
  for (int i = threadIdx.x; i < 7500; i += 256) {
    float4 v = *(const float4*)(p + (long)i*4);
    float mv = fmaxf(fmaxf(v.x, v.y), fmaxf(v.z, v.w));
    if (mv > m) { s *= __expf(m - mv); m = mv; }
    s += __expf(v.x - m) + __expf(v.y - m) + __expf(v.z - m) + __expf(v.w - m);
  }
  #pragma unroll
  for (int off = 32; off; off >>= 1) {
    float om = __shfl_xor(m, off);
    float os = __shfl_xor(s, off);
    float nm = fmaxf(m, om);
    s = s*__expf(m - nm) + os*__expf(om - nm);
    m = nm;
  }
  __shared__ float sm[4], ss[4];
  int wv = threadIdx.x >> 6;
  if ((threadIdx.x & 63) == 0) { sm[wv] = m; ss[wv] = s; }
  __syncthreads();
  if (threadIdx.x == 0) {
    float M = sm[0], S = ss[0];
    #pragma unroll
    for (int i = 1; i < 4; ++i) {
      float nm = fmaxf(M, sm[i]);
      S = S*__expf(M - nm) + ss[i]*__expf(sm[i] - nm);
      M = nm;
    }
    lse[row] = M + __logf(S);
  }
}

__global__ void sub_lse(float* __restrict__ C, const float* __restrict__ lse)
{
  int row = blockIdx.x;
  float lv = lse[row];
  float* p = C + (long)row*30000;
  for (int i = threadIdx.x; i < 7500; i += 256) {
    float4 v = *(float4*)(p + (long)i*4);
    v.x -= lv; v.y -= lv; v.z -= lv; v.w -= lv;
    *(float4*)(p + (long)i*4) = v;
  }
}

__global__ void write_hc(const float* __restrict__ hT, const float* __restrict__ cT,
                         float* __restrict__ dst)
{
  int idx = blockIdx.x*256 + threadIdx.x;   // 0..16383
  int b = idx >> 9, u = idx & 511;
  dst[idx]         = hT[u*32 + b];
  dst[16384 + idx] = cT[u*32 + b];
}

// ---------------------------------------------------------------------------
extern "C" void kernel_launch(void* const* d_in, const int* in_sizes, int n_in,
                              void* d_out, int out_size, void* d_ws, size_t ws_size,
                              hipStream_t stream)
{
  const int*   input_edits = (const int*)  d_in[0];
  const int*   simp_sent   = (const int*)  d_in[1];
  const float* enc   = (const float*)d_in[3];
  const float* h0    = (const float*)d_in[4];
  const float* c0    = (const float*)d_in[5];
  const float* emb   = (const float*)d_in[6];
  const float* Wi_e  = (const float*)d_in[7];
  const float* Wh_e  = (const float*)d_in[8];
  const float* bi_e  = (const float*)d_in[9];
  const float* bh_e  = (const float*)d_in[10];
  const float* Wi_w  = (const float*)d_in[11];
  const float* Wh_w  = (const float*)d_in[12];
  const float* bi_w  = (const float*)d_in[13];
  const float* bh_w  = (const float*)d_in[14];
  const float* Wp    = (const float*)d_in[15];
  const float* Wm    = (const float*)d_in[16];
  const float* bmv   = (const float*)d_in[17];
  const float* b_out = (const float*)d_in[18];
  float* out = (float*)d_out;

  float* ws = (float*)d_ws;
  size_t off = 0;
  auto alloc = [&](size_t n){ float* p = ws + off; off += (n + 63) & ~(size_t)63; return p; };

  short* WiPh_e  = (short*)alloc(262144);   // 2048*256 bf16
  short* WiPh_w  = (short*)alloc(262144);
  float* biasP_e = alloc(2048);
  float* biasP_w = alloc(2048);
  float* WhTp_e  = alloc(512*2048);
  float* WhTp_w  = alloc(512*2048);
  float* Xp_e    = alloc(3200*2048);
  float* Xp_w    = alloc(3200*2048);
  float* outT    = alloc(2*100*512*32);
  short* out_e   = (short*)alloc(819200);   // 3200*512 bf16
  short* out_w   = (short*)alloc(819200);
  float* hT      = alloc(2*2*512*32);
  float* cT      = alloc(2*2*512*32);
  float* Pbuf    = alloc(3200*128);
  float* lse     = alloc(3168);
  int*   ctr_del = (int*)alloc(3168);
  int*   ctr_ins = (int*)alloc(3168);
  short* Wph     = (short*)alloc(131072);   // 512*512 bf16
  short* Wmh     = (short*)alloc(262144);   // 256*2048 bf16
  // overlays (lifetimes disjoint, stream-ordered):
  float* key     = outT;                    // after transpose_out (1.64M <= 3.28M)
  float* applied = outT + 1638400;
  short* feath   = (short*)Xp_e;            // 3168*2048 bf16, after last lstm_step
  short* hmlph   = (short*)Xp_w;            // 3168*256 bf16, after MLP
  short* embh    = (short*)(Xp_w + 1048576);// 30000*256 bf16 (3.84M float-slots)

  // 1) weight prep + small bf16 converts
  prep_permute<<<4096, 256, 0, stream>>>(Wi_e, Wh_e, bi_e, bh_e, WiPh_e, WhTp_e, biasP_e);
  prep_permute<<<4096, 256, 0, stream>>>(Wi_w, Wh_w, bi_w, bh_w, WiPh_w, WhTp_w, biasP_w);
  init_state<<<128, 256, 0, stream>>>(h0, c0, hT, cT);
  conv_bf16<<<256, 256, 0, stream>>>(Wp, Wph, 512*512/4);
  conv_bf16<<<512, 256, 0, stream>>>(Wm, Wmh, 256*2048/4);

  // 2) Xproj = emb[tok] @ WiP^T + biasP   (MFMA, gather+cvt from f32 emb)
  gemm_mfma<1,1,1,0,0><<<dim3(25,16), 256, 0, stream>>>(
      emb, input_edits, WiPh_e, biasP_e, Xp_e, 3200, 2048, 256, 256, 2048);
  gemm_mfma<1,1,1,0,0><<<dim3(25,16), 256, 0, stream>>>(
      emb, simp_sent,   WiPh_w, biasP_w, Xp_w, 3200, 2048, 256, 256, 2048);

  // 3) recurrence (f32)
  for (int t = 0; t < 100; ++t)
    lstm_step<<<dim3(32,2), 256, 0, stream>>>(WhTp_e, WhTp_w, Xp_e, Xp_w, hT, cT, outT, t);

  write_hc<<<64, 256, 0, stream>>>(hT, cT, out + 95040000L);

  // emb -> bf16 into Xp_w overlay (Xp_w dead after recurrence)
  conv_bf16<<<7500, 256, 0, stream>>>(emb, embh, 30000*256/4);

  // 4) transpose sequences to bf16 [b][t][u]
  transpose_out<<<dim3(100,2), 256, 0, stream>>>(outT, out_e, out_w);

  // 5) key = out_e @ Wp^T  (MFMA)
  gemm_mfma<0,0,0,0,0><<<dim3(25,4), 256, 0, stream>>>(
      out_e, nullptr, Wph, nullptr, key, 3200, 512, 512, 512, 512);

  // 6) attention (f32)
  gemm_f32<1><<<dim3(2,2,32), 256, 0, stream>>>(
      key, enc, Pbuf, 100, 100, 512, 512, 512, 128, 51200, 51200, 12800);
  softmax_rows<<<800, 256, 0, stream>>>(Pbuf);
  gemm_f32<0><<<dim3(8,2,32), 256, 0, stream>>>(
      Pbuf, enc, applied, 100, 512, 100, 128, 512, 512, 12800, 51200, 51200);

  // 7) counters + feat(bf16) + MLP(MFMA, tanh, bf16 out)
  counters_kernel<<<1, 64, 0, stream>>>(input_edits, ctr_del, ctr_ins);
  feat_kernel<<<3168, 256, 0, stream>>>(out_e, applied, enc, out_w, ctr_del, ctr_ins, feath);
  gemm_mfma<0,0,1,1,1><<<dim3(25,2), 256, 0, stream>>>(
      feath, nullptr, Wmh, bmv, hmlph, 3168, 256, 2048, 2048, 256);

  // 8) logits (MFMA) + log-softmax
  gemm_mfma<0,0,1,0,0><<<dim3(25,235), 256, 0, stream>>>(
      hmlph, nullptr, embh, b_out, out, 3168, 30000, 256, 256, 30000);
  lse_rows<<<3168, 256, 0, stream>>>(out, lse);
  sub_lse<<<3168, 256, 0, stream>>>(out, lse);
}

// Round 4
// 1777.957 us; speedup vs baseline: 101.2226x; 1.5736x over previous
//
#include <hip/hip_runtime.h>
#include <math.h>

// Sizes (fixed): B=32, T=100, S=100, H=512, E=256, V=30000, 4H=2048, M_log=3168

typedef __attribute__((ext_vector_type(8))) short short8v;  // 8 bf16 (4 VGPRs)
typedef __attribute__((ext_vector_type(4))) float f32x4;

#define LSTM_BLOCKS 64

__device__ __forceinline__ float sigf(float x){ return 1.0f/(1.0f + __expf(-x)); }
__device__ __forceinline__ float tanhc(float x){
  x = fminf(fmaxf(x, -15.f), 15.f);
  float e = __expf(2.f*x);
  return (e-1.f)/(e+1.f);
}
__device__ __forceinline__ short f2bf(float f){
  unsigned u = __float_as_uint(f);
  u = (u + 0x7fffu + ((u >> 16) & 1u)) >> 16;
  return (short)u;
}

// ---------------------------------------------------------------------------
// prep: gate-permuted weights. o' = u*4 + g (source row g*512+u)
//  WiPh bf16 [2048][256]  (Xproj MFMA B-operand)
//  WhPh bf16 [2048][512]  (recurrence MFMA A-operand, [o'][k])
//  biasP f32 [2048]
// ---------------------------------------------------------------------------
__global__ void prep_permute(const float* __restrict__ Wi, const float* __restrict__ Wh,
                             const float* __restrict__ bi, const float* __restrict__ bh,
                             short* __restrict__ WiPh, short* __restrict__ WhPh,
                             float* __restrict__ biasP)
{
  int idx = blockIdx.x*256 + threadIdx.x;      // 0 .. 1048575
  {
    int op = idx >> 9, k = idx & 511;
    int u = op >> 2, g = op & 3;
    WhPh[idx] = f2bf(Wh[(g*512+u)*512 + k]);
  }
  if (idx < 2048*256) {
    int op = idx >> 8, e = idx & 255;
    int u = op >> 2, g = op & 3;
    WiPh[idx] = f2bf(Wi[(g*512+u)*256 + e]);
  }
  if (idx < 2048) {
    int u = idx >> 2, g = idx & 3;
    biasP[idx] = bi[g*512+u] + bh[g*512+u];
  }
}

// init h state (bf16, [parity0][lstm][b][u]) + zero barrier counters
__global__ void init_all(const float* __restrict__ h0, short* __restrict__ hbufT,
                         unsigned* __restrict__ bar)
{
  int idx = blockIdx.x*256 + threadIdx.x;   // 0..32767
  int b = (idx >> 9) & 31, u = idx & 511;
  hbufT[idx] = f2bf(h0[b*512 + u]);
  if (idx < 128) bar[idx] = 0u;
}

// f32 -> bf16 (RNE), n4 float4-groups
__global__ void conv_bf16(const float* __restrict__ src, short* __restrict__ dst, int n4)
{
  int i = blockIdx.x*256 + threadIdx.x;
  if (i >= n4) return;
  float4 v = *(const float4*)(src + (long)i*4);
  short4 o;
  o.x = f2bf(v.x); o.y = f2bf(v.y); o.z = f2bf(v.z); o.w = f2bf(v.w);
  *(short4*)(dst + (long)i*4) = o;
}

// ---------------------------------------------------------------------------
// bf16 MFMA GEMM template: C[M,N] = act( A @ B^T + bias )
// ---------------------------------------------------------------------------
template<int GATHER,int CVT_A,int BIAS,int TANH,int OUT_BF16>
__global__ __launch_bounds__(256) void gemm_mfma(
    const void* __restrict__ Av, const int* __restrict__ tok,
    const short* __restrict__ Bh, const float* __restrict__ bias,
    void* __restrict__ Cv, int M, int N, int K, int lda, int ldc)
{
  __shared__ short As[128][72];
  __shared__ short Bs[128][72];
  const int bm = blockIdx.x * 128;
  const int bn = blockIdx.y * 128;
  const int tid = threadIdx.x;
  const int w = tid >> 6, l = tid & 63;
  const int wr = (w >> 1) * 64, wc = (w & 1) * 64;
  const int lr = l & 15, kg = l >> 4;

  f32x4 acc[4][4] = {};

  for (int k0 = 0; k0 < K; k0 += 64) {
    #pragma unroll
    for (int q = 0; q < 4; ++q) {
      int ci = tid + 256*q;
      int r = ci >> 3, ch = ci & 7;
      int ar = bm + r; if (ar > M-1) ar = M-1;
      if (GATHER) ar = tok[ar];
      if (CVT_A) {
        const float* ap = ((const float*)Av) + (long)ar*lda + k0 + ch*8;
        float4 v0 = *(const float4*)ap;
        float4 v1 = *(const float4*)(ap + 4);
        short8v s;
        s[0]=f2bf(v0.x); s[1]=f2bf(v0.y); s[2]=f2bf(v0.z); s[3]=f2bf(v0.w);
        s[4]=f2bf(v1.x); s[5]=f2bf(v1.y); s[6]=f2bf(v1.z); s[7]=f2bf(v1.w);
        *(short8v*)&As[r][ch*8] = s;
      } else {
        *(short8v*)&As[r][ch*8] =
            *(const short8v*)(((const short*)Av) + (long)ar*lda + k0 + ch*8);
      }
      int br = bn + r; if (br > N-1) br = N-1;
      *(short8v*)&Bs[r][ch*8] = *(const short8v*)(Bh + (long)br*K + k0 + ch*8);
    }
    __syncthreads();
    #pragma unroll
    for (int ks = 0; ks < 2; ++ks) {
      short8v a[4], b[4];
      #pragma unroll
      for (int m = 0; m < 4; ++m)
        a[m] = *(const short8v*)&As[wr + m*16 + lr][ks*32 + kg*8];
      #pragma unroll
      for (int n = 0; n < 4; ++n)
        b[n] = *(const short8v*)&Bs[wc + n*16 + lr][ks*32 + kg*8];
      #pragma unroll
      for (int m = 0; m < 4; ++m)
        #pragma unroll
        for (int n = 0; n < 4; ++n)
          acc[m][n] = __builtin_amdgcn_mfma_f32_16x16x32_bf16(a[m], b[n], acc[m][n], 0, 0, 0);
    }
    __syncthreads();
  }

  #pragma unroll
  for (int n = 0; n < 4; ++n) {
    int col = bn + wc + n*16 + lr;
    bool cok = (col < N);
    float bv = (BIAS && cok) ? bias[col] : 0.f;
    #pragma unroll
    for (int m = 0; m < 4; ++m) {
      int row0 = bm + wr + m*16 + kg*4;
      #pragma unroll
      for (int r = 0; r < 4; ++r) {
        int row = row0 + r;
        if (cok && row < M) {
          float v = acc[m][n][r] + bv;
          if (TANH) v = tanhc(v);
          if (OUT_BF16) ((short*)Cv)[(long)row*ldc + col] = f2bf(v);
          else          ((float*)Cv)[(long)row*ldc + col] = v;
        }
      }
    }
  }
}

// ---------------------------------------------------------------------------
// Generic f32 GEMM (attention scores / applied only)
// ---------------------------------------------------------------------------
template<int TRANSB>
__global__ __launch_bounds__(256) void gemm_f32(
    const float* __restrict__ A, const float* __restrict__ Bmat,
    float* __restrict__ C,
    int M, int N, int K, int lda, int ldb, int ldc,
    long sA, long sB, long sC)
{
  __shared__ float As[32][68];
  __shared__ float Bs[32][68];
  const int z = blockIdx.z;
  A    += (long)z * sA;
  Bmat += (long)z * sB;
  C    += (long)z * sC;
  const int bm = blockIdx.y*64, bn = blockIdx.x*64;
  const int tid = threadIdx.x;
  const int tx = tid & 15, ty = tid >> 4;
  float acc[4][4] = {};

  for (int k0 = 0; k0 < K; k0 += 32) {
    {
      int r = tid >> 2;
      int c0 = (tid & 3) * 8;
      int row = bm + r; if (row > M-1) row = M-1;
      const float* ap = A + (long)row * lda;
      #pragma unroll
      for (int q = 0; q < 2; ++q) {
        int kk = c0 + q*4;
        float4 v;
        if (k0 + kk + 4 <= K) v = *(const float4*)(ap + k0 + kk);
        else {
          v.x = (k0+kk+0 < K) ? ap[k0+kk+0] : 0.f;
          v.y = (k0+kk+1 < K) ? ap[k0+kk+1] : 0.f;
          v.z = (k0+kk+2 < K) ? ap[k0+kk+2] : 0.f;
          v.w = (k0+kk+3 < K) ? ap[k0+kk+3] : 0.f;
        }
        As[kk+0][r]=v.x; As[kk+1][r]=v.y; As[kk+2][r]=v.z; As[kk+3][r]=v.w;
      }
    }
    if (TRANSB) {
      int n = tid >> 2;
      int c0 = (tid & 3) * 8;
      int col = bn + n; if (col > N-1) col = N-1;
      const float* bp = Bmat + (long)col * ldb;
      #pragma unroll
      for (int q = 0; q < 2; ++q) {
        int kk = c0 + q*4;
        float4 v;
        if (k0 + kk + 4 <= K) v = *(const float4*)(bp + k0 + kk);
        else {
          v.x = (k0+kk+0 < K) ? bp[k0+kk+0] : 0.f;
          v.y = (k0+kk+1 < K) ? bp[k0+kk+1] : 0.f;
          v.z = (k0+kk+2 < K) ? bp[k0+kk+2] : 0.f;
          v.w = (k0+kk+3 < K) ? bp[k0+kk+3] : 0.f;
        }
        Bs[kk+0][n]=v.x; Bs[kk+1][n]=v.y; Bs[kk+2][n]=v.z; Bs[kk+3][n]=v.w;
      }
    } else {
      int kk = tid >> 3;
      int c0 = (tid & 7) * 8;
      int krow = k0 + kk;
      #pragma unroll
      for (int q = 0; q < 2; ++q) {
        int cc = c0 + q*4;
        int col = bn + cc;
        float4 v = make_float4(0.f,0.f,0.f,0.f);
        if (krow < K) {
          const float* bp = Bmat + (long)krow * ldb;
          if (col + 4 <= N) v = *(const float4*)(bp + col);
          else {
            v.x = (col+0 < N) ? bp[col+0] : 0.f;
            v.y = (col+1 < N) ? bp[col+1] : 0.f;
            v.z = (col+2 < N) ? bp[col+2] : 0.f;
            v.w = (col+3 < N) ? bp[col+3] : 0.f;
          }
        }
        Bs[kk][cc+0]=v.x; Bs[kk][cc+1]=v.y; Bs[kk][cc+2]=v.z; Bs[kk][cc+3]=v.w;
      }
    }
    __syncthreads();
    #pragma unroll
    for (int kk = 0; kk < 32; ++kk) {
      float4 a = *(const float4*)&As[kk][ty*4];
      float4 b = *(const float4*)&Bs[kk][tx*4];
      acc[0][0]=fmaf(a.x,b.x,acc[0][0]); acc[0][1]=fmaf(a.x,b.y,acc[0][1]);
      acc[0][2]=fmaf(a.x,b.z,acc[0][2]); acc[0][3]=fmaf(a.x,b.w,acc[0][3]);
      acc[1][0]=fmaf(a.y,b.x,acc[1][0]); acc[1][1]=fmaf(a.y,b.y,acc[1][1]);
      acc[1][2]=fmaf(a.y,b.z,acc[1][2]); acc[1][3]=fmaf(a.y,b.w,acc[1][3]);
      acc[2][0]=fmaf(a.z,b.x,acc[2][0]); acc[2][1]=fmaf(a.z,b.y,acc[2][1]);
      acc[2][2]=fmaf(a.z,b.z,acc[2][2]); acc[2][3]=fmaf(a.z,b.w,acc[2][3]);
      acc[3][0]=fmaf(a.w,b.x,acc[3][0]); acc[3][1]=fmaf(a.w,b.y,acc[3][1]);
      acc[3][2]=fmaf(a.w,b.z,acc[3][2]); acc[3][3]=fmaf(a.w,b.w,acc[3][3]);
    }
    __syncthreads();
  }
  #pragma unroll
  for (int i = 0; i < 4; ++i) {
    int row = bm + ty*4 + i;
    if (row >= M) continue;
    #pragma unroll
    for (int j = 0; j < 4; ++j) {
      int col = bn + tx*4 + j;
      if (col >= N) continue;
      C[(long)row*ldc + col] = acc[i][j];
    }
  }
}

// ---------------------------------------------------------------------------
// Persistent LSTM recurrence, both LSTMs, 100 steps in ONE kernel.
// 64 blocks x 256 threads (4 waves). Block bx: lstm l = bx>>5, unit-block
// ublk = bx&31 (16 units = 64 o'). Wave w owns 4 units (16 o').
// Weights held in registers as 16 pre-loaded MFMA A-frags per wave.
// Per step: stage h (bf16, LDS) -> 16x2 MFMA -> lane-local cell update
// (D-layout gives all 4 gates of a unit in one lane's 4 acc regs) ->
// write h (global, dbuf by parity) -> device-scope atomic barrier.
// ---------------------------------------------------------------------------
__global__ __launch_bounds__(256, 1) void lstm_persist(
    const short* __restrict__ WhPh_e, const short* __restrict__ WhPh_w,
    const float* __restrict__ Xp_e, const float* __restrict__ Xp_w,
    const float* __restrict__ c0_in,
    short* __restrict__ hbufT,   // [2 parity][2 lstm][32 b][512 u] bf16
    short* __restrict__ outT,    // [2 lstm][100 t][512 u][32 b] bf16
    float* __restrict__ out_hc,  // he[32][512] then ce[32][512]
    unsigned* __restrict__ bar)  // [100]
{
  const int bx = blockIdx.x;
  const int l = bx >> 5;
  const int ublk = bx & 31;
  const int tid = threadIdx.x;
  const int w = tid >> 6, lane = tid & 63;
  const int uloc = lane >> 4;          // unit within wave (0..3)
  const int bn = lane & 15;            // batch (and bn+16)
  const int u_global = ublk*16 + w*4 + uloc;
  const int ob = (ublk*16 + w*4) * 4;  // o' base of wave

  const short* WhPh = l ? WhPh_w : WhPh_e;
  const float* Xp   = l ? Xp_w   : Xp_e;

  __shared__ short hT[32][520];        // [b][k], +16B pad

  // preload weight A-frags: A[m=o'loc][k], lane m=lane&15, kg=lane>>4
  short8v afr[16];
  {
    const short* wp = WhPh + (long)(ob + bn)*512 + (lane >> 4)*8;
    #pragma unroll
    for (int ks = 0; ks < 16; ++ks)
      afr[ks] = *(const short8v*)(wp + ks*32);
  }
  // persistent cell state
  float c_s0 = c0_in[bn*512 + u_global];
  float c_s1 = c0_in[(bn+16)*512 + u_global];

  for (int t = 0; t < 100; ++t) {
    const int pin = t & 1, pout = pin ^ 1;
    // issue Xp gathers early (consumed after MFMA)
    float4 x0 = *(const float4*)(Xp + ((long)(bn*100 + t))*2048 + u_global*4);
    float4 x1 = *(const float4*)(Xp + ((long)((bn+16)*100 + t))*2048 + u_global*4);
    // stage h: 32KB linear -> padded LDS
    {
      const short* hsrc = hbufT + ((pin*2 + l) << 14);
      #pragma unroll
      for (int i = 0; i < 8; ++i) {
        int idx = tid + 256*i;         // 16B chunk id, 0..2047
        int b = idx >> 6, c16 = idx & 63;
        *(short8v*)&hT[b][c16*8] = *(const short8v*)(hsrc + idx*8);
      }
    }
    __syncthreads();
    f32x4 acc0 = {}, acc1 = {};
    #pragma unroll
    for (int ks = 0; ks < 16; ++ks) {
      short8v b0 = *(const short8v*)&hT[bn][ks*32 + (lane>>4)*8];
      short8v b1 = *(const short8v*)&hT[bn+16][ks*32 + (lane>>4)*8];
      acc0 = __builtin_amdgcn_mfma_f32_16x16x32_bf16(afr[ks], b0, acc0, 0, 0, 0);
      acc1 = __builtin_amdgcn_mfma_f32_16x16x32_bf16(afr[ks], b1, acc1, 0, 0, 0);
    }
    // cell update (lane-local: acc regs 0..3 = gates i,f,g,o of this unit)
    float gi = acc0[0] + x0.x, gf = acc0[1] + x0.y, gg = acc0[2] + x0.z, go = acc0[3] + x0.w;
    c_s0 = sigf(gf)*c_s0 + sigf(gi)*tanhc(gg);
    float hv0 = sigf(go)*tanhc(c_s0);
    gi = acc1[0] + x1.x; gf = acc1[1] + x1.y; gg = acc1[2] + x1.z; go = acc1[3] + x1.w;
    c_s1 = sigf(gf)*c_s1 + sigf(gi)*tanhc(gg);
    float hv1 = sigf(go)*tanhc(c_s1);

    short hb0 = f2bf(hv0), hb1 = f2bf(hv1);
    short* hdst = hbufT + ((pout*2 + l) << 14);
    hdst[bn*512 + u_global]      = hb0;
    hdst[(bn+16)*512 + u_global] = hb1;
    short* od = outT + ((long)(l*100 + t)*512 + u_global)*32;
    od[bn]    = hb0;
    od[bn+16] = hb1;
    if (t == 99 && l == 0) {
      out_hc[bn*512 + u_global]              = hv0;
      out_hc[(bn+16)*512 + u_global]         = hv1;
      out_hc[16384 + bn*512 + u_global]      = c_s0;
      out_hc[16384 + (bn+16)*512 + u_global] = c_s1;
    }
    if (t < 99) {
      __threadfence();       // release own stores
      __syncthreads();       // all waves of block done (also guards hT reuse)
      if (tid == 0) {
        __hip_atomic_fetch_add(&bar[t], 1u, __ATOMIC_ACQ_REL, __HIP_MEMORY_SCOPE_AGENT);
        while (__hip_atomic_load(&bar[t], __ATOMIC_ACQUIRE, __HIP_MEMORY_SCOPE_AGENT)
               < (unsigned)LSTM_BLOCKS)
          __builtin_amdgcn_s_sleep(8);
      }
      __syncthreads();
    }
  }
}

// transpose out sequences bf16 [lstm][t][u][b] -> bf16 [b][t][u]
__global__ __launch_bounds__(256) void transpose_out(
    const short* __restrict__ outT, short* __restrict__ out_e, short* __restrict__ out_w)
{
  __shared__ short tile[512][40];      // 80B row stride (16B-aligned)
  const int t = blockIdx.x, l = blockIdx.y;
  const short* src = outT + (long)(l*100 + t)*16384;
  const int tid = threadIdx.x;
  #pragma unroll
  for (int i = 0; i < 8; ++i) {
    int fi = tid + 256*i;              // 16B chunk: 0..2047
    int u = fi >> 2, b8 = (fi & 3)*8;
    *(short8v*)&tile[u][b8] = *(const short8v*)(src + fi*8);
  }
  __syncthreads();
  short* dst = l ? out_w : out_e;
  for (int b = 0; b < 32; ++b) {
    short* drow = dst + (long)(b*100 + t)*512;
    drow[tid]     = tile[tid][b];
    drow[tid+256] = tile[tid+256][b];
  }
}

__global__ void softmax_rows(float* __restrict__ P)
{
  int row  = blockIdx.x*4 + (threadIdx.x >> 6);
  int lane = threadIdx.x & 63;
  float* p = P + (long)row*128;
  float x0 = (lane      < 100) ? p[lane]    : -INFINITY;
  float x1 = (lane + 64 < 100) ? p[lane+64] : -INFINITY;
  float m = fmaxf(x0, x1);
  #pragma unroll
  for (int off = 32; off; off >>= 1) m = fmaxf(m, __shfl_xor(m, off));
  float e0 = (lane      < 100) ? __expf(x0 - m) : 0.f;
  float e1 = (lane + 64 < 100) ? __expf(x1 - m) : 0.f;
  float s = e0 + e1;
  #pragma unroll
  for (int off = 32; off; off >>= 1) s += __shfl_xor(s, off);
  float inv = 1.f / s;
  if (lane      < 100) p[lane]    = e0 * inv;
  if (lane + 64 < 100) p[lane+64] = e1 * inv;
}

__global__ void counters_kernel(const int* __restrict__ ie,
                                int* __restrict__ ctr_del, int* __restrict__ ctr_ins)
{
  int b = threadIdx.x;
  if (b >= 32) return;
  int rd = 0, ri = 0;
  for (int t = 0; t < 99; ++t) {
    int a = ie[b*100 + t + 1];
    int incd = (a == 2 || a == 3) ? 1 : 0;
    int inci = (a != 3 && a != 5 && a != 0) ? 1 : 0;
    ctr_del[b*99 + t] = min(rd, 99);
    ctr_ins[b*99 + t] = min(ri, 99);
    rd += incd; ri += inci;
  }
}

// build bf16 feat rows [3168][2048] = [out_e | applied | enc[ctr_del] | out_w[ctr_ins]]
__global__ void feat_kernel(const short* __restrict__ out_e, const float* __restrict__ applied,
                            const float* __restrict__ enc,  const short* __restrict__ out_w,
                            const int* __restrict__ ctr_del, const int* __restrict__ ctr_ins,
                            short* __restrict__ feat)
{
  int n = blockIdx.x;                 // 0..3167
  int b = n / 99, t = n % 99;
  int tid = threadIdx.x;
  int seg = tid >> 6;
  int off = (tid & 63) * 8;
  short8v v;
  if (seg == 0) {
    v = *(const short8v*)(out_e + (long)(b*100 + t)*512 + off);
  } else if (seg == 3) {
    v = *(const short8v*)(out_w + (long)(b*100 + ctr_ins[n])*512 + off);
  } else {
    const float* s = (seg == 1) ? applied + (long)(b*100 + t)*512
                                : enc     + (long)(b*100 + ctr_del[n])*512;
    float4 v0 = *(const float4*)(s + off);
    float4 v1 = *(const float4*)(s + off + 4);
    v[0]=f2bf(v0.x); v[1]=f2bf(v0.y); v[2]=f2bf(v0.z); v[3]=f2bf(v0.w);
    v[4]=f2bf(v1.x); v[5]=f2bf(v1.y); v[6]=f2bf(v1.z); v[7]=f2bf(v1.w);
  }
  *(short8v*)(feat + (long)n*2048 + seg*512 + off) = v;
}

// per-row LSE over 30000 cols, one block per row
__global__ __launch_bounds__(256) void lse_rows(const float* __restrict__ C,
                                                float* __restrict__ lse)
{
  int row = blockIdx.x;
  const float* p = C + (long)row*30000;
  float m = -INFINITY, s = 0.f;
  for (int i = threadIdx.x; i < 7500; i += 256) {
    float4 v = *(const float4*)(p + (long)i*4);
    float mv = fmaxf(fmaxf(v.x, v.y), fmaxf(v.z, v.w));
    if (mv > m) { s *= __expf(m - mv); m = mv; }
    s += __expf(v.x - m) + __expf(v.y - m) + __expf(v.z - m) + __expf(v.w - m);
  }
  #pragma unroll
  for (int off = 32; off; off >>= 1) {
    float om = __shfl_xor(m, off);
    float os = __shfl_xor(s, off);
    float nm = fmaxf(m, om);
    s = s*__expf(m - nm) + os*__expf(om - nm);
    m = nm;
  }
  __shared__ float sm[4], ss[4];
  int wv = threadIdx.x >> 6;
  if ((threadIdx.x & 63) == 0) { sm[wv] = m; ss[wv] = s; }
  __syncthreads();
  if (threadIdx.x == 0) {
    float M = sm[0], S = ss[0];
    #pragma unroll
    for (int i = 1; i < 4; ++i) {
      float nm = fmaxf(M, sm[i]);
      S = S*__expf(M - nm) + ss[i]*__expf(sm[i] - nm);
      M = nm;
    }
    lse[row] = M + __logf(S);
  }
}

__global__ void sub_lse(float* __restrict__ C, const float* __restrict__ lse)
{
  int row = blockIdx.x;
  float lv = lse[row];
  float* p = C + (long)row*30000;
  for (int i = threadIdx.x; i < 7500; i += 256) {
    float4 v = *(float4*)(p + (long)i*4);
    v.x -= lv; v.y -= lv; v.z -= lv; v.w -= lv;
    *(float4*)(p + (long)i*4) = v;
  }
}

// ---------------------------------------------------------------------------
extern "C" void kernel_launch(void* const* d_in, const int* in_sizes, int n_in,
                              void* d_out, int out_size, void* d_ws, size_t ws_size,
                              hipStream_t stream)
{
  const int*   input_edits = (const int*)  d_in[0];
  const int*   simp_sent   = (const int*)  d_in[1];
  const float* enc   = (const float*)d_in[3];
  const float* h0    = (const float*)d_in[4];
  const float* c0    = (const float*)d_in[5];
  const float* emb   = (const float*)d_in[6];
  const float* Wi_e  = (const float*)d_in[7];
  const float* Wh_e  = (const float*)d_in[8];
  const float* bi_e  = (const float*)d_in[9];
  const float* bh_e  = (const float*)d_in[10];
  const float* Wi_w  = (const float*)d_in[11];
  const float* Wh_w  = (const float*)d_in[12];
  const float* bi_w  = (const float*)d_in[13];
  const float* bh_w  = (const float*)d_in[14];
  const float* Wp    = (const float*)d_in[15];
  const float* Wm    = (const float*)d_in[16];
  const float* bmv   = (const float*)d_in[17];
  const float* b_out = (const float*)d_in[18];
  float* out = (float*)d_out;

  float* ws = (float*)d_ws;
  size_t off = 0;
  auto alloc = [&](size_t n){ float* p = ws + off; off += (n + 63) & ~(size_t)63; return p; };

  short* WiPh_e   = (short*)alloc(262144);   // 2048*256 bf16
  short* WiPh_w   = (short*)alloc(262144);
  float* biasP_e  = alloc(2048);
  float* biasP_w  = alloc(2048);
  short* WhPh_e   = (short*)alloc(524288);   // 2048*512 bf16
  short* WhPh_w   = (short*)alloc(524288);
  float* Xp_e     = alloc(3200*2048);
  float* Xp_w     = alloc(3200*2048);
  short* outT     = (short*)alloc(1638400);  // 2*100*512*32 bf16
  short* out_e    = (short*)alloc(819200);   // 3200*512 bf16
  short* out_w    = (short*)alloc(819200);
  short* hbufT    = (short*)alloc(32768);    // 2*2*32*512 bf16
  unsigned* bar   = (unsigned*)alloc(128);
  float* Pbuf     = alloc(3200*128);
  float* lse      = alloc(3168);
  int*   ctr_del  = (int*)alloc(3168);
  int*   ctr_ins  = (int*)alloc(3168);
  short* Wph      = (short*)alloc(131072);   // 512*512 bf16
  short* Wmh      = (short*)alloc(262144);   // 256*2048 bf16
  float* key      = alloc(3200*512);
  float* applied  = alloc(3200*512);
  // overlays (lifetimes disjoint, stream-ordered):
  short* feath    = (short*)Xp_e;            // 3168*2048 bf16, after recurrence
  short* hmlph    = (short*)Xp_w;            // 3168*256 bf16, after MLP
  short* embh     = (short*)(Xp_w + 1048576);// 30000*256 bf16

  // 1) weight prep + h-state/barrier init + small bf16 converts
  prep_permute<<<4096, 256, 0, stream>>>(Wi_e, Wh_e, bi_e, bh_e, WiPh_e, WhPh_e, biasP_e);
  prep_permute<<<4096, 256, 0, stream>>>(Wi_w, Wh_w, bi_w, bh_w, WiPh_w, WhPh_w, biasP_w);
  init_all<<<128, 256, 0, stream>>>(h0, hbufT, bar);
  conv_bf16<<<256, 256, 0, stream>>>(Wp, Wph, 512*512/4);
  conv_bf16<<<512, 256, 0, stream>>>(Wm, Wmh, 256*2048/4);

  // 2) Xproj = emb[tok] @ WiP^T + biasP   (MFMA, gather+cvt from f32 emb)
  gemm_mfma<1,1,1,0,0><<<dim3(25,16), 256, 0, stream>>>(
      emb, input_edits, WiPh_e, biasP_e, Xp_e, 3200, 2048, 256, 256, 2048);
  gemm_mfma<1,1,1,0,0><<<dim3(25,16), 256, 0, stream>>>(
      emb, simp_sent,   WiPh_w, biasP_w, Xp_w, 3200, 2048, 256, 256, 2048);

  // 3) recurrence: ONE persistent kernel, both LSTMs, 100 steps
  lstm_persist<<<LSTM_BLOCKS, 256, 0, stream>>>(
      WhPh_e, WhPh_w, Xp_e, Xp_w, c0, hbufT, outT, out + 95040000L, bar);

  // emb -> bf16 into Xp_w overlay (Xp_w dead after recurrence)
  conv_bf16<<<7500, 256, 0, stream>>>(emb, embh, 30000*256/4);

  // 4) transpose sequences to bf16 [b][t][u]
  transpose_out<<<dim3(100,2), 256, 0, stream>>>(outT, out_e, out_w);

  // 5) key = out_e @ Wp^T  (MFMA)
  gemm_mfma<0,0,0,0,0><<<dim3(25,4), 256, 0, stream>>>(
      out_e, nullptr, Wph, nullptr, key, 3200, 512, 512, 512, 512);

  // 6) attention (f32)
  gemm_f32<1><<<dim3(2,2,32), 256, 0, stream>>>(
      key, enc, Pbuf, 100, 100, 512, 512, 512, 128, 51200, 51200, 12800);
  softmax_rows<<<800, 256, 0, stream>>>(Pbuf);
  gemm_f32<0><<<dim3(8,2,32), 256, 0, stream>>>(
      Pbuf, enc, applied, 100, 512, 100, 128, 512, 512, 12800, 51200, 51200);

  // 7) counters + feat(bf16) + MLP(MFMA, tanh, bf16 out)
  counters_kernel<<<1, 64, 0, stream>>>(input_edits, ctr_del, ctr_ins);
  feat_kernel<<<3168, 256, 0, stream>>>(out_e, applied, enc, out_w, ctr_del, ctr_ins, feath);
  gemm_mfma<0,0,1,1,1><<<dim3(25,2), 256, 0, stream>>>(
      feath, nullptr, Wmh, bmv, hmlph, 3168, 256, 2048, 2048, 256);

  // 8) logits (MFMA) + log-softmax
  gemm_mfma<0,0,1,0,0><<<dim3(25,235), 256, 0, stream>>>(
      hmlph, nullptr, embh, b_out, out, 3168, 30000, 256, 256, 30000);
  lse_rows<<<3168, 256, 0, stream>>>(out, lse);
  sub_lse<<<3168, 256, 0, stream>>>(out, lse);
}

// Round 5
// 1562.070 us; speedup vs baseline: 115.2121x; 1.1382x over previous
//
#include <hip/hip_runtime.h>
#include <math.h>

// Sizes (fixed): B=32, T=100, S=100, H=512, E=256, V=30000, 4H=2048, M_log=3168

typedef __attribute__((ext_vector_type(8))) short short8v;  // 8 bf16 (4 VGPRs)
typedef __attribute__((ext_vector_type(4))) float f32x4;
typedef unsigned long long ull;

#define LSTM_BLOCKS 64

__device__ __forceinline__ float sigf(float x){ return 1.0f/(1.0f + __expf(-x)); }
__device__ __forceinline__ float tanhc(float x){
  x = fminf(fmaxf(x, -15.f), 15.f);
  float e = __expf(2.f*x);
  return (e-1.f)/(e+1.f);
}
__device__ __forceinline__ short f2bf(float f){
  unsigned u = __float_as_uint(f);
  u = (u + 0x7fffu + ((u >> 16) & 1u)) >> 16;
  return (short)u;
}

// ---------------------------------------------------------------------------
// prep: gate-permuted weights. o' = u*4 + g (source row g*512+u)
// ---------------------------------------------------------------------------
__global__ void prep_permute(const float* __restrict__ Wi, const float* __restrict__ Wh,
                             const float* __restrict__ bi, const float* __restrict__ bh,
                             short* __restrict__ WiPh, short* __restrict__ WhPh,
                             float* __restrict__ biasP)
{
  int idx = blockIdx.x*256 + threadIdx.x;      // 0 .. 1048575
  {
    int op = idx >> 9, k = idx & 511;
    int u = op >> 2, g = op & 3;
    WhPh[idx] = f2bf(Wh[(g*512+u)*512 + k]);
  }
  if (idx < 2048*256) {
    int op = idx >> 8, e = idx & 255;
    int u = op >> 2, g = op & 3;
    WiPh[idx] = f2bf(Wi[(g*512+u)*256 + e]);
  }
  if (idx < 2048) {
    int u = idx >> 2, g = idx & 3;
    biasP[idx] = bi[g*512+u] + bh[g*512+u];
  }
}

// init h state (qword-packed bf16: hq[parity0][lstm][b][u/4]) + zero barrier
__global__ void init_all(const float* __restrict__ h0, ull* __restrict__ hq,
                         unsigned* __restrict__ bar)
{
  int idx = blockIdx.x*256 + threadIdx.x;   // 0..8191 : l,b,q
  if (idx < 8192) {
    int b = (idx >> 7) & 31, q = idx & 127;
    const float* src = h0 + b*512 + q*4;
    ull v = ((ull)(unsigned short)f2bf(src[3]) << 48) |
            ((ull)(unsigned short)f2bf(src[2]) << 32) |
            ((ull)(unsigned short)f2bf(src[1]) << 16) |
            ((ull)(unsigned short)f2bf(src[0]));
    hq[idx] = v;                          // parity 0: idx == (l<<12)+(b<<7)+q
  }
  if (idx < 128) bar[idx] = 0u;
}

// f32 -> bf16 (RNE), n4 float4-groups
__global__ void conv_bf16(const float* __restrict__ src, short* __restrict__ dst, int n4)
{
  int i = blockIdx.x*256 + threadIdx.x;
  if (i >= n4) return;
  float4 v = *(const float4*)(src + (long)i*4);
  short4 o;
  o.x = f2bf(v.x); o.y = f2bf(v.y); o.z = f2bf(v.z); o.w = f2bf(v.w);
  *(short4*)(dst + (long)i*4) = o;
}

// ---------------------------------------------------------------------------
// bf16 MFMA GEMM template: C[M,N] = act( A @ B^T + bias )
// ---------------------------------------------------------------------------
template<int GATHER,int CVT_A,int BIAS,int TANH,int OUT_BF16>
__global__ __launch_bounds__(256) void gemm_mfma(
    const void* __restrict__ Av, const int* __restrict__ tok,
    const short* __restrict__ Bh, const float* __restrict__ bias,
    void* __restrict__ Cv, int M, int N, int K, int lda, int ldc)
{
  __shared__ short As[128][72];
  __shared__ short Bs[128][72];
  const int bm = blockIdx.x * 128;
  const int bn = blockIdx.y * 128;
  const int tid = threadIdx.x;
  const int w = tid >> 6, l = tid & 63;
  const int wr = (w >> 1) * 64, wc = (w & 1) * 64;
  const int lr = l & 15, kg = l >> 4;

  f32x4 acc[4][4] = {};

  for (int k0 = 0; k0 < K; k0 += 64) {
    #pragma unroll
    for (int q = 0; q < 4; ++q) {
      int ci = tid + 256*q;
      int r = ci >> 3, ch = ci & 7;
      int ar = bm + r; if (ar > M-1) ar = M-1;
      if (GATHER) ar = tok[ar];
      if (CVT_A) {
        const float* ap = ((const float*)Av) + (long)ar*lda + k0 + ch*8;
        float4 v0 = *(const float4*)ap;
        float4 v1 = *(const float4*)(ap + 4);
        short8v s;
        s[0]=f2bf(v0.x); s[1]=f2bf(v0.y); s[2]=f2bf(v0.z); s[3]=f2bf(v0.w);
        s[4]=f2bf(v1.x); s[5]=f2bf(v1.y); s[6]=f2bf(v1.z); s[7]=f2bf(v1.w);
        *(short8v*)&As[r][ch*8] = s;
      } else {
        *(short8v*)&As[r][ch*8] =
            *(const short8v*)(((const short*)Av) + (long)ar*lda + k0 + ch*8);
      }
      int br = bn + r; if (br > N-1) br = N-1;
      *(short8v*)&Bs[r][ch*8] = *(const short8v*)(Bh + (long)br*K + k0 + ch*8);
    }
    __syncthreads();
    #pragma unroll
    for (int ks = 0; ks < 2; ++ks) {
      short8v a[4], b[4];
      #pragma unroll
      for (int m = 0; m < 4; ++m)
        a[m] = *(const short8v*)&As[wr + m*16 + lr][ks*32 + kg*8];
      #pragma unroll
      for (int n = 0; n < 4; ++n)
        b[n] = *(const short8v*)&Bs[wc + n*16 + lr][ks*32 + kg*8];
      #pragma unroll
      for (int m = 0; m < 4; ++m)
        #pragma unroll
        for (int n = 0; n < 4; ++n)
          acc[m][n] = __builtin_amdgcn_mfma_f32_16x16x32_bf16(a[m], b[n], acc[m][n], 0, 0, 0);
    }
    __syncthreads();
  }

  #pragma unroll
  for (int n = 0; n < 4; ++n) {
    int col = bn + wc + n*16 + lr;
    bool cok = (col < N);
    float bv = (BIAS && cok) ? bias[col] : 0.f;
    #pragma unroll
    for (int m = 0; m < 4; ++m) {
      int row0 = bm + wr + m*16 + kg*4;
      #pragma unroll
      for (int r = 0; r < 4; ++r) {
        int row = row0 + r;
        if (cok && row < M) {
          float v = acc[m][n][r] + bv;
          if (TANH) v = tanhc(v);
          if (OUT_BF16) ((short*)Cv)[(long)row*ldc + col] = f2bf(v);
          else          ((float*)Cv)[(long)row*ldc + col] = v;
        }
      }
    }
  }
}

// ---------------------------------------------------------------------------
// Generic f32 GEMM (attention scores / applied only)
// ---------------------------------------------------------------------------
template<int TRANSB>
__global__ __launch_bounds__(256) void gemm_f32(
    const float* __restrict__ A, const float* __restrict__ Bmat,
    float* __restrict__ C,
    int M, int N, int K, int lda, int ldb, int ldc,
    long sA, long sB, long sC)
{
  __shared__ float As[32][68];
  __shared__ float Bs[32][68];
  const int z = blockIdx.z;
  A    += (long)z * sA;
  Bmat += (long)z * sB;
  C    += (long)z * sC;
  const int bm = blockIdx.y*64, bn = blockIdx.x*64;
  const int tid = threadIdx.x;
  const int tx = tid & 15, ty = tid >> 4;
  float acc[4][4] = {};

  for (int k0 = 0; k0 < K; k0 += 32) {
    {
      int r = tid >> 2;
      int c0 = (tid & 3) * 8;
      int row = bm + r; if (row > M-1) row = M-1;
      const float* ap = A + (long)row * lda;
      #pragma unroll
      for (int q = 0; q < 2; ++q) {
        int kk = c0 + q*4;
        float4 v;
        if (k0 + kk + 4 <= K) v = *(const float4*)(ap + k0 + kk);
        else {
          v.x = (k0+kk+0 < K) ? ap[k0+kk+0] : 0.f;
          v.y = (k0+kk+1 < K) ? ap[k0+kk+1] : 0.f;
          v.z = (k0+kk+2 < K) ? ap[k0+kk+2] : 0.f;
          v.w = (k0+kk+3 < K) ? ap[k0+kk+3] : 0.f;
        }
        As[kk+0][r]=v.x; As[kk+1][r]=v.y; As[kk+2][r]=v.z; As[kk+3][r]=v.w;
      }
    }
    if (TRANSB) {
      int n = tid >> 2;
      int c0 = (tid & 3) * 8;
      int col = bn + n; if (col > N-1) col = N-1;
      const float* bp = Bmat + (long)col * ldb;
      #pragma unroll
      for (int q = 0; q < 2; ++q) {
        int kk = c0 + q*4;
        float4 v;
        if (k0 + kk + 4 <= K) v = *(const float4*)(bp + k0 + kk);
        else {
          v.x = (k0+kk+0 < K) ? bp[k0+kk+0] : 0.f;
          v.y = (k0+kk+1 < K) ? bp[k0+kk+1] : 0.f;
          v.z = (k0+kk+2 < K) ? bp[k0+kk+2] : 0.f;
          v.w = (k0+kk+3 < K) ? bp[k0+kk+3] : 0.f;
        }
        Bs[kk+0][n]=v.x; Bs[kk+1][n]=v.y; Bs[kk+2][n]=v.z; Bs[kk+3][n]=v.w;
      }
    } else {
      int kk = tid >> 3;
      int c0 = (tid & 7) * 8;
      int krow = k0 + kk;
      #pragma unroll
      for (int q = 0; q < 2; ++q) {
        int cc = c0 + q*4;
        int col = bn + cc;
        float4 v = make_float4(0.f,0.f,0.f,0.f);
        if (krow < K) {
          const float* bp = Bmat + (long)krow * ldb;
          if (col + 4 <= N) v = *(const float4*)(bp + col);
          else {
            v.x = (col+0 < N) ? bp[col+0] : 0.f;
            v.y = (col+1 < N) ? bp[col+1] : 0.f;
            v.z = (col+2 < N) ? bp[col+2] : 0.f;
            v.w = (col+3 < N) ? bp[col+3] : 0.f;
          }
        }
        Bs[kk][cc+0]=v.x; Bs[kk][cc+1]=v.y; Bs[kk][cc+2]=v.z; Bs[kk][cc+3]=v.w;
      }
    }
    __syncthreads();
    #pragma unroll
    for (int kk = 0; kk < 32; ++kk) {
      float4 a = *(const float4*)&As[kk][ty*4];
      float4 b = *(const float4*)&Bs[kk][tx*4];
      acc[0][0]=fmaf(a.x,b.x,acc[0][0]); acc[0][1]=fmaf(a.x,b.y,acc[0][1]);
      acc[0][2]=fmaf(a.x,b.z,acc[0][2]); acc[0][3]=fmaf(a.x,b.w,acc[0][3]);
      acc[1][0]=fmaf(a.y,b.x,acc[1][0]); acc[1][1]=fmaf(a.y,b.y,acc[1][1]);
      acc[1][2]=fmaf(a.y,b.z,acc[1][2]); acc[1][3]=fmaf(a.y,b.w,acc[1][3]);
      acc[2][0]=fmaf(a.z,b.x,acc[2][0]); acc[2][1]=fmaf(a.z,b.y,acc[2][1]);
      acc[2][2]=fmaf(a.z,b.z,acc[2][2]); acc[2][3]=fmaf(a.z,b.w,acc[2][3]);
      acc[3][0]=fmaf(a.w,b.x,acc[3][0]); acc[3][1]=fmaf(a.w,b.y,acc[3][1]);
      acc[3][2]=fmaf(a.w,b.z,acc[3][2]); acc[3][3]=fmaf(a.w,b.w,acc[3][3]);
    }
    __syncthreads();
  }
  #pragma unroll
  for (int i = 0; i < 4; ++i) {
    int row = bm + ty*4 + i;
    if (row >= M) continue;
    #pragma unroll
    for (int j = 0; j < 4; ++j) {
      int col = bn + tx*4 + j;
      if (col >= N) continue;
      C[(long)row*ldc + col] = acc[i][j];
    }
  }
}

// ---------------------------------------------------------------------------
// Persistent LSTM recurrence — fence-free cross-XCD sync.
// h exchanged via relaxed agent-scope 8B atomics (bypass L2 -> coherent L3);
// barrier = s_waitcnt vmcnt(0) + syncthreads + relaxed fetch_add + relaxed
// spin. NO __threadfence / acquire (those emit L2 writeback/invalidate per
// call on gfx950 — measured 10.5us/step in R4).
// hq layout: [parity][lstm][b=32][qword u/4=128], qword = 4 consecutive u bf16.
// ---------------------------------------------------------------------------
__global__ __launch_bounds__(256, 1) void lstm_persist(
    const short* __restrict__ WhPh_e, const short* __restrict__ WhPh_w,
    const float* __restrict__ Xp_e, const float* __restrict__ Xp_w,
    const float* __restrict__ c0_in,
    ull* __restrict__ hq,        // [2][2][32][128] qwords
    short* __restrict__ outT,    // [2 lstm][100 t][512 u][32 b] bf16
    float* __restrict__ out_hc,  // he[32][512] then ce[32][512]
    unsigned* __restrict__ bar)  // [100]
{
  const int bx = blockIdx.x;
  const int l = bx >> 5;
  const int ublk = bx & 31;
  const int tid = threadIdx.x;
  const int w = tid >> 6, lane = tid & 63;
  const int uloc = lane >> 4;          // unit within wave (0..3)
  const int bn = lane & 15;            // batch (and bn+16)
  const int u_global = ublk*16 + w*4 + uloc;
  const int ob = (ublk*16 + w*4) * 4;  // o' base of wave
  const int qcol = ublk*4 + w;         // this wave's qword column

  const short* WhPh = l ? WhPh_w : WhPh_e;
  const float* Xp   = l ? Xp_w   : Xp_e;

  __shared__ short hT[32][520];        // [b][k], +16B pad

  // preload weight A-frags
  short8v afr[16];
  {
    const short* wp = WhPh + (long)(ob + bn)*512 + (lane >> 4)*8;
    #pragma unroll
    for (int ks = 0; ks < 16; ++ks)
      afr[ks] = *(const short8v*)(wp + ks*32);
  }
  // persistent cell state
  float c_s0 = c0_in[bn*512 + u_global];
  float c_s1 = c0_in[(bn+16)*512 + u_global];

  for (int t = 0; t < 100; ++t) {
    const int pin = t & 1, pout = pin ^ 1;
    // Xp gathers issued early
    float4 x0 = *(const float4*)(Xp + ((long)(bn*100 + t))*2048 + u_global*4);
    float4 x1 = *(const float4*)(Xp + ((long)((bn+16)*100 + t))*2048 + u_global*4);
    // stage h: 4096 qwords via relaxed agent atomics (L3-coherent) -> LDS
    {
      const ull* hsrc = hq + ((pin*2 + l) << 12);
      #pragma unroll
      for (int i = 0; i < 16; ++i) {
        int idx = tid + 256*i;         // 0..4095
        int b = idx >> 7, q = idx & 127;
        ull v = __hip_atomic_load(hsrc + idx, __ATOMIC_RELAXED, __HIP_MEMORY_SCOPE_AGENT);
        *(ull*)&hT[b][q*4] = v;
      }
    }
    __syncthreads();
    f32x4 acc0 = {}, acc1 = {};
    #pragma unroll
    for (int ks = 0; ks < 16; ++ks) {
      short8v b0 = *(const short8v*)&hT[bn][ks*32 + (lane>>4)*8];
      short8v b1 = *(const short8v*)&hT[bn+16][ks*32 + (lane>>4)*8];
      acc0 = __builtin_amdgcn_mfma_f32_16x16x32_bf16(afr[ks], b0, acc0, 0, 0, 0);
      acc1 = __builtin_amdgcn_mfma_f32_16x16x32_bf16(afr[ks], b1, acc1, 0, 0, 0);
    }
    // cell update (lane-local: acc regs 0..3 = gates i,f,g,o of this unit)
    float gi = acc0[0] + x0.x, gf = acc0[1] + x0.y, gg = acc0[2] + x0.z, go = acc0[3] + x0.w;
    c_s0 = sigf(gf)*c_s0 + sigf(gi)*tanhc(gg);
    float hv0 = sigf(go)*tanhc(c_s0);
    gi = acc1[0] + x1.x; gf = acc1[1] + x1.y; gg = acc1[2] + x1.z; go = acc1[3] + x1.w;
    c_s1 = sigf(gf)*c_s1 + sigf(gi)*tanhc(gg);
    float hv1 = sigf(go)*tanhc(c_s1);

    short hb0 = f2bf(hv0), hb1 = f2bf(hv1);
    // pack 4 units (same bn, uloc 0..3 live in lanes bn, bn+16, bn+32, bn+48)
    unsigned p0 = (unsigned)(unsigned short)hb0;
    unsigned p1 = (unsigned)(unsigned short)hb1;
    unsigned a1 = __shfl_down((int)p0, 16), a2 = __shfl_down((int)p0, 32), a3 = __shfl_down((int)p0, 48);
    unsigned e1 = __shfl_down((int)p1, 16), e2 = __shfl_down((int)p1, 32), e3 = __shfl_down((int)p1, 48);
    if (uloc == 0) {
      ull q0 = ((ull)((a2 & 0xffffu) | (a3 << 16)) << 32) | ((p0 & 0xffffu) | (a1 << 16));
      ull q1 = ((ull)((e2 & 0xffffu) | (e3 << 16)) << 32) | ((p1 & 0xffffu) | (e1 << 16));
      ull* hd = hq + ((pout*2 + l) << 12);
      __hip_atomic_store(&hd[(bn << 7) + qcol],        q0, __ATOMIC_RELAXED, __HIP_MEMORY_SCOPE_AGENT);
      __hip_atomic_store(&hd[((bn+16) << 7) + qcol],   q1, __ATOMIC_RELAXED, __HIP_MEMORY_SCOPE_AGENT);
    }
    // sequence output (normal cached stores; consumed by later kernels)
    short* od = outT + ((long)(l*100 + t)*512 + u_global)*32;
    od[bn]    = hb0;
    od[bn+16] = hb1;
    if (t == 99 && l == 0) {
      out_hc[bn*512 + u_global]              = hv0;
      out_hc[(bn+16)*512 + u_global]         = hv1;
      out_hc[16384 + bn*512 + u_global]      = c_s0;
      out_hc[16384 + (bn+16)*512 + u_global] = c_s1;
    }
    if (t < 99) {
      asm volatile("s_waitcnt vmcnt(0)" ::: "memory");  // own h-stores at L3
      __syncthreads();                                   // whole block done
      if (tid == 0)
        __hip_atomic_fetch_add(&bar[t], 1u, __ATOMIC_RELAXED, __HIP_MEMORY_SCOPE_AGENT);
      while (__hip_atomic_load(&bar[t], __ATOMIC_RELAXED, __HIP_MEMORY_SCOPE_AGENT)
             < (unsigned)LSTM_BLOCKS)
        __builtin_amdgcn_s_sleep(2);
      // no trailing syncthreads: all hT reads happened before the pre-add
      // syncthreads, so overwriting hT next iteration is safe.
    }
  }
}

// transpose out sequences bf16 [lstm][t][u][b] -> bf16 [b][t][u]
__global__ __launch_bounds__(256) void transpose_out(
    const short* __restrict__ outT, short* __restrict__ out_e, short* __restrict__ out_w)
{
  __shared__ short tile[512][40];
  const int t = blockIdx.x, l = blockIdx.y;
  const short* src = outT + (long)(l*100 + t)*16384;
  const int tid = threadIdx.x;
  #pragma unroll
  for (int i = 0; i < 8; ++i) {
    int fi = tid + 256*i;
    int u = fi >> 2, b8 = (fi & 3)*8;
    *(short8v*)&tile[u][b8] = *(const short8v*)(src + fi*8);
  }
  __syncthreads();
  short* dst = l ? out_w : out_e;
  for (int b = 0; b < 32; ++b) {
    short* drow = dst + (long)(b*100 + t)*512;
    drow[tid]     = tile[tid][b];
    drow[tid+256] = tile[tid+256][b];
  }
}

__global__ void softmax_rows(float* __restrict__ P)
{
  int row  = blockIdx.x*4 + (threadIdx.x >> 6);
  int lane = threadIdx.x & 63;
  float* p = P + (long)row*128;
  float x0 = (lane      < 100) ? p[lane]    : -INFINITY;
  float x1 = (lane + 64 < 100) ? p[lane+64] : -INFINITY;
  float m = fmaxf(x0, x1);
  #pragma unroll
  for (int off = 32; off; off >>= 1) m = fmaxf(m, __shfl_xor(m, off));
  float e0 = (lane      < 100) ? __expf(x0 - m) : 0.f;
  float e1 = (lane + 64 < 100) ? __expf(x1 - m) : 0.f;
  float s = e0 + e1;
  #pragma unroll
  for (int off = 32; off; off >>= 1) s += __shfl_xor(s, off);
  float inv = 1.f / s;
  if (lane      < 100) p[lane]    = e0 * inv;
  if (lane + 64 < 100) p[lane+64] = e1 * inv;
}

__global__ void counters_kernel(const int* __restrict__ ie,
                                int* __restrict__ ctr_del, int* __restrict__ ctr_ins)
{
  int b = threadIdx.x;
  if (b >= 32) return;
  int rd = 0, ri = 0;
  for (int t = 0; t < 99; ++t) {
    int a = ie[b*100 + t + 1];
    int incd = (a == 2 || a == 3) ? 1 : 0;
    int inci = (a != 3 && a != 5 && a != 0) ? 1 : 0;
    ctr_del[b*99 + t] = min(rd, 99);
    ctr_ins[b*99 + t] = min(ri, 99);
    rd += incd; ri += inci;
  }
}

// build bf16 feat rows [3168][2048] = [out_e | applied | enc[ctr_del] | out_w[ctr_ins]]
__global__ void feat_kernel(const short* __restrict__ out_e, const float* __restrict__ applied,
                            const float* __restrict__ enc,  const short* __restrict__ out_w,
                            const int* __restrict__ ctr_del, const int* __restrict__ ctr_ins,
                            short* __restrict__ feat)
{
  int n = blockIdx.x;                 // 0..3167
  int b = n / 99, t = n % 99;
  int tid = threadIdx.x;
  int seg = tid >> 6;
  int off = (tid & 63) * 8;
  short8v v;
  if (seg == 0) {
    v = *(const short8v*)(out_e + (long)(b*100 + t)*512 + off);
  } else if (seg == 3) {
    v = *(const short8v*)(out_w + (long)(b*100 + ctr_ins[n])*512 + off);
  } else {
    const float* s = (seg == 1) ? applied + (long)(b*100 + t)*512
                                : enc     + (long)(b*100 + ctr_del[n])*512;
    float4 v0 = *(const float4*)(s + off);
    float4 v1 = *(const float4*)(s + off + 4);
    v[0]=f2bf(v0.x); v[1]=f2bf(v0.y); v[2]=f2bf(v0.z); v[3]=f2bf(v0.w);
    v[4]=f2bf(v1.x); v[5]=f2bf(v1.y); v[6]=f2bf(v1.z); v[7]=f2bf(v1.w);
  }
  *(short8v*)(feat + (long)n*2048 + seg*512 + off) = v;
}

// per-row LSE over 30000 cols, one block per row
__global__ __launch_bounds__(256) void lse_rows(const float* __restrict__ C,
                                                float* __restrict__ lse)
{
  int row = blockIdx.x;
  const float* p = C + (long)row*30000;
  float m = -INFINITY, s = 0.f;
  for (int i = threadIdx.x; i < 7500; i += 256) {
    float4 v = *(const float4*)(p + (long)i*4);
    float mv = fmaxf(fmaxf(v.x, v.y), fmaxf(v.z, v.w));
    if (mv > m) { s *= __expf(m - mv); m = mv; }
    s += __expf(v.x - m) + __expf(v.y - m) + __expf(v.z - m) + __expf(v.w - m);
  }
  #pragma unroll
  for (int off = 32; off; off >>= 1) {
    float om = __shfl_xor(m, off);
    float os = __shfl_xor(s, off);
    float nm = fmaxf(m, om);
    s = s*__expf(m - nm) + os*__expf(om - nm);
    m = nm;
  }
  __shared__ float sm[4], ss[4];
  int wv = threadIdx.x >> 6;
  if ((threadIdx.x & 63) == 0) { sm[wv] = m; ss[wv] = s; }
  __syncthreads();
  if (threadIdx.x == 0) {
    float M = sm[0], S = ss[0];
    #pragma unroll
    for (int i = 1; i < 4; ++i) {
      float nm = fmaxf(M, sm[i]);
      S = S*__expf(M - nm) + ss[i]*__expf(sm[i] - nm);
      M = nm;
    }
    lse[row] = M + __logf(S);
  }
}

__global__ void sub_lse(float* __restrict__ C, const float* __restrict__ lse)
{
  int row = blockIdx.x;
  float lv = lse[row];
  float* p = C + (long)row*30000;
  for (int i = threadIdx.x; i < 7500; i += 256) {
    float4 v = *(float4*)(p + (long)i*4);
    v.x -= lv; v.y -= lv; v.z -= lv; v.w -= lv;
    *(float4*)(p + (long)i*4) = v;
  }
}

// ---------------------------------------------------------------------------
extern "C" void kernel_launch(void* const* d_in, const int* in_sizes, int n_in,
                              void* d_out, int out_size, void* d_ws, size_t ws_size,
                              hipStream_t stream)
{
  const int*   input_edits = (const int*)  d_in[0];
  const int*   simp_sent   = (const int*)  d_in[1];
  const float* enc   = (const float*)d_in[3];
  const float* h0    = (const float*)d_in[4];
  const float* c0    = (const float*)d_in[5];
  const float* emb   = (const float*)d_in[6];
  const float* Wi_e  = (const float*)d_in[7];
  const float* Wh_e  = (const float*)d_in[8];
  const float* bi_e  = (const float*)d_in[9];
  const float* bh_e  = (const float*)d_in[10];
  const float* Wi_w  = (const float*)d_in[11];
  const float* Wh_w  = (const float*)d_in[12];
  const float* bi_w  = (const float*)d_in[13];
  const float* bh_w  = (const float*)d_in[14];
  const float* Wp    = (const float*)d_in[15];
  const float* Wm    = (const float*)d_in[16];
  const float* bmv   = (const float*)d_in[17];
  const float* b_out = (const float*)d_in[18];
  float* out = (float*)d_out;

  float* ws = (float*)d_ws;
  size_t off = 0;
  auto alloc = [&](size_t n){ float* p = ws + off; off += (n + 63) & ~(size_t)63; return p; };

  short* WiPh_e   = (short*)alloc(262144);   // 2048*256 bf16
  short* WiPh_w   = (short*)alloc(262144);
  float* biasP_e  = alloc(2048);
  float* biasP_w  = alloc(2048);
  short* WhPh_e   = (short*)alloc(524288);   // 2048*512 bf16
  short* WhPh_w   = (short*)alloc(524288);
  float* Xp_e     = alloc(3200*2048);
  float* Xp_w     = alloc(3200*2048);
  short* outT     = (short*)alloc(1638400);  // 2*100*512*32 bf16
  short* out_e    = (short*)alloc(819200);   // 3200*512 bf16
  short* out_w    = (short*)alloc(819200);
  ull*   hq       = (ull*)alloc(32768);      // 2*2*32*128 qwords (128 KB)
  unsigned* bar   = (unsigned*)alloc(128);
  float* Pbuf     = alloc(3200*128);
  float* lse      = alloc(3168);
  int*   ctr_del  = (int*)alloc(3168);
  int*   ctr_ins  = (int*)alloc(3168);
  short* Wph      = (short*)alloc(131072);   // 512*512 bf16
  short* Wmh      = (short*)alloc(262144);   // 256*2048 bf16
  float* key      = alloc(3200*512);
  float* applied  = alloc(3200*512);
  // overlays (lifetimes disjoint, stream-ordered):
  short* feath    = (short*)Xp_e;            // 3168*2048 bf16, after recurrence
  short* hmlph    = (short*)Xp_w;            // 3168*256 bf16, after MLP
  short* embh     = (short*)(Xp_w + 1048576);// 30000*256 bf16

  // 1) weight prep + h-state/barrier init + small bf16 converts
  prep_permute<<<4096, 256, 0, stream>>>(Wi_e, Wh_e, bi_e, bh_e, WiPh_e, WhPh_e, biasP_e);
  prep_permute<<<4096, 256, 0, stream>>>(Wi_w, Wh_w, bi_w, bh_w, WiPh_w, WhPh_w, biasP_w);
  init_all<<<32, 256, 0, stream>>>(h0, hq, bar);
  conv_bf16<<<256, 256, 0, stream>>>(Wp, Wph, 512*512/4);
  conv_bf16<<<512, 256, 0, stream>>>(Wm, Wmh, 256*2048/4);

  // 2) Xproj = emb[tok] @ WiP^T + biasP   (MFMA, gather+cvt from f32 emb)
  gemm_mfma<1,1,1,0,0><<<dim3(25,16), 256, 0, stream>>>(
      emb, input_edits, WiPh_e, biasP_e, Xp_e, 3200, 2048, 256, 256, 2048);
  gemm_mfma<1,1,1,0,0><<<dim3(25,16), 256, 0, stream>>>(
      emb, simp_sent,   WiPh_w, biasP_w, Xp_w, 3200, 2048, 256, 256, 2048);

  // 3) recurrence: ONE persistent kernel, fence-free sync
  lstm_persist<<<LSTM_BLOCKS, 256, 0, stream>>>(
      WhPh_e, WhPh_w, Xp_e, Xp_w, c0, hq, outT, out + 95040000L, bar);

  // emb -> bf16 into Xp_w overlay (Xp_w dead after recurrence)
  conv_bf16<<<7500, 256, 0, stream>>>(emb, embh, 30000*256/4);

  // 4) transpose sequences to bf16 [b][t][u]
  transpose_out<<<dim3(100,2), 256, 0, stream>>>(outT, out_e, out_w);

  // 5) key = out_e @ Wp^T  (MFMA)
  gemm_mfma<0,0,0,0,0><<<dim3(25,4), 256, 0, stream>>>(
      out_e, nullptr, Wph, nullptr, key, 3200, 512, 512, 512, 512);

  // 6) attention (f32)
  gemm_f32<1><<<dim3(2,2,32), 256, 0, stream>>>(
      key, enc, Pbuf, 100, 100, 512, 512, 512, 128, 51200, 51200, 12800);
  softmax_rows<<<800, 256, 0, stream>>>(Pbuf);
  gemm_f32<0><<<dim3(8,2,32), 256, 0, stream>>>(
      Pbuf, enc, applied, 100, 512, 100, 128, 512, 512, 12800, 51200, 51200);

  // 7) counters + feat(bf16) + MLP(MFMA, tanh, bf16 out)
  counters_kernel<<<1, 64, 0, stream>>>(input_edits, ctr_del, ctr_ins);
  feat_kernel<<<3168, 256, 0, stream>>>(out_e, applied, enc, out_w, ctr_del, ctr_ins, feath);
  gemm_mfma<0,0,1,1,1><<<dim3(25,2), 256, 0, stream>>>(
      feath, nullptr, Wmh, bmv, hmlph, 3168, 256, 2048, 2048, 256);

  // 8) logits (MFMA) + log-softmax
  gemm_mfma<0,0,1,0,0><<<dim3(25,235), 256, 0, stream>>>(
      hmlph, nullptr, embh, b_out, out, 3168, 30000, 256, 256, 30000);
  lse_rows<<<3168, 256, 0, stream>>>(out, lse);
  sub_lse<<<3168, 256, 0, stream>>>(out, lse);
}

// Round 6
// 1292.563 us; speedup vs baseline: 139.2345x; 1.2085x over previous
//
#include <hip/hip_runtime.h>
#include <math.h>

// Sizes (fixed): B=32, T=100, S=100, H=512, E=256, V=30000, 4H=2048, M_log=3168

typedef __attribute__((ext_vector_type(8))) short short8v;  // 8 bf16 (4 VGPRs)
typedef __attribute__((ext_vector_type(4))) float f32x4;
typedef unsigned long long ull;

#define LSTM_BLOCKS 64

__device__ __forceinline__ float sigf(float x){ return 1.0f/(1.0f + __expf(-x)); }
__device__ __forceinline__ float tanhc(float x){
  x = fminf(fmaxf(x, -15.f), 15.f);
  float e = __expf(2.f*x);
  return (e-1.f)/(e+1.f);
}
__device__ __forceinline__ short f2bf(float f){
  unsigned u = __float_as_uint(f);
  u = (u + 0x7fffu + ((u >> 16) & 1u)) >> 16;
  return (short)u;
}

// ---------------------------------------------------------------------------
// prep: gate-permuted weights. o' = u*4 + g (source row g*512+u)
// ---------------------------------------------------------------------------
__global__ void prep_permute(const float* __restrict__ Wi, const float* __restrict__ Wh,
                             const float* __restrict__ bi, const float* __restrict__ bh,
                             short* __restrict__ WiPh, short* __restrict__ WhPh,
                             float* __restrict__ biasP)
{
  int idx = blockIdx.x*256 + threadIdx.x;      // 0 .. 1048575
  {
    int op = idx >> 9, k = idx & 511;
    int u = op >> 2, g = op & 3;
    WhPh[idx] = f2bf(Wh[(g*512+u)*512 + k]);
  }
  if (idx < 2048*256) {
    int op = idx >> 8, e = idx & 255;
    int u = op >> 2, g = op & 3;
    WiPh[idx] = f2bf(Wi[(g*512+u)*256 + e]);
  }
  if (idx < 2048) {
    int u = idx >> 2, g = idx & 3;
    biasP[idx] = bi[g*512+u] + bh[g*512+u];
  }
}

// init h step-0 buffer (qword-packed bf16: [l][b][u/4]) + zero barrier slots
__global__ void init_all(const float* __restrict__ h0, ull* __restrict__ hq,
                         unsigned* __restrict__ bar)
{
  int idx = blockIdx.x*256 + threadIdx.x;   // 0..8191 : l,b,q
  if (idx < 8192) {
    int b = (idx >> 7) & 31, q = idx & 127;
    const float* src = h0 + b*512 + q*4;
    ull v = ((ull)(unsigned short)f2bf(src[3]) << 48) |
            ((ull)(unsigned short)f2bf(src[2]) << 32) |
            ((ull)(unsigned short)f2bf(src[1]) << 16) |
            ((ull)(unsigned short)f2bf(src[0]));
    hq[idx] = v;                          // buffer 0: idx == (l<<12)+(b<<7)+q
  }
  if (idx < 128) bar[idx] = 0u;
}

// f32 -> bf16 (RNE), n4 float4-groups
__global__ void conv_bf16(const float* __restrict__ src, short* __restrict__ dst, int n4)
{
  int i = blockIdx.x*256 + threadIdx.x;
  if (i >= n4) return;
  float4 v = *(const float4*)(src + (long)i*4);
  short4 o;
  o.x = f2bf(v.x); o.y = f2bf(v.y); o.z = f2bf(v.z); o.w = f2bf(v.w);
  *(short4*)(dst + (long)i*4) = o;
}

// ---------------------------------------------------------------------------
// bf16 MFMA GEMM template: C[M,N] = act( A @ B^T + bias )
// ---------------------------------------------------------------------------
template<int GATHER,int CVT_A,int BIAS,int TANH,int OUT_BF16>
__global__ __launch_bounds__(256) void gemm_mfma(
    const void* __restrict__ Av, const int* __restrict__ tok,
    const short* __restrict__ Bh, const float* __restrict__ bias,
    void* __restrict__ Cv, int M, int N, int K, int lda, int ldc)
{
  __shared__ short As[128][72];
  __shared__ short Bs[128][72];
  const int bm = blockIdx.x * 128;
  const int bn = blockIdx.y * 128;
  const int tid = threadIdx.x;
  const int w = tid >> 6, l = tid & 63;
  const int wr = (w >> 1) * 64, wc = (w & 1) * 64;
  const int lr = l & 15, kg = l >> 4;

  f32x4 acc[4][4] = {};

  for (int k0 = 0; k0 < K; k0 += 64) {
    #pragma unroll
    for (int q = 0; q < 4; ++q) {
      int ci = tid + 256*q;
      int r = ci >> 3, ch = ci & 7;
      int ar = bm + r; if (ar > M-1) ar = M-1;
      if (GATHER) ar = tok[ar];
      if (CVT_A) {
        const float* ap = ((const float*)Av) + (long)ar*lda + k0 + ch*8;
        float4 v0 = *(const float4*)ap;
        float4 v1 = *(const float4*)(ap + 4);
        short8v s;
        s[0]=f2bf(v0.x); s[1]=f2bf(v0.y); s[2]=f2bf(v0.z); s[3]=f2bf(v0.w);
        s[4]=f2bf(v1.x); s[5]=f2bf(v1.y); s[6]=f2bf(v1.z); s[7]=f2bf(v1.w);
        *(short8v*)&As[r][ch*8] = s;
      } else {
        *(short8v*)&As[r][ch*8] =
            *(const short8v*)(((const short*)Av) + (long)ar*lda + k0 + ch*8);
      }
      int br = bn + r; if (br > N-1) br = N-1;
      *(short8v*)&Bs[r][ch*8] = *(const short8v*)(Bh + (long)br*K + k0 + ch*8);
    }
    __syncthreads();
    #pragma unroll
    for (int ks = 0; ks < 2; ++ks) {
      short8v a[4], b[4];
      #pragma unroll
      for (int m = 0; m < 4; ++m)
        a[m] = *(const short8v*)&As[wr + m*16 + lr][ks*32 + kg*8];
      #pragma unroll
      for (int n = 0; n < 4; ++n)
        b[n] = *(const short8v*)&Bs[wc + n*16 + lr][ks*32 + kg*8];
      #pragma unroll
      for (int m = 0; m < 4; ++m)
        #pragma unroll
        for (int n = 0; n < 4; ++n)
          acc[m][n] = __builtin_amdgcn_mfma_f32_16x16x32_bf16(a[m], b[n], acc[m][n], 0, 0, 0);
    }
    __syncthreads();
  }

  #pragma unroll
  for (int n = 0; n < 4; ++n) {
    int col = bn + wc + n*16 + lr;
    bool cok = (col < N);
    float bv = (BIAS && cok) ? bias[col] : 0.f;
    #pragma unroll
    for (int m = 0; m < 4; ++m) {
      int row0 = bm + wr + m*16 + kg*4;
      #pragma unroll
      for (int r = 0; r < 4; ++r) {
        int row = row0 + r;
        if (cok && row < M) {
          float v = acc[m][n][r] + bv;
          if (TANH) v = tanhc(v);
          if (OUT_BF16) ((short*)Cv)[(long)row*ldc + col] = f2bf(v);
          else          ((float*)Cv)[(long)row*ldc + col] = v;
        }
      }
    }
  }
}

// ---------------------------------------------------------------------------
// Generic f32 GEMM (attention scores / applied only)
// ---------------------------------------------------------------------------
template<int TRANSB>
__global__ __launch_bounds__(256) void gemm_f32(
    const float* __restrict__ A, const float* __restrict__ Bmat,
    float* __restrict__ C,
    int M, int N, int K, int lda, int ldb, int ldc,
    long sA, long sB, long sC)
{
  __shared__ float As[32][68];
  __shared__ float Bs[32][68];
  const int z = blockIdx.z;
  A    += (long)z * sA;
  Bmat += (long)z * sB;
  C    += (long)z * sC;
  const int bm = blockIdx.y*64, bn = blockIdx.x*64;
  const int tid = threadIdx.x;
  const int tx = tid & 15, ty = tid >> 4;
  float acc[4][4] = {};

  for (int k0 = 0; k0 < K; k0 += 32) {
    {
      int r = tid >> 2;
      int c0 = (tid & 3) * 8;
      int row = bm + r; if (row > M-1) row = M-1;
      const float* ap = A + (long)row * lda;
      #pragma unroll
      for (int q = 0; q < 2; ++q) {
        int kk = c0 + q*4;
        float4 v;
        if (k0 + kk + 4 <= K) v = *(const float4*)(ap + k0 + kk);
        else {
          v.x = (k0+kk+0 < K) ? ap[k0+kk+0] : 0.f;
          v.y = (k0+kk+1 < K) ? ap[k0+kk+1] : 0.f;
          v.z = (k0+kk+2 < K) ? ap[k0+kk+2] : 0.f;
          v.w = (k0+kk+3 < K) ? ap[k0+kk+3] : 0.f;
        }
        As[kk+0][r]=v.x; As[kk+1][r]=v.y; As[kk+2][r]=v.z; As[kk+3][r]=v.w;
      }
    }
    if (TRANSB) {
      int n = tid >> 2;
      int c0 = (tid & 3) * 8;
      int col = bn + n; if (col > N-1) col = N-1;
      const float* bp = Bmat + (long)col * ldb;
      #pragma unroll
      for (int q = 0; q < 2; ++q) {
        int kk = c0 + q*4;
        float4 v;
        if (k0 + kk + 4 <= K) v = *(const float4*)(bp + k0 + kk);
        else {
          v.x = (k0+kk+0 < K) ? bp[k0+kk+0] : 0.f;
          v.y = (k0+kk+1 < K) ? bp[k0+kk+1] : 0.f;
          v.z = (k0+kk+2 < K) ? bp[k0+kk+2] : 0.f;
          v.w = (k0+kk+3 < K) ? bp[k0+kk+3] : 0.f;
        }
        Bs[kk+0][n]=v.x; Bs[kk+1][n]=v.y; Bs[kk+2][n]=v.z; Bs[kk+3][n]=v.w;
      }
    } else {
      int kk = tid >> 3;
      int c0 = (tid & 7) * 8;
      int krow = k0 + kk;
      #pragma unroll
      for (int q = 0; q < 2; ++q) {
        int cc = c0 + q*4;
        int col = bn + cc;
        float4 v = make_float4(0.f,0.f,0.f,0.f);
        if (krow < K) {
          const float* bp = Bmat + (long)krow * ldb;
          if (col + 4 <= N) v = *(const float4*)(bp + col);
          else {
            v.x = (col+0 < N) ? bp[col+0] : 0.f;
            v.y = (col+1 < N) ? bp[col+1] : 0.f;
            v.z = (col+2 < N) ? bp[col+2] : 0.f;
            v.w = (col+3 < N) ? bp[col+3] : 0.f;
          }
        }
        Bs[kk][cc+0]=v.x; Bs[kk][cc+1]=v.y; Bs[kk][cc+2]=v.z; Bs[kk][cc+3]=v.w;
      }
    }
    __syncthreads();
    #pragma unroll
    for (int kk = 0; kk < 32; ++kk) {
      float4 a = *(const float4*)&As[kk][ty*4];
      float4 b = *(const float4*)&Bs[kk][tx*4];
      acc[0][0]=fmaf(a.x,b.x,acc[0][0]); acc[0][1]=fmaf(a.x,b.y,acc[0][1]);
      acc[0][2]=fmaf(a.x,b.z,acc[0][2]); acc[0][3]=fmaf(a.x,b.w,acc[0][3]);
      acc[1][0]=fmaf(a.y,b.x,acc[1][0]); acc[1][1]=fmaf(a.y,b.y,acc[1][1]);
      acc[1][2]=fmaf(a.y,b.z,acc[1][2]); acc[1][3]=fmaf(a.y,b.w,acc[1][3]);
      acc[2][0]=fmaf(a.z,b.x,acc[2][0]); acc[2][1]=fmaf(a.z,b.y,acc[2][1]);
      acc[2][2]=fmaf(a.z,b.z,acc[2][2]); acc[2][3]=fmaf(a.z,b.w,acc[2][3]);
      acc[3][0]=fmaf(a.w,b.x,acc[3][0]); acc[3][1]=fmaf(a.w,b.y,acc[3][1]);
      acc[3][2]=fmaf(a.w,b.z,acc[3][2]); acc[3][3]=fmaf(a.w,b.w,acc[3][3]);
    }
    __syncthreads();
  }
  #pragma unroll
  for (int i = 0; i < 4; ++i) {
    int row = bm + ty*4 + i;
    if (row >= M) continue;
    #pragma unroll
    for (int j = 0; j < 4; ++j) {
      int col = bn + tx*4 + j;
      if (col >= N) continue;
      C[(long)row*ldc + col] = acc[i][j];
    }
  }
}

// ---------------------------------------------------------------------------
// Persistent LSTM recurrence — per-step h buffers (write-once/read-once).
// Stores: relaxed agent atomics (bypass L2 -> coherent L3).
// Loads:  NORMAL coalesced loads — safe because each buffer is first-touched
//         in this dispatch (single-use), so no stale L2 copy can exist;
//         cross-replay staleness covered by dispatch-start acquire + one
//         explicit agent-acquire at kernel entry.
// Barrier: per-wave vmcnt(0) -> syncthreads -> relaxed fetch_add -> relaxed
//          spin (all threads). No per-step cache maintenance.
// hq layout: [step t=0..100][l][b=32][qword u/4=128]; 64KB per step buffer.
// ---------------------------------------------------------------------------
__global__ __launch_bounds__(256, 1) void lstm_persist(
    const short* __restrict__ WhPh_e, const short* __restrict__ WhPh_w,
    const float* __restrict__ Xp_e, const float* __restrict__ Xp_w,
    const float* __restrict__ c0_in,
    ull* __restrict__ hq,        // [101][2][32][128] qwords
    short* __restrict__ outT,    // [2 lstm][100 t][512 u][32 b] bf16
    float* __restrict__ out_hc,  // he[32][512] then ce[32][512]
    unsigned* __restrict__ bar)  // [128]; t uses 0..98, 100 = entry fence slot
{
  const int bx = blockIdx.x;
  const int l = bx >> 5;
  const int ublk = bx & 31;
  const int tid = threadIdx.x;
  const int w = tid >> 6, lane = tid & 63;
  const int uloc = lane >> 4;          // unit within wave (0..3)
  const int bn = lane & 15;            // batch (and bn+16)
  const int u_global = ublk*16 + w*4 + uloc;
  const int ob = (ublk*16 + w*4) * 4;  // o' base of wave
  const int qcol = ublk*4 + w;         // this wave's qword column

  const short* WhPh = l ? WhPh_w : WhPh_e;
  const float* Xp   = l ? Xp_w   : Xp_e;

  __shared__ short hT[32][520];        // [b][k], +16B pad

  // one-time agent acquire: invalidate L1/L2 so no cross-replay stale lines
  __hip_atomic_load(&bar[100], __ATOMIC_ACQUIRE, __HIP_MEMORY_SCOPE_AGENT);

  // preload weight A-frags
  short8v afr[16];
  {
    const short* wp = WhPh + (long)(ob + bn)*512 + (lane >> 4)*8;
    #pragma unroll
    for (int ks = 0; ks < 16; ++ks)
      afr[ks] = *(const short8v*)(wp + ks*32);
  }
  // persistent cell state
  float c_s0 = c0_in[bn*512 + u_global];
  float c_s1 = c0_in[(bn+16)*512 + u_global];

  for (int t = 0; t < 100; ++t) {
    // Xp gathers issued early
    float4 x0 = *(const float4*)(Xp + ((long)(bn*100 + t))*2048 + u_global*4);
    float4 x1 = *(const float4*)(Xp + ((long)((bn+16)*100 + t))*2048 + u_global*4);
    // stage h: NORMAL coalesced loads of this step's single-use buffer
    {
      const ull* hsrc = hq + (size_t)t*8192 + (l << 12);
      #pragma unroll
      for (int i = 0; i < 16; ++i) {
        int idx = tid + 256*i;         // 0..4095
        int b = idx >> 7, q = idx & 127;
        ull v = hsrc[idx];
        *(ull*)&hT[b][q*4] = v;
      }
    }
    __syncthreads();
    f32x4 acc0 = {}, acc1 = {};
    #pragma unroll
    for (int ks = 0; ks < 16; ++ks) {
      short8v b0 = *(const short8v*)&hT[bn][ks*32 + (lane>>4)*8];
      short8v b1 = *(const short8v*)&hT[bn+16][ks*32 + (lane>>4)*8];
      acc0 = __builtin_amdgcn_mfma_f32_16x16x32_bf16(afr[ks], b0, acc0, 0, 0, 0);
      acc1 = __builtin_amdgcn_mfma_f32_16x16x32_bf16(afr[ks], b1, acc1, 0, 0, 0);
    }
    // cell update (lane-local: acc regs 0..3 = gates i,f,g,o of this unit)
    float gi = acc0[0] + x0.x, gf = acc0[1] + x0.y, gg = acc0[2] + x0.z, go = acc0[3] + x0.w;
    c_s0 = sigf(gf)*c_s0 + sigf(gi)*tanhc(gg);
    float hv0 = sigf(go)*tanhc(c_s0);
    gi = acc1[0] + x1.x; gf = acc1[1] + x1.y; gg = acc1[2] + x1.z; go = acc1[3] + x1.w;
    c_s1 = sigf(gf)*c_s1 + sigf(gi)*tanhc(gg);
    float hv1 = sigf(go)*tanhc(c_s1);

    short hb0 = f2bf(hv0), hb1 = f2bf(hv1);
    // pack 4 units (uloc 0..3 live in lanes bn, bn+16, bn+32, bn+48)
    unsigned p0 = (unsigned)(unsigned short)hb0;
    unsigned p1 = (unsigned)(unsigned short)hb1;
    unsigned a1 = __shfl_down((int)p0, 16), a2 = __shfl_down((int)p0, 32), a3 = __shfl_down((int)p0, 48);
    unsigned e1 = __shfl_down((int)p1, 16), e2 = __shfl_down((int)p1, 32), e3 = __shfl_down((int)p1, 48);
    if (uloc == 0) {
      ull q0 = ((ull)((a2 & 0xffffu) | (a3 << 16)) << 32) | ((p0 & 0xffffu) | (a1 << 16));
      ull q1 = ((ull)((e2 & 0xffffu) | (e3 << 16)) << 32) | ((p1 & 0xffffu) | (e1 << 16));
      ull* hd = hq + (size_t)(t+1)*8192 + (l << 12);
      __hip_atomic_store(&hd[(bn << 7) + qcol],      q0, __ATOMIC_RELAXED, __HIP_MEMORY_SCOPE_AGENT);
      __hip_atomic_store(&hd[((bn+16) << 7) + qcol], q1, __ATOMIC_RELAXED, __HIP_MEMORY_SCOPE_AGENT);
    }
    // sequence output (normal cached stores; visible after kernel end)
    short* od = outT + ((long)(l*100 + t)*512 + u_global)*32;
    od[bn]    = hb0;
    od[bn+16] = hb1;
    if (t == 99 && l == 0) {
      out_hc[bn*512 + u_global]              = hv0;
      out_hc[(bn+16)*512 + u_global]         = hv1;
      out_hc[16384 + bn*512 + u_global]      = c_s0;
      out_hc[16384 + (bn+16)*512 + u_global] = c_s1;
    }
    if (t < 99) {
      asm volatile("s_waitcnt vmcnt(0)" ::: "memory");  // own h-stores at L3
      __syncthreads();                                   // whole block done
      if (tid == 0)
        __hip_atomic_fetch_add(&bar[t], 1u, __ATOMIC_RELAXED, __HIP_MEMORY_SCOPE_AGENT);
      while (__hip_atomic_load(&bar[t], __ATOMIC_RELAXED, __HIP_MEMORY_SCOPE_AGENT)
             < (unsigned)LSTM_BLOCKS)
        __builtin_amdgcn_s_sleep(1);
      // no trailing syncthreads: all hT reads precede the pre-add syncthreads
    }
  }
}

// transpose out sequences bf16 [lstm][t][u][b] -> bf16 [b][t][u]
__global__ __launch_bounds__(256) void transpose_out(
    const short* __restrict__ outT, short* __restrict__ out_e, short* __restrict__ out_w)
{
  __shared__ short tile[512][40];
  const int t = blockIdx.x, l = blockIdx.y;
  const short* src = outT + (long)(l*100 + t)*16384;
  const int tid = threadIdx.x;
  #pragma unroll
  for (int i = 0; i < 8; ++i) {
    int fi = tid + 256*i;
    int u = fi >> 2, b8 = (fi & 3)*8;
    *(short8v*)&tile[u][b8] = *(const short8v*)(src + fi*8);
  }
  __syncthreads();
  short* dst = l ? out_w : out_e;
  for (int b = 0; b < 32; ++b) {
    short* drow = dst + (long)(b*100 + t)*512;
    drow[tid]     = tile[tid][b];
    drow[tid+256] = tile[tid+256][b];
  }
}

__global__ void softmax_rows(float* __restrict__ P)
{
  int row  = blockIdx.x*4 + (threadIdx.x >> 6);
  int lane = threadIdx.x & 63;
  float* p = P + (long)row*128;
  float x0 = (lane      < 100) ? p[lane]    : -INFINITY;
  float x1 = (lane + 64 < 100) ? p[lane+64] : -INFINITY;
  float m = fmaxf(x0, x1);
  #pragma unroll
  for (int off = 32; off; off >>= 1) m = fmaxf(m, __shfl_xor(m, off));
  float e0 = (lane      < 100) ? __expf(x0 - m) : 0.f;
  float e1 = (lane + 64 < 100) ? __expf(x1 - m) : 0.f;
  float s = e0 + e1;
  #pragma unroll
  for (int off = 32; off; off >>= 1) s += __shfl_xor(s, off);
  float inv = 1.f / s;
  if (lane      < 100) p[lane]    = e0 * inv;
  if (lane + 64 < 100) p[lane+64] = e1 * inv;
}

__global__ void counters_kernel(const int* __restrict__ ie,
                                int* __restrict__ ctr_del, int* __restrict__ ctr_ins)
{
  int b = threadIdx.x;
  if (b >= 32) return;
  int rd = 0, ri = 0;
  for (int t = 0; t < 99; ++t) {
    int a = ie[b*100 + t + 1];
    int incd = (a == 2 || a == 3) ? 1 : 0;
    int inci = (a != 3 && a != 5 && a != 0) ? 1 : 0;
    ctr_del[b*99 + t] = min(rd, 99);
    ctr_ins[b*99 + t] = min(ri, 99);
    rd += incd; ri += inci;
  }
}

// build bf16 feat rows [3168][2048] = [out_e | applied | enc[ctr_del] | out_w[ctr_ins]]
__global__ void feat_kernel(const short* __restrict__ out_e, const float* __restrict__ applied,
                            const float* __restrict__ enc,  const short* __restrict__ out_w,
                            const int* __restrict__ ctr_del, const int* __restrict__ ctr_ins,
                            short* __restrict__ feat)
{
  int n = blockIdx.x;                 // 0..3167
  int b = n / 99, t = n % 99;
  int tid = threadIdx.x;
  int seg = tid >> 6;
  int off = (tid & 63) * 8;
  short8v v;
  if (seg == 0) {
    v = *(const short8v*)(out_e + (long)(b*100 + t)*512 + off);
  } else if (seg == 3) {
    v = *(const short8v*)(out_w + (long)(b*100 + ctr_ins[n])*512 + off);
  } else {
    const float* s = (seg == 1) ? applied + (long)(b*100 + t)*512
                                : enc     + (long)(b*100 + ctr_del[n])*512;
    float4 v0 = *(const float4*)(s + off);
    float4 v1 = *(const float4*)(s + off + 4);
    v[0]=f2bf(v0.x); v[1]=f2bf(v0.y); v[2]=f2bf(v0.z); v[3]=f2bf(v0.w);
    v[4]=f2bf(v1.x); v[5]=f2bf(v1.y); v[6]=f2bf(v1.z); v[7]=f2bf(v1.w);
  }
  *(short8v*)(feat + (long)n*2048 + seg*512 + off) = v;
}

// per-row LSE over 30000 cols, one block per row
__global__ __launch_bounds__(256) void lse_rows(const float* __restrict__ C,
                                                float* __restrict__ lse)
{
  int row = blockIdx.x;
  const float* p = C + (long)row*30000;
  float m = -INFINITY, s = 0.f;
  for (int i = threadIdx.x; i < 7500; i += 256) {
    float4 v = *(const float4*)(p + (long)i*4);
    float mv = fmaxf(fmaxf(v.x, v.y), fmaxf(v.z, v.w));
    if (mv > m) { s *= __expf(m - mv); m = mv; }
    s += __expf(v.x - m) + __expf(v.y - m) + __expf(v.z - m) + __expf(v.w - m);
  }
  #pragma unroll
  for (int off = 32; off; off >>= 1) {
    float om = __shfl_xor(m, off);
    float os = __shfl_xor(s, off);
    float nm = fmaxf(m, om);
    s = s*__expf(m - nm) + os*__expf(om - nm);
    m = nm;
  }
  __shared__ float sm[4], ss[4];
  int wv = threadIdx.x >> 6;
  if ((threadIdx.x & 63) == 0) { sm[wv] = m; ss[wv] = s; }
  __syncthreads();
  if (threadIdx.x == 0) {
    float M = sm[0], S = ss[0];
    #pragma unroll
    for (int i = 1; i < 4; ++i) {
      float nm = fmaxf(M, sm[i]);
      S = S*__expf(M - nm) + ss[i]*__expf(sm[i] - nm);
      M = nm;
    }
    lse[row] = M + __logf(S);
  }
}

__global__ void sub_lse(float* __restrict__ C, const float* __restrict__ lse)
{
  int row = blockIdx.x;
  float lv = lse[row];
  float* p = C + (long)row*30000;
  for (int i = threadIdx.x; i < 7500; i += 256) {
    float4 v = *(float4*)(p + (long)i*4);
    v.x -= lv; v.y -= lv; v.z -= lv; v.w -= lv;
    *(float4*)(p + (long)i*4) = v;
  }
}

// ---------------------------------------------------------------------------
extern "C" void kernel_launch(void* const* d_in, const int* in_sizes, int n_in,
                              void* d_out, int out_size, void* d_ws, size_t ws_size,
                              hipStream_t stream)
{
  const int*   input_edits = (const int*)  d_in[0];
  const int*   simp_sent   = (const int*)  d_in[1];
  const float* enc   = (const float*)d_in[3];
  const float* h0    = (const float*)d_in[4];
  const float* c0    = (const float*)d_in[5];
  const float* emb   = (const float*)d_in[6];
  const float* Wi_e  = (const float*)d_in[7];
  const float* Wh_e  = (const float*)d_in[8];
  const float* bi_e  = (const float*)d_in[9];
  const float* bh_e  = (const float*)d_in[10];
  const float* Wi_w  = (const float*)d_in[11];
  const float* Wh_w  = (const float*)d_in[12];
  const float* bi_w  = (const float*)d_in[13];
  const float* bh_w  = (const float*)d_in[14];
  const float* Wp    = (const float*)d_in[15];
  const float* Wm    = (const float*)d_in[16];
  const float* bmv   = (const float*)d_in[17];
  const float* b_out = (const float*)d_in[18];
  float* out = (float*)d_out;

  float* ws = (float*)d_ws;
  size_t off = 0;
  auto alloc = [&](size_t n){ float* p = ws + off; off += (n + 63) & ~(size_t)63; return p; };

  short* WiPh_e   = (short*)alloc(262144);   // 2048*256 bf16
  short* WiPh_w   = (short*)alloc(262144);
  float* biasP_e  = alloc(2048);
  float* biasP_w  = alloc(2048);
  short* WhPh_e   = (short*)alloc(524288);   // 2048*512 bf16
  short* WhPh_w   = (short*)alloc(524288);
  float* Xp_e     = alloc(3200*2048);
  float* Xp_w     = alloc(3200*2048);
  short* outT     = (short*)alloc(1638400);  // 2*100*512*32 bf16
  short* out_e    = (short*)alloc(819200);   // 3200*512 bf16
  short* out_w    = (short*)alloc(819200);
  ull*   hq       = (ull*)alloc(101*8192*2); // 101 step buffers x 64KB
  unsigned* bar   = (unsigned*)alloc(128);
  float* Pbuf     = alloc(3200*128);
  float* lse      = alloc(3168);
  int*   ctr_del  = (int*)alloc(3168);
  int*   ctr_ins  = (int*)alloc(3168);
  short* Wph      = (short*)alloc(131072);   // 512*512 bf16
  short* Wmh      = (short*)alloc(262144);   // 256*2048 bf16
  float* key      = alloc(3200*512);
  float* applied  = alloc(3200*512);
  // overlays (lifetimes disjoint, stream-ordered):
  short* feath    = (short*)Xp_e;            // 3168*2048 bf16, after recurrence
  short* hmlph    = (short*)Xp_w;            // 3168*256 bf16, after MLP
  short* embh     = (short*)(Xp_w + 1048576);// 30000*256 bf16

  // 1) weight prep + h-state/barrier init + small bf16 converts
  prep_permute<<<4096, 256, 0, stream>>>(Wi_e, Wh_e, bi_e, bh_e, WiPh_e, WhPh_e, biasP_e);
  prep_permute<<<4096, 256, 0, stream>>>(Wi_w, Wh_w, bi_w, bh_w, WiPh_w, WhPh_w, biasP_w);
  init_all<<<32, 256, 0, stream>>>(h0, hq, bar);
  conv_bf16<<<256, 256, 0, stream>>>(Wp, Wph, 512*512/4);
  conv_bf16<<<512, 256, 0, stream>>>(Wm, Wmh, 256*2048/4);

  // 2) Xproj = emb[tok] @ WiP^T + biasP   (MFMA, gather+cvt from f32 emb)
  gemm_mfma<1,1,1,0,0><<<dim3(25,16), 256, 0, stream>>>(
      emb, input_edits, WiPh_e, biasP_e, Xp_e, 3200, 2048, 256, 256, 2048);
  gemm_mfma<1,1,1,0,0><<<dim3(25,16), 256, 0, stream>>>(
      emb, simp_sent,   WiPh_w, biasP_w, Xp_w, 3200, 2048, 256, 256, 2048);

  // 3) recurrence: ONE persistent kernel, per-step h buffers
  lstm_persist<<<LSTM_BLOCKS, 256, 0, stream>>>(
      WhPh_e, WhPh_w, Xp_e, Xp_w, c0, hq, outT, out + 95040000L, bar);

  // emb -> bf16 into Xp_w overlay (Xp_w dead after recurrence)
  conv_bf16<<<7500, 256, 0, stream>>>(emb, embh, 30000*256/4);

  // 4) transpose sequences to bf16 [b][t][u]
  transpose_out<<<dim3(100,2), 256, 0, stream>>>(outT, out_e, out_w);

  // 5) key = out_e @ Wp^T  (MFMA)
  gemm_mfma<0,0,0,0,0><<<dim3(25,4), 256, 0, stream>>>(
      out_e, nullptr, Wph, nullptr, key, 3200, 512, 512, 512, 512);

  // 6) attention (f32)
  gemm_f32<1><<<dim3(2,2,32), 256, 0, stream>>>(
      key, enc, Pbuf, 100, 100, 512, 512, 512, 128, 51200, 51200, 12800);
  softmax_rows<<<800, 256, 0, stream>>>(Pbuf);
  gemm_f32<0><<<dim3(8,2,32), 256, 0, stream>>>(
      Pbuf, enc, applied, 100, 512, 100, 128, 512, 512, 12800, 51200, 51200);

  // 7) counters + feat(bf16) + MLP(MFMA, tanh, bf16 out)
  counters_kernel<<<1, 64, 0, stream>>>(input_edits, ctr_del, ctr_ins);
  feat_kernel<<<3168, 256, 0, stream>>>(out_e, applied, enc, out_w, ctr_del, ctr_ins, feath);
  gemm_mfma<0,0,1,1,1><<<dim3(25,2), 256, 0, stream>>>(
      feath, nullptr, Wmh, bmv, hmlph, 3168, 256, 2048, 2048, 256);

  // 8) logits (MFMA) + log-softmax
  gemm_mfma<0,0,1,0,0><<<dim3(25,235), 256, 0, stream>>>(
      hmlph, nullptr, embh, b_out, out, 3168, 30000, 256, 256, 30000);
  lse_rows<<<3168, 256, 0, stream>>>(out, lse);
  sub_lse<<<3168, 256, 0, stream>>>(out, lse);
}

// Round 7
// 964.384 us; speedup vs baseline: 186.6158x; 1.3403x over previous
//
#include <hip/hip_runtime.h>
#include <math.h>

// Sizes (fixed): B=32, T=100, S=100, H=512, E=256, V=30000, 4H=2048, M_log=3168

typedef __attribute__((ext_vector_type(8))) short short8v;  // 8 bf16 (4 VGPRs)
typedef __attribute__((ext_vector_type(4))) float f32x4;
typedef unsigned long long ull;

#define LSTM_BLOCKS 64
#define NTIL 235

__device__ __forceinline__ float sigf(float x){ return 1.0f/(1.0f + __expf(-x)); }
__device__ __forceinline__ float tanhc(float x){
  x = fminf(fmaxf(x, -15.f), 15.f);
  float e = __expf(2.f*x);
  return (e-1.f)/(e+1.f);
}
__device__ __forceinline__ short f2bf(float f){
  unsigned u = __float_as_uint(f);
  u = (u + 0x7fffu + ((u >> 16) & 1u)) >> 16;
  return (short)u;
}
__device__ __forceinline__ float bf2f(short s){
  return __uint_as_float(((unsigned)(unsigned short)s) << 16);
}

// ---------------------------------------------------------------------------
// prep: gate-permuted weights. o' = u*4 + g (source row g*512+u)
// ---------------------------------------------------------------------------
__global__ void prep_permute(const float* __restrict__ Wi, const float* __restrict__ Wh,
                             const float* __restrict__ bi, const float* __restrict__ bh,
                             short* __restrict__ WiPh, short* __restrict__ WhPh,
                             float* __restrict__ biasP)
{
  int idx = blockIdx.x*256 + threadIdx.x;      // 0 .. 1048575
  {
    int op = idx >> 9, k = idx & 511;
    int u = op >> 2, g = op & 3;
    WhPh[idx] = f2bf(Wh[(g*512+u)*512 + k]);
  }
  if (idx < 2048*256) {
    int op = idx >> 8, e = idx & 255;
    int u = op >> 2, g = op & 3;
    WiPh[idx] = f2bf(Wi[(g*512+u)*256 + e]);
  }
  if (idx < 2048) {
    int u = idx >> 2, g = idx & 3;
    biasP[idx] = bi[g*512+u] + bh[g*512+u];
  }
}

// init h step-0 buffer (qword-packed bf16: [l][b][u/4]) + zero flag slots
__global__ void init_all(const float* __restrict__ h0, ull* __restrict__ hq,
                         unsigned* __restrict__ bar)
{
  int idx = blockIdx.x*256 + threadIdx.x;   // 0..8191 : l,b,q
  if (idx < 8192) {
    int b = (idx >> 7) & 31, q = idx & 127;
    const float* src = h0 + b*512 + q*4;
    ull v = ((ull)(unsigned short)f2bf(src[3]) << 48) |
            ((ull)(unsigned short)f2bf(src[2]) << 32) |
            ((ull)(unsigned short)f2bf(src[1]) << 16) |
            ((ull)(unsigned short)f2bf(src[0]));
    hq[idx] = v;                          // buffer 0: idx == (l<<12)+(b<<7)+q
  }
  if (idx < 128) bar[idx] = 0u;
}

// f32 -> bf16 (RNE), n4 float4-groups
__global__ void conv_bf16(const float* __restrict__ src, short* __restrict__ dst, int n4)
{
  int i = blockIdx.x*256 + threadIdx.x;
  if (i >= n4) return;
  float4 v = *(const float4*)(src + (long)i*4);
  short4 o;
  o.x = f2bf(v.x); o.y = f2bf(v.y); o.z = f2bf(v.z); o.w = f2bf(v.w);
  *(short4*)(dst + (long)i*4) = o;
}

// ---------------------------------------------------------------------------
// bf16 MFMA GEMM template: C[M,N] = act( A @ B^T + bias )
// ---------------------------------------------------------------------------
template<int GATHER,int CVT_A,int BIAS,int TANH,int OUT_BF16>
__global__ __launch_bounds__(256) void gemm_mfma(
    const void* __restrict__ Av, const int* __restrict__ tok,
    const short* __restrict__ Bh, const float* __restrict__ bias,
    void* __restrict__ Cv, int M, int N, int K, int lda, int ldc)
{
  __shared__ short As[128][72];
  __shared__ short Bs[128][72];
  const int bm = blockIdx.x * 128;
  const int bn = blockIdx.y * 128;
  const int tid = threadIdx.x;
  const int w = tid >> 6, l = tid & 63;
  const int wr = (w >> 1) * 64, wc = (w & 1) * 64;
  const int lr = l & 15, kg = l >> 4;

  f32x4 acc[4][4] = {};

  for (int k0 = 0; k0 < K; k0 += 64) {
    #pragma unroll
    for (int q = 0; q < 4; ++q) {
      int ci = tid + 256*q;
      int r = ci >> 3, ch = ci & 7;
      int ar = bm + r; if (ar > M-1) ar = M-1;
      if (GATHER) ar = tok[ar];
      if (CVT_A) {
        const float* ap = ((const float*)Av) + (long)ar*lda + k0 + ch*8;
        float4 v0 = *(const float4*)ap;
        float4 v1 = *(const float4*)(ap + 4);
        short8v s;
        s[0]=f2bf(v0.x); s[1]=f2bf(v0.y); s[2]=f2bf(v0.z); s[3]=f2bf(v0.w);
        s[4]=f2bf(v1.x); s[5]=f2bf(v1.y); s[6]=f2bf(v1.z); s[7]=f2bf(v1.w);
        *(short8v*)&As[r][ch*8] = s;
      } else {
        *(short8v*)&As[r][ch*8] =
            *(const short8v*)(((const short*)Av) + (long)ar*lda + k0 + ch*8);
      }
      int br = bn + r; if (br > N-1) br = N-1;
      *(short8v*)&Bs[r][ch*8] = *(const short8v*)(Bh + (long)br*K + k0 + ch*8);
    }
    __syncthreads();
    #pragma unroll
    for (int ks = 0; ks < 2; ++ks) {
      short8v a[4], b[4];
      #pragma unroll
      for (int m = 0; m < 4; ++m)
        a[m] = *(const short8v*)&As[wr + m*16 + lr][ks*32 + kg*8];
      #pragma unroll
      for (int n = 0; n < 4; ++n)
        b[n] = *(const short8v*)&Bs[wc + n*16 + lr][ks*32 + kg*8];
      #pragma unroll
      for (int m = 0; m < 4; ++m)
        #pragma unroll
        for (int n = 0; n < 4; ++n)
          acc[m][n] = __builtin_amdgcn_mfma_f32_16x16x32_bf16(a[m], b[n], acc[m][n], 0, 0, 0);
    }
    __syncthreads();
  }

  #pragma unroll
  for (int n = 0; n < 4; ++n) {
    int col = bn + wc + n*16 + lr;
    bool cok = (col < N);
    float bv = (BIAS && cok) ? bias[col] : 0.f;
    #pragma unroll
    for (int m = 0; m < 4; ++m) {
      int row0 = bm + wr + m*16 + kg*4;
      #pragma unroll
      for (int r = 0; r < 4; ++r) {
        int row = row0 + r;
        if (cok && row < M) {
          float v = acc[m][n][r] + bv;
          if (TANH) v = tanhc(v);
          if (OUT_BF16) ((short*)Cv)[(long)row*ldc + col] = f2bf(v);
          else          ((float*)Cv)[(long)row*ldc + col] = v;
        }
      }
    }
  }
}

// ---------------------------------------------------------------------------
// logits GEMM + per-tile LSE partials, bf16 logits out.
// C[3168][30000] = hmlp @ emb^T + b_out; partial[row][tile]=(max,sumexp).
// ---------------------------------------------------------------------------
__global__ __launch_bounds__(256) void logits_mfma_partial(
    const short* __restrict__ Ah,   // [3168][256] bf16
    const short* __restrict__ Bh,   // [30000][256] bf16
    const float* __restrict__ bias,
    short* __restrict__ Cg,         // [3168][30000] bf16 logits
    float2* __restrict__ partial)   // [3168][NTIL]
{
  __shared__ short As[128][72];
  __shared__ short Bs[128][72];
  __shared__ float2 red[128][2];
  const int bm = blockIdx.x * 128;
  const int bn = blockIdx.y * 128;
  const int tid = threadIdx.x;
  const int w = tid >> 6, l = tid & 63;
  const int wr = (w >> 1) * 64, wc = (w & 1) * 64;
  const int lr = l & 15, kg = l >> 4;

  f32x4 acc[4][4] = {};

  #pragma unroll
  for (int k0 = 0; k0 < 256; k0 += 64) {
    #pragma unroll
    for (int q = 0; q < 4; ++q) {
      int ci = tid + 256*q;
      int r = ci >> 3, ch = ci & 7;
      int ar = bm + r; if (ar > 3167) ar = 3167;
      *(short8v*)&As[r][ch*8] = *(const short8v*)(Ah + (long)ar*256 + k0 + ch*8);
      int br = bn + r; if (br > 29999) br = 29999;
      *(short8v*)&Bs[r][ch*8] = *(const short8v*)(Bh + (long)br*256 + k0 + ch*8);
    }
    __syncthreads();
    #pragma unroll
    for (int ks = 0; ks < 2; ++ks) {
      short8v a[4], b[4];
      #pragma unroll
      for (int m = 0; m < 4; ++m)
        a[m] = *(const short8v*)&As[wr + m*16 + lr][ks*32 + kg*8];
      #pragma unroll
      for (int n = 0; n < 4; ++n)
        b[n] = *(const short8v*)&Bs[wc + n*16 + lr][ks*32 + kg*8];
      #pragma unroll
      for (int m = 0; m < 4; ++m)
        #pragma unroll
        for (int n = 0; n < 4; ++n)
          acc[m][n] = __builtin_amdgcn_mfma_f32_16x16x32_bf16(a[m], b[n], acc[m][n], 0, 0, 0);
    }
    __syncthreads();
  }

  // bias + OOB mask (-inf)
  #pragma unroll
  for (int n = 0; n < 4; ++n) {
    int col = bn + wc + n*16 + lr;
    float bv = (col < 30000) ? bias[col] : 0.f;
    #pragma unroll
    for (int m = 0; m < 4; ++m)
      #pragma unroll
      for (int r = 0; r < 4; ++r)
        acc[m][n][r] = (col < 30000) ? acc[m][n][r] + bv : -INFINITY;
  }
  // per-row (over this wave's 64 cols) max + sumexp via 16-lane shfl groups.
  // row = wr + m*16 + kg*4 + r lives in lanes kg*16+lr (lr=0..15), cols n*16+lr.
  #pragma unroll
  for (int m = 0; m < 4; ++m) {
    #pragma unroll
    for (int r = 0; r < 4; ++r) {
      float a0 = acc[m][0][r], a1 = acc[m][1][r], a2 = acc[m][2][r], a3 = acc[m][3][r];
      float mx = fmaxf(fmaxf(a0, a1), fmaxf(a2, a3));
      #pragma unroll
      for (int off = 1; off < 16; off <<= 1) mx = fmaxf(mx, __shfl_xor(mx, off));
      float se = 0.f;
      if (mx > -INFINITY)
        se = __expf(a0-mx) + __expf(a1-mx) + __expf(a2-mx) + __expf(a3-mx);
      #pragma unroll
      for (int off = 1; off < 16; off <<= 1) se += __shfl_xor(se, off);
      if (lr == 0) red[wr + m*16 + kg*4 + r][w & 1] = make_float2(mx, se);
    }
  }
  // bf16 logits store
  #pragma unroll
  for (int n = 0; n < 4; ++n) {
    int col = bn + wc + n*16 + lr;
    if (col < 30000) {
      #pragma unroll
      for (int m = 0; m < 4; ++m) {
        int row0 = bm + wr + m*16 + kg*4;
        #pragma unroll
        for (int r = 0; r < 4; ++r) {
          int row = row0 + r;
          if (row < 3168) Cg[(long)row*30000 + col] = f2bf(acc[m][n][r]);
        }
      }
    }
  }
  __syncthreads();
  if (tid < 128) {
    int row = bm + tid;
    if (row < 3168) {
      float2 A = red[tid][0], B = red[tid][1];
      float M = fmaxf(A.x, B.x);
      float S = 0.f;
      if (M > -INFINITY) S = A.y*__expf(A.x - M) + B.y*__expf(B.x - M);
      partial[(long)row*NTIL + blockIdx.y] = make_float2(M, S);
    }
  }
}

// combine per-tile partials -> lse per row; one wave per row
__global__ void lse_reduce(const float2* __restrict__ partial, float* __restrict__ lse)
{
  int row  = blockIdx.x*4 + (threadIdx.x >> 6);
  int lane = threadIdx.x & 63;
  if (row >= 3168) return;
  const float2* pr = partial + (long)row*NTIL;
  float m = -INFINITY, s = 0.f;
  for (int tl = lane; tl < NTIL; tl += 64) {
    float2 p = pr[tl];
    float nm = fmaxf(m, p.x);
    if (nm > -INFINITY) {
      s = s*__expf(m - nm) + p.y*__expf(p.x - nm);
      m = nm;
    }
  }
  #pragma unroll
  for (int off = 32; off; off >>= 1) {
    float om = __shfl_xor(m, off);
    float os = __shfl_xor(s, off);
    float nm = fmaxf(m, om);
    if (nm > -INFINITY) {
      s = s*__expf(m - nm) + os*__expf(om - nm);
      m = nm;
    }
  }
  if (lane == 0) lse[row] = m + __logf(s);
}

// logp = bf16logit - lse  (read 190MB, write 380MB)
__global__ __launch_bounds__(256) void sub_lse_bf16(const short* __restrict__ Cg,
                                                    const float* __restrict__ lse,
                                                    float* __restrict__ out)
{
  int row = blockIdx.x;
  float lv = lse[row];
  const short* src = Cg + (long)row*30000;
  float* dst = out + (long)row*30000;
  for (int i = threadIdx.x; i < 3750; i += 256) {
    short8v v = *(const short8v*)(src + i*8);
    float4 o0, o1;
    o0.x = bf2f(v[0]) - lv; o0.y = bf2f(v[1]) - lv;
    o0.z = bf2f(v[2]) - lv; o0.w = bf2f(v[3]) - lv;
    o1.x = bf2f(v[4]) - lv; o1.y = bf2f(v[5]) - lv;
    o1.z = bf2f(v[6]) - lv; o1.w = bf2f(v[7]) - lv;
    *(float4*)(dst + i*8)     = o0;
    *(float4*)(dst + i*8 + 4) = o1;
  }
}

// ---------------------------------------------------------------------------
// Generic f32 GEMM (attention scores / applied only)
// ---------------------------------------------------------------------------
template<int TRANSB>
__global__ __launch_bounds__(256) void gemm_f32(
    const float* __restrict__ A, const float* __restrict__ Bmat,
    float* __restrict__ C,
    int M, int N, int K, int lda, int ldb, int ldc,
    long sA, long sB, long sC)
{
  __shared__ float As[32][68];
  __shared__ float Bs[32][68];
  const int z = blockIdx.z;
  A    += (long)z * sA;
  Bmat += (long)z * sB;
  C    += (long)z * sC;
  const int bm = blockIdx.y*64, bn = blockIdx.x*64;
  const int tid = threadIdx.x;
  const int tx = tid & 15, ty = tid >> 4;
  float acc[4][4] = {};

  for (int k0 = 0; k0 < K; k0 += 32) {
    {
      int r = tid >> 2;
      int c0 = (tid & 3) * 8;
      int row = bm + r; if (row > M-1) row = M-1;
      const float* ap = A + (long)row * lda;
      #pragma unroll
      for (int q = 0; q < 2; ++q) {
        int kk = c0 + q*4;
        float4 v;
        if (k0 + kk + 4 <= K) v = *(const float4*)(ap + k0 + kk);
        else {
          v.x = (k0+kk+0 < K) ? ap[k0+kk+0] : 0.f;
          v.y = (k0+kk+1 < K) ? ap[k0+kk+1] : 0.f;
          v.z = (k0+kk+2 < K) ? ap[k0+kk+2] : 0.f;
          v.w = (k0+kk+3 < K) ? ap[k0+kk+3] : 0.f;
        }
        As[kk+0][r]=v.x; As[kk+1][r]=v.y; As[kk+2][r]=v.z; As[kk+3][r]=v.w;
      }
    }
    if (TRANSB) {
      int n = tid >> 2;
      int c0 = (tid & 3) * 8;
      int col = bn + n; if (col > N-1) col = N-1;
      const float* bp = Bmat + (long)col * ldb;
      #pragma unroll
      for (int q = 0; q < 2; ++q) {
        int kk = c0 + q*4;
        float4 v;
        if (k0 + kk + 4 <= K) v = *(const float4*)(bp + k0 + kk);
        else {
          v.x = (k0+kk+0 < K) ? bp[k0+kk+0] : 0.f;
          v.y = (k0+kk+1 < K) ? bp[k0+kk+1] : 0.f;
          v.z = (k0+kk+2 < K) ? bp[k0+kk+2] : 0.f;
          v.w = (k0+kk+3 < K) ? bp[k0+kk+3] : 0.f;
        }
        Bs[kk+0][n]=v.x; Bs[kk+1][n]=v.y; Bs[kk+2][n]=v.z; Bs[kk+3][n]=v.w;
      }
    } else {
      int kk = tid >> 3;
      int c0 = (tid & 7) * 8;
      int krow = k0 + kk;
      #pragma unroll
      for (int q = 0; q < 2; ++q) {
        int cc = c0 + q*4;
        int col = bn + cc;
        float4 v = make_float4(0.f,0.f,0.f,0.f);
        if (krow < K) {
          const float* bp = Bmat + (long)krow * ldb;
          if (col + 4 <= N) v = *(const float4*)(bp + col);
          else {
            v.x = (col+0 < N) ? bp[col+0] : 0.f;
            v.y = (col+1 < N) ? bp[col+1] : 0.f;
            v.z = (col+2 < N) ? bp[col+2] : 0.f;
            v.w = (col+3 < N) ? bp[col+3] : 0.f;
          }
        }
        Bs[kk][cc+0]=v.x; Bs[kk][cc+1]=v.y; Bs[kk][cc+2]=v.z; Bs[kk][cc+3]=v.w;
      }
    }
    __syncthreads();
    #pragma unroll
    for (int kk = 0; kk < 32; ++kk) {
      float4 a = *(const float4*)&As[kk][ty*4];
      float4 b = *(const float4*)&Bs[kk][tx*4];
      acc[0][0]=fmaf(a.x,b.x,acc[0][0]); acc[0][1]=fmaf(a.x,b.y,acc[0][1]);
      acc[0][2]=fmaf(a.x,b.z,acc[0][2]); acc[0][3]=fmaf(a.x,b.w,acc[0][3]);
      acc[1][0]=fmaf(a.y,b.x,acc[1][0]); acc[1][1]=fmaf(a.y,b.y,acc[1][1]);
      acc[1][2]=fmaf(a.y,b.z,acc[1][2]); acc[1][3]=fmaf(a.y,b.w,acc[1][3]);
      acc[2][0]=fmaf(a.z,b.x,acc[2][0]); acc[2][1]=fmaf(a.z,b.y,acc[2][1]);
      acc[2][2]=fmaf(a.z,b.z,acc[2][2]); acc[2][3]=fmaf(a.z,b.w,acc[2][3]);
      acc[3][0]=fmaf(a.w,b.x,acc[3][0]); acc[3][1]=fmaf(a.w,b.y,acc[3][1]);
      acc[3][2]=fmaf(a.w,b.z,acc[3][2]); acc[3][3]=fmaf(a.w,b.w,acc[3][3]);
    }
    __syncthreads();
  }
  #pragma unroll
  for (int i = 0; i < 4; ++i) {
    int row = bm + ty*4 + i;
    if (row >= M) continue;
    #pragma unroll
    for (int j = 0; j < 4; ++j) {
      int col = bn + tx*4 + j;
      if (col >= N) continue;
      C[(long)row*ldc + col] = acc[i][j];
    }
  }
}

// ---------------------------------------------------------------------------
// Persistent LSTM recurrence — producer-flag sync (no central barrier).
// Per-block monotonic flags: flags[bx] = t+1 once block bx's h[t+1] atomic
// stores are drained to L3 (vmcnt(0) + syncthreads first). Consumers poll
// only their LSTM's 32 flags (32 lanes, one read burst, no RMW, no hot line).
// h data: relaxed agent atomic stores (L3) / normal coalesced loads of
// single-use per-step buffers (first touch in-dispatch -> no stale L2).
// ---------------------------------------------------------------------------
__global__ __launch_bounds__(256, 1) void lstm_persist(
    const short* __restrict__ WhPh_e, const short* __restrict__ WhPh_w,
    const float* __restrict__ Xp_e, const float* __restrict__ Xp_w,
    const float* __restrict__ c0_in,
    ull* __restrict__ hq,        // [101][2][32][128] qwords
    short* __restrict__ outT,    // [2 lstm][100 t][512 u][32 b] bf16
    float* __restrict__ out_hc,  // he[32][512] then ce[32][512]
    unsigned* __restrict__ flags)// [0..63] per-block flags; [100] entry fence
{
  const int bx = blockIdx.x;
  const int l = bx >> 5;
  const int ublk = bx & 31;
  const int tid = threadIdx.x;
  const int w = tid >> 6, lane = tid & 63;
  const int uloc = lane >> 4;          // unit within wave (0..3)
  const int bn = lane & 15;            // batch (and bn+16)
  const int u_global = ublk*16 + w*4 + uloc;
  const int ob = (ublk*16 + w*4) * 4;  // o' base of wave
  const int qcol = ublk*4 + w;         // this wave's qword column

  const short* WhPh = l ? WhPh_w : WhPh_e;
  const float* Xp   = l ? Xp_w   : Xp_e;
  const unsigned* myfl = flags + l*32;

  __shared__ short hT[32][520];        // [b][k], +16B pad

  // one-time agent acquire: no cross-replay stale lines in L1/L2
  __hip_atomic_load(&flags[100], __ATOMIC_ACQUIRE, __HIP_MEMORY_SCOPE_AGENT);

  // preload weight A-frags
  short8v afr[16];
  {
    const short* wp = WhPh + (long)(ob + bn)*512 + (lane >> 4)*8;
    #pragma unroll
    for (int ks = 0; ks < 16; ++ks)
      afr[ks] = *(const short8v*)(wp + ks*32);
  }
  // persistent cell state
  float c_s0 = c0_in[bn*512 + u_global];
  float c_s1 = c0_in[(bn+16)*512 + u_global];

  for (int t = 0; t < 100; ++t) {
    // Xp gathers issued early (independent of flags)
    float4 x0 = *(const float4*)(Xp + ((long)(bn*100 + t))*2048 + u_global*4);
    float4 x1 = *(const float4*)(Xp + ((long)((bn+16)*100 + t))*2048 + u_global*4);
    // wait for all 32 producers of this lstm to have published h[t]
    if (t) {
      int ok;
      do {
        unsigned f = (lane < 32)
          ? __hip_atomic_load(&myfl[lane], __ATOMIC_RELAXED, __HIP_MEMORY_SCOPE_AGENT)
          : 0xffffffffu;
        ok = __all((int)(f >= (unsigned)t));
        if (!ok) __builtin_amdgcn_s_sleep(1);
      } while (!ok);
    }
    // stage h: normal coalesced loads of this step's single-use buffer
    {
      const ull* hsrc = hq + (size_t)t*8192 + (l << 12);
      #pragma unroll
      for (int i = 0; i < 16; ++i) {
        int idx = tid + 256*i;         // 0..4095
        int b = idx >> 7, q = idx & 127;
        *(ull*)&hT[b][q*4] = hsrc[idx];
      }
    }
    __syncthreads();
    f32x4 acc0 = {}, acc1 = {};
    #pragma unroll
    for (int ks = 0; ks < 16; ++ks) {
      short8v b0 = *(const short8v*)&hT[bn][ks*32 + (lane>>4)*8];
      short8v b1 = *(const short8v*)&hT[bn+16][ks*32 + (lane>>4)*8];
      acc0 = __builtin_amdgcn_mfma_f32_16x16x32_bf16(afr[ks], b0, acc0, 0, 0, 0);
      acc1 = __builtin_amdgcn_mfma_f32_16x16x32_bf16(afr[ks], b1, acc1, 0, 0, 0);
    }
    // cell update (lane-local: acc regs 0..3 = gates i,f,g,o of this unit)
    float gi = acc0[0] + x0.x, gf = acc0[1] + x0.y, gg = acc0[2] + x0.z, go = acc0[3] + x0.w;
    c_s0 = sigf(gf)*c_s0 + sigf(gi)*tanhc(gg);
    float hv0 = sigf(go)*tanhc(c_s0);
    gi = acc1[0] + x1.x; gf = acc1[1] + x1.y; gg = acc1[2] + x1.z; go = acc1[3] + x1.w;
    c_s1 = sigf(gf)*c_s1 + sigf(gi)*tanhc(gg);
    float hv1 = sigf(go)*tanhc(c_s1);

    short hb0 = f2bf(hv0), hb1 = f2bf(hv1);
    // pack 4 units (uloc 0..3 live in lanes bn, bn+16, bn+32, bn+48)
    unsigned p0 = (unsigned)(unsigned short)hb0;
    unsigned p1 = (unsigned)(unsigned short)hb1;
    unsigned a1 = __shfl_down((int)p0, 16), a2 = __shfl_down((int)p0, 32), a3 = __shfl_down((int)p0, 48);
    unsigned e1 = __shfl_down((int)p1, 16), e2 = __shfl_down((int)p1, 32), e3 = __shfl_down((int)p1, 48);
    if (uloc == 0) {
      ull q0 = ((ull)((a2 & 0xffffu) | (a3 << 16)) << 32) | ((p0 & 0xffffu) | (a1 << 16));
      ull q1 = ((ull)((e2 & 0xffffu) | (e3 << 16)) << 32) | ((p1 & 0xffffu) | (e1 << 16));
      ull* hd = hq + (size_t)(t+1)*8192 + (l << 12);
      __hip_atomic_store(&hd[(bn << 7) + qcol],      q0, __ATOMIC_RELAXED, __HIP_MEMORY_SCOPE_AGENT);
      __hip_atomic_store(&hd[((bn+16) << 7) + qcol], q1, __ATOMIC_RELAXED, __HIP_MEMORY_SCOPE_AGENT);
    }
    // sequence output (normal cached stores; visible after kernel end)
    short* od = outT + ((long)(l*100 + t)*512 + u_global)*32;
    od[bn]    = hb0;
    od[bn+16] = hb1;
    if (t == 99 && l == 0) {
      out_hc[bn*512 + u_global]              = hv0;
      out_hc[(bn+16)*512 + u_global]         = hv1;
      out_hc[16384 + bn*512 + u_global]      = c_s0;
      out_hc[16384 + (bn+16)*512 + u_global] = c_s1;
    }
    if (t < 99) {
      asm volatile("s_waitcnt vmcnt(0)" ::: "memory");  // own h-stores at L3
      __syncthreads();                                   // whole block drained
      if (tid == 0)
        __hip_atomic_store(&flags[bx], (unsigned)(t+1),
                           __ATOMIC_RELAXED, __HIP_MEMORY_SCOPE_AGENT);
    }
  }
}

// transpose out sequences bf16 [lstm][t][u][b] -> bf16 [b][t][u]
__global__ __launch_bounds__(256) void transpose_out(
    const short* __restrict__ outT, short* __restrict__ out_e, short* __restrict__ out_w)
{
  __shared__ short tile[512][40];
  const int t = blockIdx.x, l = blockIdx.y;
  const short* src = outT + (long)(l*100 + t)*16384;
  const int tid = threadIdx.x;
  #pragma unroll
  for (int i = 0; i < 8; ++i) {
    int fi = tid + 256*i;
    int u = fi >> 2, b8 = (fi & 3)*8;
    *(short8v*)&tile[u][b8] = *(const short8v*)(src + fi*8);
  }
  __syncthreads();
  short* dst = l ? out_w : out_e;
  for (int b = 0; b < 32; ++b) {
    short* drow = dst + (long)(b*100 + t)*512;
    drow[tid]     = tile[tid][b];
    drow[tid+256] = tile[tid+256][b];
  }
}

__global__ void softmax_rows(float* __restrict__ P)
{
  int row  = blockIdx.x*4 + (threadIdx.x >> 6);
  int lane = threadIdx.x & 63;
  float* p = P + (long)row*128;
  float x0 = (lane      < 100) ? p[lane]    : -INFINITY;
  float x1 = (lane + 64 < 100) ? p[lane+64] : -INFINITY;
  float m = fmaxf(x0, x1);
  #pragma unroll
  for (int off = 32; off; off >>= 1) m = fmaxf(m, __shfl_xor(m, off));
  float e0 = (lane      < 100) ? __expf(x0 - m) : 0.f;
  float e1 = (lane + 64 < 100) ? __expf(x1 - m) : 0.f;
  float s = e0 + e1;
  #pragma unroll
  for (int off = 32; off; off >>= 1) s += __shfl_xor(s, off);
  float inv = 1.f / s;
  if (lane      < 100) p[lane]    = e0 * inv;
  if (lane + 64 < 100) p[lane+64] = e1 * inv;
}

__global__ void counters_kernel(const int* __restrict__ ie,
                                int* __restrict__ ctr_del, int* __restrict__ ctr_ins)
{
  int b = threadIdx.x;
  if (b >= 32) return;
  int rd = 0, ri = 0;
  for (int t = 0; t < 99; ++t) {
    int a = ie[b*100 + t + 1];
    int incd = (a == 2 || a == 3) ? 1 : 0;
    int inci = (a != 3 && a != 5 && a != 0) ? 1 : 0;
    ctr_del[b*99 + t] = min(rd, 99);
    ctr_ins[b*99 + t] = min(ri, 99);
    rd += incd; ri += inci;
  }
}

// build bf16 feat rows [3168][2048] = [out_e | applied | enc[ctr_del] | out_w[ctr_ins]]
__global__ void feat_kernel(const short* __restrict__ out_e, const float* __restrict__ applied,
                            const float* __restrict__ enc,  const short* __restrict__ out_w,
                            const int* __restrict__ ctr_del, const int* __restrict__ ctr_ins,
                            short* __restrict__ feat)
{
  int n = blockIdx.x;                 // 0..3167
  int b = n / 99, t = n % 99;
  int tid = threadIdx.x;
  int seg = tid >> 6;
  int off = (tid & 63) * 8;
  short8v v;
  if (seg == 0) {
    v = *(const short8v*)(out_e + (long)(b*100 + t)*512 + off);
  } else if (seg == 3) {
    v = *(const short8v*)(out_w + (long)(b*100 + ctr_ins[n])*512 + off);
  } else {
    const float* s = (seg == 1) ? applied + (long)(b*100 + t)*512
                                : enc     + (long)(b*100 + ctr_del[n])*512;
    float4 v0 = *(const float4*)(s + off);
    float4 v1 = *(const float4*)(s + off + 4);
    v[0]=f2bf(v0.x); v[1]=f2bf(v0.y); v[2]=f2bf(v0.z); v[3]=f2bf(v0.w);
    v[4]=f2bf(v1.x); v[5]=f2bf(v1.y); v[6]=f2bf(v1.z); v[7]=f2bf(v1.w);
  }
  *(short8v*)(feat + (long)n*2048 + seg*512 + off) = v;
}

// ---------------------------------------------------------------------------
extern "C" void kernel_launch(void* const* d_in, const int* in_sizes, int n_in,
                              void* d_out, int out_size, void* d_ws, size_t ws_size,
                              hipStream_t stream)
{
  const int*   input_edits = (const int*)  d_in[0];
  const int*   simp_sent   = (const int*)  d_in[1];
  const float* enc   = (const float*)d_in[3];
  const float* h0    = (const float*)d_in[4];
  const float* c0    = (const float*)d_in[5];
  const float* emb   = (const float*)d_in[6];
  const float* Wi_e  = (const float*)d_in[7];
  const float* Wh_e  = (const float*)d_in[8];
  const float* bi_e  = (const float*)d_in[9];
  const float* bh_e  = (const float*)d_in[10];
  const float* Wi_w  = (const float*)d_in[11];
  const float* Wh_w  = (const float*)d_in[12];
  const float* bi_w  = (const float*)d_in[13];
  const float* bh_w  = (const float*)d_in[14];
  const float* Wp    = (const float*)d_in[15];
  const float* Wm    = (const float*)d_in[16];
  const float* bmv   = (const float*)d_in[17];
  const float* b_out = (const float*)d_in[18];
  float* out = (float*)d_out;

  float* ws = (float*)d_ws;
  size_t off = 0;
  auto alloc = [&](size_t n){ float* p = ws + off; off += (n + 63) & ~(size_t)63; return p; };

  short* WiPh_e   = (short*)alloc(262144);   // 2048*256 bf16
  short* WiPh_w   = (short*)alloc(262144);
  float* biasP_e  = alloc(2048);
  float* biasP_w  = alloc(2048);
  short* WhPh_e   = (short*)alloc(524288);   // 2048*512 bf16
  short* WhPh_w   = (short*)alloc(524288);
  float* Xp_e     = alloc(3200*2048);
  float* Xp_w     = alloc(3200*2048);
  short* outT     = (short*)alloc(1638400);  // 2*100*512*32 bf16
  short* out_e    = (short*)alloc(819200);   // 3200*512 bf16
  short* out_w    = (short*)alloc(819200);
  ull*   hq       = (ull*)alloc(101*8192*2); // 101 step buffers x 64KB
  unsigned* bar   = (unsigned*)alloc(128);   // flags[0..63] + entry slot [100]
  float* Pbuf     = alloc(3200*128);
  float* lse      = alloc(3168);
  int*   ctr_del  = (int*)alloc(3168);
  int*   ctr_ins  = (int*)alloc(3168);
  short* Wph      = (short*)alloc(131072);   // 512*512 bf16
  short* Wmh      = (short*)alloc(262144);   // 256*2048 bf16
  float* key      = alloc(3200*512);
  float* applied  = alloc(3200*512);
  short* logith   = (short*)alloc(47520000); // 3168*30000 bf16 logits (190MB)
  float2* partial = (float2*)alloc(3168*NTIL*2);
  // overlays (lifetimes disjoint, stream-ordered):
  short* feath    = (short*)Xp_e;            // 3168*2048 bf16, after recurrence
  short* hmlph    = (short*)Xp_w;            // 3168*256 bf16, after MLP
  short* embh     = (short*)(Xp_w + 1048576);// 30000*256 bf16

  // 1) weight prep + h-state/flag init + small bf16 converts
  prep_permute<<<4096, 256, 0, stream>>>(Wi_e, Wh_e, bi_e, bh_e, WiPh_e, WhPh_e, biasP_e);
  prep_permute<<<4096, 256, 0, stream>>>(Wi_w, Wh_w, bi_w, bh_w, WiPh_w, WhPh_w, biasP_w);
  init_all<<<32, 256, 0, stream>>>(h0, hq, bar);
  conv_bf16<<<256, 256, 0, stream>>>(Wp, Wph, 512*512/4);
  conv_bf16<<<512, 256, 0, stream>>>(Wm, Wmh, 256*2048/4);

  // 2) Xproj = emb[tok] @ WiP^T + biasP   (MFMA, gather+cvt from f32 emb)
  gemm_mfma<1,1,1,0,0><<<dim3(25,16), 256, 0, stream>>>(
      emb, input_edits, WiPh_e, biasP_e, Xp_e, 3200, 2048, 256, 256, 2048);
  gemm_mfma<1,1,1,0,0><<<dim3(25,16), 256, 0, stream>>>(
      emb, simp_sent,   WiPh_w, biasP_w, Xp_w, 3200, 2048, 256, 256, 2048);

  // 3) recurrence: ONE persistent kernel, producer-flag sync
  lstm_persist<<<LSTM_BLOCKS, 256, 0, stream>>>(
      WhPh_e, WhPh_w, Xp_e, Xp_w, c0, hq, outT, out + 95040000L, bar);

  // emb -> bf16 into Xp_w overlay (Xp_w dead after recurrence)
  conv_bf16<<<7500, 256, 0, stream>>>(emb, embh, 30000*256/4);

  // 4) transpose sequences to bf16 [b][t][u]
  transpose_out<<<dim3(100,2), 256, 0, stream>>>(outT, out_e, out_w);

  // 5) key = out_e @ Wp^T  (MFMA)
  gemm_mfma<0,0,0,0,0><<<dim3(25,4), 256, 0, stream>>>(
      out_e, nullptr, Wph, nullptr, key, 3200, 512, 512, 512, 512);

  // 6) attention (f32)
  gemm_f32<1><<<dim3(2,2,32), 256, 0, stream>>>(
      key, enc, Pbuf, 100, 100, 512, 512, 512, 128, 51200, 51200, 12800);
  softmax_rows<<<800, 256, 0, stream>>>(Pbuf);
  gemm_f32<0><<<dim3(8,2,32), 256, 0, stream>>>(
      Pbuf, enc, applied, 100, 512, 100, 128, 512, 512, 12800, 51200, 51200);

  // 7) counters + feat(bf16) + MLP(MFMA, tanh, bf16 out)
  counters_kernel<<<1, 64, 0, stream>>>(input_edits, ctr_del, ctr_ins);
  feat_kernel<<<3168, 256, 0, stream>>>(out_e, applied, enc, out_w, ctr_del, ctr_ins, feath);
  gemm_mfma<0,0,1,1,1><<<dim3(25,2), 256, 0, stream>>>(
      feath, nullptr, Wmh, bmv, hmlph, 3168, 256, 2048, 2048, 256);

  // 8) logits (MFMA, bf16 out + LSE partials) + log-softmax
  logits_mfma_partial<<<dim3(25, NTIL), 256, 0, stream>>>(
      hmlph, embh, b_out, logith, partial);
  lse_reduce<<<792, 256, 0, stream>>>(partial, lse);
  sub_lse_bf16<<<3168, 256, 0, stream>>>(logith, lse, out);
}